// Round 11
// baseline (259.557 us; speedup 1.0000x reference)
//
#include <hip/hip_runtime.h>
#include <hip/hip_fp16.h>

#define N_NODES 100000
#define N_EDGES 3200000
#define N_PAD   100096
#define BNODES  128
#define NBUCK   ((N_NODES + BNODES - 1) / BNODES)       // 782
#define BCAP    4800                                    // mean 4096, sigma 64 (11 sigma)
#define EPB_BIN 4096                                    // edges per bin block (16/thread)
#define BIN_BLOCKS ((N_EDGES + EPB_BIN - 1) / EPB_BIN)  // 782
#define SPILL_MAX 65536
#define NPX      (N_NODES / 8)                          // 12500 nodes per XCD slab
#define GBLK     (8 * ((NPX + 7) / 8))                  // 12504 gather blocks (8 nodes each)
#define SCAN_CHUNK 2048
#define SCAN_BLOCKS ((N_NODES + SCAN_CHUNK - 1) / SCAN_CHUNK)

typedef unsigned int uint;
typedef unsigned short ushort;
typedef unsigned long long ull;
typedef uint uintx4 __attribute__((ext_vector_type(4)));   // native vector for nontemporal builtin

__device__ __forceinline__ __half2 as_h2(uint u) { return *reinterpret_cast<__half2*>(&u); }
__device__ __forceinline__ uint as_u32(__half2 h) { return *reinterpret_cast<uint*>(&h); }

// fixed-stride row address inside the bucket region (bucket stride BCAP*2 uints)
__device__ __forceinline__ size_t srow(int n) {
    return (size_t)(n >> 7) * (BCAP * 2) + (size_t)(n & 127) * 64;
}

// ===================== fast path: pre0 -> bin -> sortz -> gather =====================

// zero bucket_cnt + spill_cnt only
__global__ __launch_bounds__(256) void k_pre0(int* __restrict__ bucket_cnt,
                                              int* __restrict__ spill_cnt) {
    int i = blockIdx.x * 256 + threadIdx.x;
    if (i < NBUCK) bucket_cnt[i] = 0;
    if (i == 0) *spill_cnt = 0;
}

// counting-sort edges into 782 dst-buckets. Block-local LDS sort first, then
// RUN-ORDERED writeback: a wave's 64 stores span ~12 contiguous runs instead of
// 64 scattered lines (cross-XCD partial-line write amplification was k_bin's cost).
__global__ __launch_bounds__(256) void k_bin(const int* __restrict__ src,
                                             const int* __restrict__ dst,
                                             const float* __restrict__ w,
                                             int* __restrict__ bucket_cnt,
                                             uint2* __restrict__ ebuf,
                                             int4* __restrict__ sp,
                                             int* __restrict__ spill_cnt) {
    __shared__ int   hist[NBUCK];          // 3.1 KB
    __shared__ int   base[NBUCK];          // 3.1 KB  global run start for this block
    __shared__ int   pref[NBUCK];          // 3.1 KB  block-local exclusive prefix
    __shared__ int   rank[NBUCK];          // 3.1 KB
    __shared__ int   psum[256];            // 1 KB
    __shared__ uint2 sorted[EPB_BIN];      // 32 KB   bucket-sorted entries
    __shared__ ushort bid[EPB_BIN];        // 8 KB    bucket id per position
    int tid = threadIdx.x;
    for (int b = tid; b < NBUCK; b += 256) { hist[b] = 0; rank[b] = 0; }
    __syncthreads();
    int e0 = blockIdx.x * EPB_BIN;
    // pass 1: histogram (plain loads -> window stays L2-hot for pass 2)
#pragma unroll 4
    for (int k = 0; k < 16; k++) {
        int e = e0 + tid + k * 256;
        if (e < N_EDGES) atomicAdd(&hist[dst[e] >> 7], 1);
    }
    __syncthreads();
    // reserve global bases
    for (int b = tid; b < NBUCK; b += 256) {
        int c = hist[b];
        base[b] = c ? atomicAdd(&bucket_cnt[b], c) : 0;
    }
    // block-wide exclusive scan of hist -> pref (thread t owns elements 4t..4t+3)
    int loc[4]; int s4 = 0;
#pragma unroll
    for (int j = 0; j < 4; j++) {
        int idx = tid * 4 + j;
        int h = (idx < NBUCK) ? hist[idx] : 0;
        loc[j] = s4; s4 += h;
    }
    psum[tid] = s4;
    __syncthreads();
    for (int off = 1; off < 256; off <<= 1) {
        int t = (tid >= off) ? psum[tid - off] : 0;
        __syncthreads();
        psum[tid] += t;
        __syncthreads();
    }
    int run = psum[tid] - s4;               // exclusive across threads
#pragma unroll
    for (int j = 0; j < 4; j++) {
        int idx = tid * 4 + j;
        if (idx < NBUCK) pref[idx] = run + loc[j];
    }
    __syncthreads();
    // pass 2: re-read (L2-hot) and scatter into bucket-sorted LDS order
#pragma unroll 4
    for (int k = 0; k < 16; k++) {
        int e = e0 + tid + k * 256;
        if (e < N_EDGES) {
            int s = src[e];
            int d = dst[e];
            float wv = w[e];
            int b = d >> 7;
            int p = pref[b] + atomicAdd(&rank[b], 1);
            sorted[p] = make_uint2(((uint)(d & 127) << 17) | (uint)s,
                                   __float_as_uint(wv));
            bid[p] = (ushort)b;
        }
    }
    __syncthreads();
    // run-ordered writeback: consecutive positions -> consecutive global addresses
    int nval = N_EDGES - e0; if (nval > EPB_BIN) nval = EPB_BIN;
    for (int p = tid; p < nval; p += 256) {
        uint2 v = sorted[p];
        int b = (int)bid[p];
        int gpos = base[b] + (p - pref[b]);
        if (gpos < BCAP) {
            ebuf[(size_t)b * BCAP + gpos] = v;
        } else {
            int oi = atomicAdd(spill_cnt, 1);
            if (oi < SPILL_MAX)
                sp[oi] = make_int4((int)(v.x & 0x1FFFF), b * 128 + (int)(v.x >> 17),
                                   (int)v.y, 0);
        }
    }
}

// per-bucket: weighted degree (pass 1), scatter into zero-initialized 32KB LDS
// staging table (pass 2 re-reads the L2-hot bucket), coalesced writeback.
// Also writes dinv and fused y16 = dinv*x fp16 conversion.
__global__ __launch_bounds__(256) void k_sortz(uint2* __restrict__ ebuf,
                                               const int* __restrict__ bucket_cnt,
                                               int4* __restrict__ sp,
                                               int* __restrict__ spill_cnt,
                                               const float* __restrict__ x,
                                               float* __restrict__ dinv,
                                               __half* __restrict__ y16) {
    __shared__ uint  tbl[BNODES * 64];   // 32 KB staging (4B entries, incl. zero pads)
    __shared__ float wacc[BNODES];
    __shared__ int   curs[BNODES];
    int b = blockIdx.x, tid = threadIdx.x;
    int lo = b * BNODES;
    int n = N_NODES - lo; if (n > BNODES) n = BNODES;
    if (tid < BNODES) { wacc[tid] = 0.0f; curs[tid] = 0; }
    {   // zero the staging table (2048 uint4 stores)
        uint4* t4 = (uint4*)tbl;
        for (int i = tid; i < BNODES * 16; i += 256) t4[i] = make_uint4(0, 0, 0, 0);
    }
    __syncthreads();
    int cnt = bucket_cnt[b]; if (cnt > BCAP) cnt = BCAP;
    const uint2* srcrow = ebuf + (size_t)b * BCAP;
    // pass 1: weighted degree
    for (int j = tid; j < cnt; j += 256) {
        uint2 e = srcrow[j];
        atomicAdd(&wacc[e.x >> 17], __uint_as_float(e.y));
    }
    // bucket-overflow spills from k_bin contribute to weighted degree
    int ns0 = *spill_cnt; if (ns0 > SPILL_MAX) ns0 = SPILL_MAX;
    for (int i = tid; i < ns0; i += 256) {
        int4 q = sp[i];
        if ((q.y >> 7) == b) atomicAdd(&wacc[q.y & 127], __int_as_float(q.z));
    }
    __syncthreads();
    // dinv + fused y16 = dinv * x (coalesced, bucket-contiguous)
    if (tid < n) dinv[lo + tid] = rsqrtf(1.0f + wacc[tid]);
    {
        int nl = tid >> 1, half = tid & 1;
        if (nl < n) {
            float di = rsqrtf(1.0f + wacc[nl]);
            const float4* xr = (const float4*)(x + (size_t)(lo + nl) * 16 + half * 8);
            float4 va = xr[0], vb = xr[1];
            __half2 h0 = __floats2half2_rn(di * va.x, di * va.y);
            __half2 h1 = __floats2half2_rn(di * va.z, di * va.w);
            __half2 h2v = __floats2half2_rn(di * vb.x, di * vb.y);
            __half2 h3 = __floats2half2_rn(di * vb.z, di * vb.w);
            uint4* yr = (uint4*)(y16 + (size_t)(lo + nl) * 16 + half * 8);
            yr[0] = make_uint4(as_u32(h0), as_u32(h1), as_u32(h2v), as_u32(h3));
        }
    }
    // pass 2: re-read bucket (L2-hot), scatter into LDS staging
    for (int j = tid; j < cnt; j += 256) {
        uint2 e = srcrow[j];
        int nl = e.x >> 17;
        int pos = atomicAdd(&curs[nl], 1);
        if (pos < 64) {
            uint wh = (uint)__half_as_ushort(__float2half(__uint_as_float(e.y)));
            tbl[nl * 64 + pos] = (wh << 17) | (e.x & 0x1FFFF);
        } else {
            // rare overflow (degree > 64): global spill, handled by gathers
            int oi = atomicAdd(spill_cnt, 1);
            if (oi < SPILL_MAX)
                sp[oi] = make_int4((int)(e.x & 0x1FFFF), lo + nl, (int)e.y, 0);
        }
    }
    __syncthreads();
    // coalesced writeback of the full bucket region (entries + zero pads)
    {
        uint4* o4 = (uint4*)((uint*)ebuf + (size_t)b * (BCAP * 2));
        const uint4* t4 = (const uint4*)tbl;
        for (int i = tid; i < BNODES * 16; i += 256) o4[i] = t4[i];
    }
}

// fused: layer-1 gather (fixed 64-slot rows, 2 nodes/wave, packed fp16) + fp32 self
// + concurrent half-wave MLP. Self-term loads HOISTED to entry (hide under gather).
// o1s uses transposed layout pos=(j<<5)|hl -> conflict-free b32 stores.
// All LDS wave-private -> no __syncthreads (wave64 lockstep).
__global__ __launch_bounds__(256) void k_gather_mlp(const uint* __restrict__ table,
                                                    const int4* __restrict__ sp,
                                                    const int* __restrict__ spill_cnt,
                                                    const float* __restrict__ dinv,
                                                    const __half* __restrict__ y16,
                                                    const float* __restrict__ x,
                                                    const float* __restrict__ W1,
                                                    const float* __restrict__ b1,
                                                    const float* __restrict__ W2,
                                                    const float* __restrict__ b2,
                                                    __half* __restrict__ h2,
                                                    float* __restrict__ out) {
    __shared__ float fvs[8][16];
    __shared__ float o1s[4][2][128];
    int wave = threadIdx.x >> 6, lane = threadIdx.x & 63;
    int nsel = lane >> 5;            // which node of the wave's pair
    int hl   = lane & 31;            // lane within the node's half-wave
    int c2   = lane & 1;             // feature half (8 halfs each)
    int eo   = (lane >> 1) & 15;     // slot group (4 slots each)
    int bid  = blockIdx.x;
    int local = ((bid >> 3) * 4 + wave) * 2 + nsel;  // node index within XCD slab
    int node  = (bid & 7) * NPX + local;
    bool alive = (local < NPX);
    float di = dinv[node];
    int ns = *spill_cnt;                       // hoisted (uniform scalar)
    // hoisted self-term loads: in flight during the whole gather+reduce
    float4 xa = make_float4(0.f, 0.f, 0.f, 0.f), xb = xa;
    if (hl < 2 && alive) {
        const float4* xr = (const float4*)(x + (size_t)node * 16 + c2 * 8);
        xa = xr[0]; xb = xr[1];
    }
    float4 bv = *(const float4*)(b1 + 4 * hl);  // hoisted bias
    const uint* row = table + srow(node);
    uintx4 ev = __builtin_nontemporal_load(reinterpret_cast<const uintx4*>(row + 4 * eo));
    int s0 = ev.x & 0x1FFFF, s1 = ev.y & 0x1FFFF;
    int s2 = ev.z & 0x1FFFF, s3 = ev.w & 0x1FFFF;
    uint4 hv0 = *(const uint4*)(y16 + (size_t)s0 * 16 + c2 * 8);
    uint4 hv1 = *(const uint4*)(y16 + (size_t)s1 * 16 + c2 * 8);
    uint4 hv2 = *(const uint4*)(y16 + (size_t)s2 * 16 + c2 * 8);
    uint4 hv3 = *(const uint4*)(y16 + (size_t)s3 * 16 + c2 * 8);
    __half2 q0 = __half2half2(__ushort_as_half((ushort)(ev.x >> 17)));
    __half2 q1 = __half2half2(__ushort_as_half((ushort)(ev.y >> 17)));
    __half2 q2 = __half2half2(__ushort_as_half((ushort)(ev.z >> 17)));
    __half2 q3 = __half2half2(__ushort_as_half((ushort)(ev.w >> 17)));
    __half2 acc[4];
    acc[0] = __hmul2(q0, as_h2(hv0.x));
    acc[1] = __hmul2(q0, as_h2(hv0.y));
    acc[2] = __hmul2(q0, as_h2(hv0.z));
    acc[3] = __hmul2(q0, as_h2(hv0.w));
    acc[0] = __hfma2(q1, as_h2(hv1.x), acc[0]);
    acc[1] = __hfma2(q1, as_h2(hv1.y), acc[1]);
    acc[2] = __hfma2(q1, as_h2(hv1.z), acc[2]);
    acc[3] = __hfma2(q1, as_h2(hv1.w), acc[3]);
    acc[0] = __hfma2(q2, as_h2(hv2.x), acc[0]);
    acc[1] = __hfma2(q2, as_h2(hv2.y), acc[1]);
    acc[2] = __hfma2(q2, as_h2(hv2.z), acc[2]);
    acc[3] = __hfma2(q2, as_h2(hv2.w), acc[3]);
    acc[0] = __hfma2(q3, as_h2(hv3.x), acc[0]);
    acc[1] = __hfma2(q3, as_h2(hv3.y), acc[1]);
    acc[2] = __hfma2(q3, as_h2(hv3.z), acc[2]);
    acc[3] = __hfma2(q3, as_h2(hv3.w), acc[3]);
    // reduce across 16 slot-groups (lane bits 1..4); stays within 32-lane node half
#pragma unroll
    for (int m = 2; m < 32; m <<= 1) {
#pragma unroll
        for (int k = 0; k < 4; k++)
            acc[k] = __hadd2(acc[k], as_h2(__shfl_xor(as_u32(acc[k]), m, 64)));
    }
    if ((hl < 2) && alive) {
        float accf[8];
#pragma unroll
        for (int k = 0; k < 4; k++) {
            float2 f = __half22float2(acc[k]);
            accf[2 * k + 0] = f.x;
            accf[2 * k + 1] = f.y;
        }
        float slf[8] = {xa.x, xa.y, xa.z, xa.w, xb.x, xb.y, xb.z, xb.w};
        float r[8];
#pragma unroll
        for (int k = 0; k < 8; k++) r[k] = accf[k] + di * slf[k];
        if (ns > 0) {
            int nss = ns > SPILL_MAX ? SPILL_MAX : ns;
            for (int i = 0; i < nss; i++) {
                int4 q = sp[i];
                if (q.y == node) {
                    float f = __int_as_float(q.z);     // raw w; dinv_s already in y16
                    uint4 qv = *(const uint4*)(y16 + (size_t)q.x * 16 + c2 * 8);
                    float2 u0 = __half22float2(as_h2(qv.x));
                    float2 u1 = __half22float2(as_h2(qv.y));
                    float2 u2 = __half22float2(as_h2(qv.z));
                    float2 u3 = __half22float2(as_h2(qv.w));
                    float uv[8] = {u0.x, u0.y, u1.x, u1.y, u2.x, u2.y, u3.x, u3.y};
                    for (int k = 0; k < 8; k++) r[k] += f * uv[k];
                }
            }
        }
#pragma unroll
        for (int k = 0; k < 8; k++) fvs[wave * 2 + nsel][c2 * 8 + k] = r[k] * di;
    }
    // no barrier: fvs[wave*2+nsel] is wave-private, wave64 lockstep
    // MLP: both nodes concurrently; each half-wave owns its node.
    float fv[16];
#pragma unroll
    for (int k = 0; k < 16; k++) fv[k] = fvs[wave * 2 + nsel][k];
    // W1: lane computes hidden outputs o = 4*hl + j
    float a0 = bv.x, a1 = bv.y, a2 = bv.z, a3 = bv.w;
#pragma unroll
    for (int k = 0; k < 16; k++) {
        float4 wv = *(const float4*)(W1 + k * 128 + 4 * hl);
        a0 = fmaf(fv[k], wv.x, a0);
        a1 = fmaf(fv[k], wv.y, a1);
        a2 = fmaf(fv[k], wv.z, a2);
        a3 = fmaf(fv[k], wv.w, a3);
    }
    // transposed store: pos(o) = ((o&3)<<5) | (o>>2) = (j<<5)|hl  -> conflict-free
    float* o1p = &o1s[wave][nsel][0];     // wave-private
    o1p[(0 << 5) | hl] = fmaxf(a0, 0.0f);
    o1p[(1 << 5) | hl] = fmaxf(a1, 0.0f);
    o1p[(2 << 5) | hl] = fmaxf(a2, 0.0f);
    o1p[(3 << 5) | hl] = fmaxf(a3, 0.0f);
    // W2: output c = hl&15, K-half g = hl>>4 (2 lanes per output)
    int c = hl & 15, g = hl >> 4;
    float p = 0.0f;
#pragma unroll
    for (int k = 0; k < 64; k++) {
        int kk = g * 64 + k;
        p = fmaf(o1p[((kk & 3) << 5) | (kk >> 2)], W2[kk * 16 + c], p);
    }
    p += __shfl_down(p, 16, 64);          // combine the two K-halves (stays in node half)
    if (hl < 16 && alive) {
        h2[(size_t)node * 16 + c] = __float2half(di * p);   // pre-scaled by dinv_s
        out[(size_t)node * 16 + c] = di * di * p + b2[c];
    }
}

// layer-2 gather: out[node] += di * sum w*h2[s] (+spill); h2 pre-scaled by dinv_s.
// out RMW loads HOISTED to entry (hide the dependent tail under gather+reduce).
__global__ __launch_bounds__(256) void k_gather2(const uint* __restrict__ table,
                                                 const int4* __restrict__ sp,
                                                 const int* __restrict__ spill_cnt,
                                                 const float* __restrict__ dinv,
                                                 const __half* __restrict__ h2,
                                                 float* __restrict__ out) {
    int wave = threadIdx.x >> 6, lane = threadIdx.x & 63;
    int nsel = lane >> 5;
    int hl   = lane & 31;
    int c2   = lane & 1;
    int eo   = (lane >> 1) & 15;
    int bid  = blockIdx.x;
    int local = ((bid >> 3) * 4 + wave) * 2 + nsel;
    int node  = (bid & 7) * NPX + local;
    bool alive = (local < NPX);
    float di = dinv[node];
    int ns = *spill_cnt;                       // hoisted (uniform scalar)
    // hoisted out RMW loads: in flight during the whole gather+reduce
    float4 o0 = make_float4(0.f, 0.f, 0.f, 0.f), o1 = o0;
    float4* op = (float4*)(out + (size_t)node * 16 + c2 * 8);
    if (hl < 2 && alive) { o0 = op[0]; o1 = op[1]; }
    const uint* row = table + srow(node);
    uintx4 ev = __builtin_nontemporal_load(reinterpret_cast<const uintx4*>(row + 4 * eo));
    int s0 = ev.x & 0x1FFFF, s1 = ev.y & 0x1FFFF;
    int s2 = ev.z & 0x1FFFF, s3 = ev.w & 0x1FFFF;
    uint4 hv0 = *(const uint4*)(h2 + (size_t)s0 * 16 + c2 * 8);
    uint4 hv1 = *(const uint4*)(h2 + (size_t)s1 * 16 + c2 * 8);
    uint4 hv2 = *(const uint4*)(h2 + (size_t)s2 * 16 + c2 * 8);
    uint4 hv3 = *(const uint4*)(h2 + (size_t)s3 * 16 + c2 * 8);
    __half2 q0 = __half2half2(__ushort_as_half((ushort)(ev.x >> 17)));
    __half2 q1 = __half2half2(__ushort_as_half((ushort)(ev.y >> 17)));
    __half2 q2 = __half2half2(__ushort_as_half((ushort)(ev.z >> 17)));
    __half2 q3 = __half2half2(__ushort_as_half((ushort)(ev.w >> 17)));
    __half2 acc[4];
    acc[0] = __hmul2(q0, as_h2(hv0.x));
    acc[1] = __hmul2(q0, as_h2(hv0.y));
    acc[2] = __hmul2(q0, as_h2(hv0.z));
    acc[3] = __hmul2(q0, as_h2(hv0.w));
    acc[0] = __hfma2(q1, as_h2(hv1.x), acc[0]);
    acc[1] = __hfma2(q1, as_h2(hv1.y), acc[1]);
    acc[2] = __hfma2(q1, as_h2(hv1.z), acc[2]);
    acc[3] = __hfma2(q1, as_h2(hv1.w), acc[3]);
    acc[0] = __hfma2(q2, as_h2(hv2.x), acc[0]);
    acc[1] = __hfma2(q2, as_h2(hv2.y), acc[1]);
    acc[2] = __hfma2(q2, as_h2(hv2.z), acc[2]);
    acc[3] = __hfma2(q2, as_h2(hv2.w), acc[3]);
    acc[0] = __hfma2(q3, as_h2(hv3.x), acc[0]);
    acc[1] = __hfma2(q3, as_h2(hv3.y), acc[1]);
    acc[2] = __hfma2(q3, as_h2(hv3.z), acc[2]);
    acc[3] = __hfma2(q3, as_h2(hv3.w), acc[3]);
#pragma unroll
    for (int m = 2; m < 32; m <<= 1) {
#pragma unroll
        for (int k = 0; k < 4; k++)
            acc[k] = __hadd2(acc[k], as_h2(__shfl_xor(as_u32(acc[k]), m, 64)));
    }
    if ((hl < 2) && alive) {
        float accf[8];
#pragma unroll
        for (int k = 0; k < 4; k++) {
            float2 f = __half22float2(acc[k]);
            accf[2 * k + 0] = f.x;
            accf[2 * k + 1] = f.y;
        }
        if (ns > 0) {
            int nss = ns > SPILL_MAX ? SPILL_MAX : ns;
            for (int i = 0; i < nss; i++) {
                int4 q = sp[i];
                if (q.y == node) {
                    float f = __int_as_float(q.z);
                    uint4 qv = *(const uint4*)(h2 + (size_t)q.x * 16 + c2 * 8);
                    float2 u0 = __half22float2(as_h2(qv.x));
                    float2 u1 = __half22float2(as_h2(qv.y));
                    float2 u2 = __half22float2(as_h2(qv.z));
                    float2 u3 = __half22float2(as_h2(qv.w));
                    float uv[8] = {u0.x, u0.y, u1.x, u1.y, u2.x, u2.y, u3.x, u3.y};
                    for (int k = 0; k < 8; k++) accf[k] += f * uv[k];
                }
            }
        }
        o0.x += di * accf[0]; o0.y += di * accf[1];
        o0.z += di * accf[2]; o0.w += di * accf[3];
        o1.x += di * accf[4]; o1.y += di * accf[5];
        o1.z += di * accf[6]; o1.w += di * accf[7];
        op[0] = o0; op[1] = o1;
    }
}

// ===================== CSR fallback (round-2) =====================

__global__ void k_init(float* __restrict__ deg, int* __restrict__ cnt) {
    int i = blockIdx.x * blockDim.x + threadIdx.x;
    if (i < N_NODES) { deg[i] = 1.0f; if (cnt) cnt[i] = 0; }
}

__global__ void k_degcnt(const int* __restrict__ dst, const float* __restrict__ w,
                         float* __restrict__ deg, int* __restrict__ cnt) {
    int e = blockIdx.x * blockDim.x + threadIdx.x;
    if (e < N_EDGES) {
        int d = dst[e];
        atomicAdd(&deg[d], w[e]);
        if (cnt) atomicAdd(&cnt[d], 1);
    }
}

__global__ void k_dinv_agg(const float* __restrict__ x, float* __restrict__ deg_dinv,
                           float* __restrict__ agg) {
    int i = blockIdx.x * blockDim.x + threadIdx.x;
    if (i >= N_NODES) return;
    float di = rsqrtf(deg_dinv[i]);
    deg_dinv[i] = di;
    float s = di * di;
    const float4* xr = (const float4*)(x + (size_t)i * 16);
    float4* ar = (float4*)(agg + (size_t)i * 16);
#pragma unroll
    for (int k = 0; k < 4; k++) {
        float4 v = xr[k];
        v.x *= s; v.y *= s; v.z *= s; v.w *= s;
        ar[k] = v;
    }
}

__global__ __launch_bounds__(256) void k_scan1(const int* __restrict__ cnt,
                                               int* __restrict__ rowptr,
                                               int* __restrict__ bsum) {
    __shared__ int ts[256];
    int tid = threadIdx.x;
    int base = blockIdx.x * SCAN_CHUNK + tid * 8;
    int v[8]; int s = 0;
#pragma unroll
    for (int k = 0; k < 8; k++) {
        int idx = base + k;
        v[k] = (idx < N_NODES) ? cnt[idx] : 0;
        s += v[k];
    }
    ts[tid] = s;
    __syncthreads();
    for (int off = 1; off < 256; off <<= 1) {
        int t = (tid >= off) ? ts[tid - off] : 0;
        __syncthreads();
        ts[tid] += t;
        __syncthreads();
    }
    int run = ts[tid] - s;
#pragma unroll
    for (int k = 0; k < 8; k++) {
        int idx = base + k;
        if (idx < N_NODES) rowptr[idx] = run;
        run += v[k];
    }
    if (tid == 255) bsum[blockIdx.x] = ts[255];
}

__global__ void k_scan2(int* __restrict__ bsum) {
    if (threadIdx.x == 0 && blockIdx.x == 0) {
        int run = 0;
        for (int g = 0; g < SCAN_BLOCKS; g++) { int t = bsum[g]; bsum[g] = run; run += t; }
    }
}

__global__ __launch_bounds__(256) void k_scan3(int* __restrict__ rowptr,
                                               const int* __restrict__ bsum) {
    int tid = threadIdx.x;
    int base = blockIdx.x * SCAN_CHUNK + tid * 8;
    int off = bsum[blockIdx.x];
#pragma unroll
    for (int k = 0; k < 8; k++) {
        int idx = base + k;
        if (idx < N_NODES) rowptr[idx] += off;
    }
    if (blockIdx.x == 0 && tid == 0) rowptr[N_NODES] = N_EDGES;
}

__global__ void k_fill(const int* __restrict__ src, const int* __restrict__ dst,
                       const float* __restrict__ w, const float* __restrict__ dinv,
                       const int* __restrict__ rowptr, int* __restrict__ cnt,
                       int2* __restrict__ perm) {
    int e = blockIdx.x * blockDim.x + threadIdx.x;
    if (e >= N_EDGES) return;
    int s = src[e], d = dst[e];
    float nrm = dinv[s] * w[e] * dinv[d];
    int r = atomicSub(&cnt[d], 1) - 1;
    int pos = rowptr[d] + r;
    perm[pos] = make_int2(s, __float_as_int(nrm));
}

__global__ __launch_bounds__(256) void k_gather(const int2* __restrict__ perm,
                                                const int* __restrict__ rowptr,
                                                const float* __restrict__ feat,
                                                float* __restrict__ out) {
    int wave = threadIdx.x >> 6, lane = threadIdx.x & 63;
    int node = blockIdx.x * 4 + wave;
    int c = lane & 15, eo = lane >> 4;
    int beg = rowptr[node], end = rowptr[node + 1];
    float acc = 0.0f;
    for (int j = beg + eo; j < end; j += 4) {
        int2 ed = perm[j];
        acc = fmaf(__int_as_float(ed.y), feat[(size_t)ed.x * 16 + c], acc);
    }
    acc += __shfl_xor(acc, 16, 64);
    acc += __shfl_xor(acc, 32, 64);
    if (lane < 16) out[(size_t)node * 16 + c] += acc;
}

__global__ __launch_bounds__(256) void k_mlp(float* __restrict__ agg,
                                             const float* __restrict__ W1,
                                             const float* __restrict__ b1,
                                             const float* __restrict__ W2,
                                             const float* __restrict__ b2,
                                             const float* __restrict__ dinv,
                                             float* __restrict__ out) {
    __shared__ float o1s[4][128];
    int wave = threadIdx.x >> 6;
    int lane = threadIdx.x & 63;
    int node = blockIdx.x * 4 + wave;
    const float* f = agg + (size_t)node * 16;
    float fv[16];
#pragma unroll
    for (int k = 0; k < 4; k++) {
        float4 v = ((const float4*)f)[k];
        fv[4 * k + 0] = v.x; fv[4 * k + 1] = v.y; fv[4 * k + 2] = v.z; fv[4 * k + 3] = v.w;
    }
    float a = b1[2 * lane], b = b1[2 * lane + 1];
#pragma unroll
    for (int k = 0; k < 16; k++) {
        float2 wv = *(const float2*)(W1 + k * 128 + 2 * lane);
        a = fmaf(fv[k], wv.x, a);
        b = fmaf(fv[k], wv.y, b);
    }
    o1s[wave][2 * lane + 0] = fmaxf(a, 0.0f);
    o1s[wave][2 * lane + 1] = fmaxf(b, 0.0f);
    __syncthreads();
    int c = lane & 15, g = lane >> 4;
    float p = 0.0f;
#pragma unroll
    for (int k = 0; k < 32; k++) {
        int kk = g * 32 + k;
        p = fmaf(o1s[wave][kk], W2[kk * 16 + c], p);
    }
    p += __shfl_down(p, 16, 64);
    p += __shfl_down(p, 32, 64);
    __syncthreads();
    if (lane < 16) {
        float h2v = p;
        agg[(size_t)node * 16 + c] = h2v;
        float di = dinv[node];
        out[(size_t)node * 16 + c] = di * di * h2v + b2[c];
    }
}

__global__ void k_scatter(const int* __restrict__ src, const int* __restrict__ dst,
                          const float* __restrict__ w, const float* __restrict__ dinv,
                          const float* __restrict__ feat, float* __restrict__ out) {
    int t = blockIdx.x * blockDim.x + threadIdx.x;
    int e = t >> 2;
    int c4 = (t & 3) * 4;
    if (e >= N_EDGES) return;
    int s = src[e], d = dst[e];
    float nrm = dinv[s] * w[e] * dinv[d];
    float4 v = *(const float4*)(feat + (size_t)s * 16 + c4);
    float* o = out + (size_t)d * 16 + c4;
    atomicAdd(o + 0, nrm * v.x);
    atomicAdd(o + 1, nrm * v.y);
    atomicAdd(o + 2, nrm * v.z);
    atomicAdd(o + 3, nrm * v.w);
}

// ===================== launch =====================

extern "C" void kernel_launch(void* const* d_in, const int* in_sizes, int n_in,
                              void* d_out, int out_size, void* d_ws, size_t ws_size,
                              hipStream_t stream) {
    const float* x  = (const float*)d_in[0];
    const int*   ei = (const int*)d_in[1];
    const float* w  = (const float*)d_in[2];
    const float* W1 = (const float*)d_in[3];
    const float* b1 = (const float*)d_in[4];
    const float* W2 = (const float*)d_in[5];
    const float* b2 = (const float*)d_in[6];
    float* out = (float*)d_out;

    const int* src = ei;
    const int* dst = ei + N_EDGES;
    const int B = 256;

    // ---- fast-path workspace layout (16B-aligned blocks) ----
    char* p = (char*)d_ws;
    int*    bucket_cnt = (int*)p;        p += (size_t)((NBUCK + 3) & ~3) * 4;
    int*    spill_cnt  = (int*)p;        p += 16;
    float*  dinv       = (float*)p;      p += (size_t)N_PAD * 4;
    __half* y16        = (__half*)p;     p += (size_t)N_NODES * 16 * 2;
    __half* h2         = (__half*)p;     p += (size_t)N_NODES * 16 * 2;
    int4*   sp         = (int4*)p;       p += (size_t)SPILL_MAX * 16;
    uint2*  ebuf       = (uint2*)p;      p += (size_t)NBUCK * BCAP * 8;
    const size_t WS_FAST = (size_t)(p - (char*)d_ws);

    if (ws_size >= WS_FAST) {
        k_pre0<<<(NBUCK + B - 1) / B, B, 0, stream>>>(bucket_cnt, spill_cnt);
        k_bin<<<BIN_BLOCKS, B, 0, stream>>>(src, dst, w, bucket_cnt, ebuf, sp, spill_cnt);
        k_sortz<<<NBUCK, B, 0, stream>>>(ebuf, bucket_cnt, sp, spill_cnt, x, dinv, y16);
        k_gather_mlp<<<GBLK, B, 0, stream>>>((const uint*)ebuf, sp, spill_cnt, dinv,
                                             y16, x, W1, b1, W2, b2, h2, out);
        k_gather2<<<GBLK, B, 0, stream>>>((const uint*)ebuf, sp, spill_cnt, dinv,
                                          h2, out);
        return;
    }

    // ---- CSR fallback (round-2 path) ----
    float* deg_dinv = (float*)d_ws;
    int*   cntb     = (int*)(deg_dinv + N_PAD);
    int*   rowptr   = cntb + N_PAD;
    int*   bsum     = rowptr + N_PAD;
    float* agg      = (float*)(bsum + 64);
    int2*  perm     = (int2*)(agg + (size_t)N_NODES * 16);
    const size_t WS_CSR = ((size_t)N_PAD * 3 + 64 + (size_t)N_NODES * 16) * 4
                          + (size_t)N_EDGES * 8;

    if (ws_size >= WS_CSR) {
        k_init<<<(N_NODES + B - 1) / B, B, 0, stream>>>(deg_dinv, cntb);
        k_degcnt<<<(N_EDGES + B - 1) / B, B, 0, stream>>>(dst, w, deg_dinv, cntb);
        k_dinv_agg<<<(N_NODES + B - 1) / B, B, 0, stream>>>(x, deg_dinv, agg);
        k_scan1<<<SCAN_BLOCKS, 256, 0, stream>>>(cntb, rowptr, bsum);
        k_scan2<<<1, 64, 0, stream>>>(bsum);
        k_scan3<<<SCAN_BLOCKS, 256, 0, stream>>>(rowptr, bsum);
        k_fill<<<(N_EDGES + B - 1) / B, B, 0, stream>>>(src, dst, w, deg_dinv,
                                                        rowptr, cntb, perm);
        k_gather<<<N_NODES / 4, B, 0, stream>>>(perm, rowptr, x, agg);
        k_mlp<<<N_NODES / 4, B, 0, stream>>>(agg, W1, b1, W2, b2, deg_dinv, out);
        k_gather<<<N_NODES / 4, B, 0, stream>>>(perm, rowptr, agg, out);
    } else {
        float* deg = (float*)d_ws;
        float* ag  = (float*)d_ws + N_NODES;
        k_init<<<(N_NODES + B - 1) / B, B, 0, stream>>>(deg, (int*)nullptr);
        k_degcnt<<<(N_EDGES + B - 1) / B, B, 0, stream>>>(dst, w, deg, (int*)nullptr);
        k_dinv_agg<<<(N_NODES + B - 1) / B, B, 0, stream>>>(x, deg, ag);
        k_scatter<<<((size_t)N_EDGES * 4 + B - 1) / B, B, 0, stream>>>(src, dst, w, deg, x, ag);
        k_mlp<<<N_NODES / 4, B, 0, stream>>>(ag, W1, b1, W2, b2, deg, out);
        k_scatter<<<((size_t)N_EDGES * 4 + B - 1) / B, B, 0, stream>>>(src, dst, w, deg, ag, out);
    }
}

// Round 12
// 238.997 us; speedup vs baseline: 1.0860x; 1.0860x over previous
//
#include <hip/hip_runtime.h>
#include <hip/hip_fp16.h>

#define N_NODES 100000
#define N_EDGES 3200000
#define N_PAD   100096
#define BNODES  128
#define NBUCK   ((N_NODES + BNODES - 1) / BNODES)       // 782
#define BCAP    4800                                    // mean 4096, sigma 64 (11 sigma)
#define EPB_BIN 4096                                    // edges per bin block (16/thread)
#define BIN_BLOCKS ((N_EDGES + EPB_BIN - 1) / EPB_BIN)  // 782
#define SPILL_MAX 65536
#define NPX      (N_NODES / 8)                          // 12500 nodes per XCD slab
#define GBLK     (8 * ((NPX + 7) / 8))                  // 12504 gather blocks (8 nodes each)
#define SCAN_CHUNK 2048
#define SCAN_BLOCKS ((N_NODES + SCAN_CHUNK - 1) / SCAN_CHUNK)

typedef unsigned int uint;
typedef unsigned short ushort;
typedef unsigned long long ull;
typedef uint uintx4 __attribute__((ext_vector_type(4)));   // native vector for nontemporal builtin

__device__ __forceinline__ __half2 as_h2(uint u) { return *reinterpret_cast<__half2*>(&u); }
__device__ __forceinline__ uint as_u32(__half2 h) { return *reinterpret_cast<uint*>(&h); }

// fixed-stride row address inside the bucket region (bucket stride BCAP*2 uints)
__device__ __forceinline__ size_t srow(int n) {
    return (size_t)(n >> 7) * (BCAP * 2) + (size_t)(n & 127) * 64;
}

// ===================== fast path: pre0 -> bin -> sortz -> gather =====================

// zero bucket_cnt + spill_cnt only
__global__ __launch_bounds__(256) void k_pre0(int* __restrict__ bucket_cnt,
                                              int* __restrict__ spill_cnt) {
    int i = blockIdx.x * 256 + threadIdx.x;
    if (i < NBUCK) bucket_cnt[i] = 0;
    if (i == 0) *spill_cnt = 0;
}

// counting-sort edges into 782 dst-buckets. Block-local LDS sort first, then
// RUN-ORDERED writeback: a wave's 64 stores span ~12 contiguous runs instead of
// 64 scattered lines (cross-XCD partial-line write amplification was k_bin's cost).
__global__ __launch_bounds__(256) void k_bin(const int* __restrict__ src,
                                             const int* __restrict__ dst,
                                             const float* __restrict__ w,
                                             int* __restrict__ bucket_cnt,
                                             uint2* __restrict__ ebuf,
                                             int4* __restrict__ sp,
                                             int* __restrict__ spill_cnt) {
    __shared__ int   hist[NBUCK];          // 3.1 KB
    __shared__ int   base[NBUCK];          // 3.1 KB  global run start for this block
    __shared__ int   pref[NBUCK];          // 3.1 KB  block-local exclusive prefix
    __shared__ int   rank[NBUCK];          // 3.1 KB
    __shared__ int   psum[256];            // 1 KB
    __shared__ uint2 sorted[EPB_BIN];      // 32 KB   bucket-sorted entries
    __shared__ ushort bid[EPB_BIN];        // 8 KB    bucket id per position
    int tid = threadIdx.x;
    for (int b = tid; b < NBUCK; b += 256) { hist[b] = 0; rank[b] = 0; }
    __syncthreads();
    int e0 = blockIdx.x * EPB_BIN;
    // pass 1: histogram (plain loads -> window stays L2-hot for pass 2)
#pragma unroll 4
    for (int k = 0; k < 16; k++) {
        int e = e0 + tid + k * 256;
        if (e < N_EDGES) atomicAdd(&hist[dst[e] >> 7], 1);
    }
    __syncthreads();
    // reserve global bases
    for (int b = tid; b < NBUCK; b += 256) {
        int c = hist[b];
        base[b] = c ? atomicAdd(&bucket_cnt[b], c) : 0;
    }
    // block-wide exclusive scan of hist -> pref (thread t owns elements 4t..4t+3)
    int loc[4]; int s4 = 0;
#pragma unroll
    for (int j = 0; j < 4; j++) {
        int idx = tid * 4 + j;
        int h = (idx < NBUCK) ? hist[idx] : 0;
        loc[j] = s4; s4 += h;
    }
    psum[tid] = s4;
    __syncthreads();
    for (int off = 1; off < 256; off <<= 1) {
        int t = (tid >= off) ? psum[tid - off] : 0;
        __syncthreads();
        psum[tid] += t;
        __syncthreads();
    }
    int run = psum[tid] - s4;               // exclusive across threads
#pragma unroll
    for (int j = 0; j < 4; j++) {
        int idx = tid * 4 + j;
        if (idx < NBUCK) pref[idx] = run + loc[j];
    }
    __syncthreads();
    // pass 2: re-read (L2-hot) and scatter into bucket-sorted LDS order
#pragma unroll 4
    for (int k = 0; k < 16; k++) {
        int e = e0 + tid + k * 256;
        if (e < N_EDGES) {
            int s = src[e];
            int d = dst[e];
            float wv = w[e];
            int b = d >> 7;
            int p = pref[b] + atomicAdd(&rank[b], 1);
            sorted[p] = make_uint2(((uint)(d & 127) << 17) | (uint)s,
                                   __float_as_uint(wv));
            bid[p] = (ushort)b;
        }
    }
    __syncthreads();
    // run-ordered writeback: consecutive positions -> consecutive global addresses
    int nval = N_EDGES - e0; if (nval > EPB_BIN) nval = EPB_BIN;
    for (int p = tid; p < nval; p += 256) {
        uint2 v = sorted[p];
        int b = (int)bid[p];
        int gpos = base[b] + (p - pref[b]);
        if (gpos < BCAP) {
            ebuf[(size_t)b * BCAP + gpos] = v;
        } else {
            int oi = atomicAdd(spill_cnt, 1);
            if (oi < SPILL_MAX)
                sp[oi] = make_int4((int)(v.x & 0x1FFFF), b * 128 + (int)(v.x >> 17),
                                   (int)v.y, 0);
        }
    }
}

// per-bucket: weighted degree (pass 1), scatter into zero-initialized 32KB LDS
// staging table (pass 2 re-reads the L2-hot bucket), coalesced writeback.
// Also writes dinv and fused y16 = dinv*x fp16 conversion.
__global__ __launch_bounds__(256) void k_sortz(uint2* __restrict__ ebuf,
                                               const int* __restrict__ bucket_cnt,
                                               int4* __restrict__ sp,
                                               int* __restrict__ spill_cnt,
                                               const float* __restrict__ x,
                                               float* __restrict__ dinv,
                                               __half* __restrict__ y16) {
    __shared__ uint  tbl[BNODES * 64];   // 32 KB staging (4B entries, incl. zero pads)
    __shared__ float wacc[BNODES];
    __shared__ int   curs[BNODES];
    int b = blockIdx.x, tid = threadIdx.x;
    int lo = b * BNODES;
    int n = N_NODES - lo; if (n > BNODES) n = BNODES;
    if (tid < BNODES) { wacc[tid] = 0.0f; curs[tid] = 0; }
    {   // zero the staging table (2048 uint4 stores)
        uint4* t4 = (uint4*)tbl;
        for (int i = tid; i < BNODES * 16; i += 256) t4[i] = make_uint4(0, 0, 0, 0);
    }
    __syncthreads();
    int cnt = bucket_cnt[b]; if (cnt > BCAP) cnt = BCAP;
    const uint2* srcrow = ebuf + (size_t)b * BCAP;
    // pass 1: weighted degree
    for (int j = tid; j < cnt; j += 256) {
        uint2 e = srcrow[j];
        atomicAdd(&wacc[e.x >> 17], __uint_as_float(e.y));
    }
    // bucket-overflow spills from k_bin contribute to weighted degree
    int ns0 = *spill_cnt; if (ns0 > SPILL_MAX) ns0 = SPILL_MAX;
    for (int i = tid; i < ns0; i += 256) {
        int4 q = sp[i];
        if ((q.y >> 7) == b) atomicAdd(&wacc[q.y & 127], __int_as_float(q.z));
    }
    __syncthreads();
    // dinv + fused y16 = dinv * x (coalesced, bucket-contiguous)
    if (tid < n) dinv[lo + tid] = rsqrtf(1.0f + wacc[tid]);
    {
        int nl = tid >> 1, half = tid & 1;
        if (nl < n) {
            float di = rsqrtf(1.0f + wacc[nl]);
            const float4* xr = (const float4*)(x + (size_t)(lo + nl) * 16 + half * 8);
            float4 va = xr[0], vb = xr[1];
            __half2 h0 = __floats2half2_rn(di * va.x, di * va.y);
            __half2 h1 = __floats2half2_rn(di * va.z, di * va.w);
            __half2 h2v = __floats2half2_rn(di * vb.x, di * vb.y);
            __half2 h3 = __floats2half2_rn(di * vb.z, di * vb.w);
            uint4* yr = (uint4*)(y16 + (size_t)(lo + nl) * 16 + half * 8);
            yr[0] = make_uint4(as_u32(h0), as_u32(h1), as_u32(h2v), as_u32(h3));
        }
    }
    // pass 2: re-read bucket (L2-hot), scatter into LDS staging
    for (int j = tid; j < cnt; j += 256) {
        uint2 e = srcrow[j];
        int nl = e.x >> 17;
        int pos = atomicAdd(&curs[nl], 1);
        if (pos < 64) {
            uint wh = (uint)__half_as_ushort(__float2half(__uint_as_float(e.y)));
            tbl[nl * 64 + pos] = (wh << 17) | (e.x & 0x1FFFF);
        } else {
            // rare overflow (degree > 64): global spill, handled by gathers
            int oi = atomicAdd(spill_cnt, 1);
            if (oi < SPILL_MAX)
                sp[oi] = make_int4((int)(e.x & 0x1FFFF), lo + nl, (int)e.y, 0);
        }
    }
    __syncthreads();
    // coalesced writeback of the full bucket region (entries + zero pads)
    {
        uint4* o4 = (uint4*)((uint*)ebuf + (size_t)b * (BCAP * 2));
        const uint4* t4 = (const uint4*)tbl;
        for (int i = tid; i < BNODES * 16; i += 256) o4[i] = t4[i];
    }
}

// fused: layer-1 gather (fixed 64-slot rows, 2 nodes/wave, packed fp16) + fp32 self
// + concurrent half-wave MLP with LDS-staged weights:
//   W1s (8KB, natural) and W2T (8KB, transposed, row stride 132) staged once per
//   block with ONE entry barrier -> W2 inner loop = 16x{2 ds_read_b128 + 4 fma}
//   instead of 64 scalar global loads + 64 scalar LDS reads.
__global__ __launch_bounds__(256) void k_gather_mlp(const uint* __restrict__ table,
                                                    const int4* __restrict__ sp,
                                                    const int* __restrict__ spill_cnt,
                                                    const float* __restrict__ dinv,
                                                    const __half* __restrict__ y16,
                                                    const float* __restrict__ x,
                                                    const float* __restrict__ W1,
                                                    const float* __restrict__ b1,
                                                    const float* __restrict__ W2,
                                                    const float* __restrict__ b2,
                                                    __half* __restrict__ h2,
                                                    float* __restrict__ out) {
    __shared__ float W1s[16 * 128];       // 8 KB, natural layout
    __shared__ float W2T[16 * 132];       // 8.25 KB, transposed, +4 pad per row
    __shared__ float fvs[8][16];
    __shared__ float o1s[4][2][128];      // natural layout (conflicts proven harmless)
    int wave = threadIdx.x >> 6, lane = threadIdx.x & 63;
    int tid = threadIdx.x;
    // stage weights once per block (coalesced reads; LDS scatter for transpose)
    {
        const float4* w1g = (const float4*)W1;
        float4* w1l = (float4*)W1s;
        for (int i = tid; i < 512; i += 256) w1l[i] = w1g[i];
        for (int j = tid; j < 2048; j += 256) {
            int kk = j >> 4, c = j & 15;
            W2T[c * 132 + kk] = W2[j];
        }
    }
    __syncthreads();                       // only barrier in the kernel
    int nsel = lane >> 5;            // which node of the wave's pair
    int hl   = lane & 31;            // lane within the node's half-wave
    int c2   = lane & 1;             // feature half (8 halfs each)
    int eo   = (lane >> 1) & 15;     // slot group (4 slots each)
    int bid  = blockIdx.x;
    int local = ((bid >> 3) * 4 + wave) * 2 + nsel;  // node index within XCD slab
    int node  = (bid & 7) * NPX + local;
    bool alive = (local < NPX);
    float di = dinv[node];
    int ns = *spill_cnt;                       // hoisted (uniform scalar)
    // hoisted self-term loads: in flight during the whole gather+reduce
    float4 xa = make_float4(0.f, 0.f, 0.f, 0.f), xb = xa;
    if (hl < 2 && alive) {
        const float4* xr = (const float4*)(x + (size_t)node * 16 + c2 * 8);
        xa = xr[0]; xb = xr[1];
    }
    float4 bv = *(const float4*)(b1 + 4 * hl);  // hoisted bias
    const uint* row = table + srow(node);
    uintx4 ev = __builtin_nontemporal_load(reinterpret_cast<const uintx4*>(row + 4 * eo));
    int s0 = ev.x & 0x1FFFF, s1 = ev.y & 0x1FFFF;
    int s2 = ev.z & 0x1FFFF, s3 = ev.w & 0x1FFFF;
    uint4 hv0 = *(const uint4*)(y16 + (size_t)s0 * 16 + c2 * 8);
    uint4 hv1 = *(const uint4*)(y16 + (size_t)s1 * 16 + c2 * 8);
    uint4 hv2 = *(const uint4*)(y16 + (size_t)s2 * 16 + c2 * 8);
    uint4 hv3 = *(const uint4*)(y16 + (size_t)s3 * 16 + c2 * 8);
    __half2 q0 = __half2half2(__ushort_as_half((ushort)(ev.x >> 17)));
    __half2 q1 = __half2half2(__ushort_as_half((ushort)(ev.y >> 17)));
    __half2 q2 = __half2half2(__ushort_as_half((ushort)(ev.z >> 17)));
    __half2 q3 = __half2half2(__ushort_as_half((ushort)(ev.w >> 17)));
    __half2 acc[4];
    acc[0] = __hmul2(q0, as_h2(hv0.x));
    acc[1] = __hmul2(q0, as_h2(hv0.y));
    acc[2] = __hmul2(q0, as_h2(hv0.z));
    acc[3] = __hmul2(q0, as_h2(hv0.w));
    acc[0] = __hfma2(q1, as_h2(hv1.x), acc[0]);
    acc[1] = __hfma2(q1, as_h2(hv1.y), acc[1]);
    acc[2] = __hfma2(q1, as_h2(hv1.z), acc[2]);
    acc[3] = __hfma2(q1, as_h2(hv1.w), acc[3]);
    acc[0] = __hfma2(q2, as_h2(hv2.x), acc[0]);
    acc[1] = __hfma2(q2, as_h2(hv2.y), acc[1]);
    acc[2] = __hfma2(q2, as_h2(hv2.z), acc[2]);
    acc[3] = __hfma2(q2, as_h2(hv2.w), acc[3]);
    acc[0] = __hfma2(q3, as_h2(hv3.x), acc[0]);
    acc[1] = __hfma2(q3, as_h2(hv3.y), acc[1]);
    acc[2] = __hfma2(q3, as_h2(hv3.z), acc[2]);
    acc[3] = __hfma2(q3, as_h2(hv3.w), acc[3]);
    // reduce across 16 slot-groups (lane bits 1..4); stays within 32-lane node half
#pragma unroll
    for (int m = 2; m < 32; m <<= 1) {
#pragma unroll
        for (int k = 0; k < 4; k++)
            acc[k] = __hadd2(acc[k], as_h2(__shfl_xor(as_u32(acc[k]), m, 64)));
    }
    if ((hl < 2) && alive) {
        float accf[8];
#pragma unroll
        for (int k = 0; k < 4; k++) {
            float2 f = __half22float2(acc[k]);
            accf[2 * k + 0] = f.x;
            accf[2 * k + 1] = f.y;
        }
        float slf[8] = {xa.x, xa.y, xa.z, xa.w, xb.x, xb.y, xb.z, xb.w};
        float r[8];
#pragma unroll
        for (int k = 0; k < 8; k++) r[k] = accf[k] + di * slf[k];
        if (ns > 0) {
            int nss = ns > SPILL_MAX ? SPILL_MAX : ns;
            for (int i = 0; i < nss; i++) {
                int4 q = sp[i];
                if (q.y == node) {
                    float f = __int_as_float(q.z);     // raw w; dinv_s already in y16
                    uint4 qv = *(const uint4*)(y16 + (size_t)q.x * 16 + c2 * 8);
                    float2 u0 = __half22float2(as_h2(qv.x));
                    float2 u1 = __half22float2(as_h2(qv.y));
                    float2 u2 = __half22float2(as_h2(qv.z));
                    float2 u3 = __half22float2(as_h2(qv.w));
                    float uv[8] = {u0.x, u0.y, u1.x, u1.y, u2.x, u2.y, u3.x, u3.y};
                    for (int k = 0; k < 8; k++) r[k] += f * uv[k];
                }
            }
        }
#pragma unroll
        for (int k = 0; k < 8; k++) fvs[wave * 2 + nsel][c2 * 8 + k] = r[k] * di;
    }
    // no barrier: fvs[wave*2+nsel] is wave-private, wave64 lockstep
    // MLP: both nodes concurrently; each half-wave owns its node.
    float fv[16];
#pragma unroll
    for (int k = 0; k < 16; k++) fv[k] = fvs[wave * 2 + nsel][k];
    // W1 from LDS: lane computes hidden outputs o = 4*hl + j
    float a0 = bv.x, a1 = bv.y, a2 = bv.z, a3 = bv.w;
#pragma unroll
    for (int k = 0; k < 16; k++) {
        float4 wv = *(const float4*)(W1s + k * 128 + 4 * hl);
        a0 = fmaf(fv[k], wv.x, a0);
        a1 = fmaf(fv[k], wv.y, a1);
        a2 = fmaf(fv[k], wv.z, a2);
        a3 = fmaf(fv[k], wv.w, a3);
    }
    // natural layout, single conflict-free float4 store (contiguous across lanes)
    float* o1p = &o1s[wave][nsel][0];     // wave-private
    *(float4*)(o1p + 4 * hl) = make_float4(fmaxf(a0, 0.0f), fmaxf(a1, 0.0f),
                                           fmaxf(a2, 0.0f), fmaxf(a3, 0.0f));
    // W2 from LDS (transposed): output c = hl&15, K-half g = hl>>4
    int c = hl & 15, g = hl >> 4;
    const float4* o1v = (const float4*)(o1p + g * 64);        // broadcast reads
    const float4* w2v = (const float4*)(W2T + c * 132 + g * 64);
    float p = 0.0f;
#pragma unroll
    for (int k = 0; k < 16; k++) {
        float4 hv = o1v[k];
        float4 wv = w2v[k];
        p = fmaf(hv.x, wv.x, p);
        p = fmaf(hv.y, wv.y, p);
        p = fmaf(hv.z, wv.z, p);
        p = fmaf(hv.w, wv.w, p);
    }
    p += __shfl_down(p, 16, 64);          // combine the two K-halves (stays in node half)
    if (hl < 16 && alive) {
        h2[(size_t)node * 16 + c] = __float2half(di * p);   // pre-scaled by dinv_s
        out[(size_t)node * 16 + c] = di * di * p + b2[c];
    }
}

// layer-2 gather: out[node] += di * sum w*h2[s] (+spill); h2 pre-scaled by dinv_s.
// out RMW loads HOISTED to entry (hide the dependent tail under gather+reduce).
__global__ __launch_bounds__(256) void k_gather2(const uint* __restrict__ table,
                                                 const int4* __restrict__ sp,
                                                 const int* __restrict__ spill_cnt,
                                                 const float* __restrict__ dinv,
                                                 const __half* __restrict__ h2,
                                                 float* __restrict__ out) {
    int wave = threadIdx.x >> 6, lane = threadIdx.x & 63;
    int nsel = lane >> 5;
    int hl   = lane & 31;
    int c2   = lane & 1;
    int eo   = (lane >> 1) & 15;
    int bid  = blockIdx.x;
    int local = ((bid >> 3) * 4 + wave) * 2 + nsel;
    int node  = (bid & 7) * NPX + local;
    bool alive = (local < NPX);
    float di = dinv[node];
    int ns = *spill_cnt;                       // hoisted (uniform scalar)
    // hoisted out RMW loads: in flight during the whole gather+reduce
    float4 o0 = make_float4(0.f, 0.f, 0.f, 0.f), o1 = o0;
    float4* op = (float4*)(out + (size_t)node * 16 + c2 * 8);
    if (hl < 2 && alive) { o0 = op[0]; o1 = op[1]; }
    const uint* row = table + srow(node);
    uintx4 ev = __builtin_nontemporal_load(reinterpret_cast<const uintx4*>(row + 4 * eo));
    int s0 = ev.x & 0x1FFFF, s1 = ev.y & 0x1FFFF;
    int s2 = ev.z & 0x1FFFF, s3 = ev.w & 0x1FFFF;
    uint4 hv0 = *(const uint4*)(h2 + (size_t)s0 * 16 + c2 * 8);
    uint4 hv1 = *(const uint4*)(h2 + (size_t)s1 * 16 + c2 * 8);
    uint4 hv2 = *(const uint4*)(h2 + (size_t)s2 * 16 + c2 * 8);
    uint4 hv3 = *(const uint4*)(h2 + (size_t)s3 * 16 + c2 * 8);
    __half2 q0 = __half2half2(__ushort_as_half((ushort)(ev.x >> 17)));
    __half2 q1 = __half2half2(__ushort_as_half((ushort)(ev.y >> 17)));
    __half2 q2 = __half2half2(__ushort_as_half((ushort)(ev.z >> 17)));
    __half2 q3 = __half2half2(__ushort_as_half((ushort)(ev.w >> 17)));
    __half2 acc[4];
    acc[0] = __hmul2(q0, as_h2(hv0.x));
    acc[1] = __hmul2(q0, as_h2(hv0.y));
    acc[2] = __hmul2(q0, as_h2(hv0.z));
    acc[3] = __hmul2(q0, as_h2(hv0.w));
    acc[0] = __hfma2(q1, as_h2(hv1.x), acc[0]);
    acc[1] = __hfma2(q1, as_h2(hv1.y), acc[1]);
    acc[2] = __hfma2(q1, as_h2(hv1.z), acc[2]);
    acc[3] = __hfma2(q1, as_h2(hv1.w), acc[3]);
    acc[0] = __hfma2(q2, as_h2(hv2.x), acc[0]);
    acc[1] = __hfma2(q2, as_h2(hv2.y), acc[1]);
    acc[2] = __hfma2(q2, as_h2(hv2.z), acc[2]);
    acc[3] = __hfma2(q2, as_h2(hv2.w), acc[3]);
    acc[0] = __hfma2(q3, as_h2(hv3.x), acc[0]);
    acc[1] = __hfma2(q3, as_h2(hv3.y), acc[1]);
    acc[2] = __hfma2(q3, as_h2(hv3.z), acc[2]);
    acc[3] = __hfma2(q3, as_h2(hv3.w), acc[3]);
#pragma unroll
    for (int m = 2; m < 32; m <<= 1) {
#pragma unroll
        for (int k = 0; k < 4; k++)
            acc[k] = __hadd2(acc[k], as_h2(__shfl_xor(as_u32(acc[k]), m, 64)));
    }
    if ((hl < 2) && alive) {
        float accf[8];
#pragma unroll
        for (int k = 0; k < 4; k++) {
            float2 f = __half22float2(acc[k]);
            accf[2 * k + 0] = f.x;
            accf[2 * k + 1] = f.y;
        }
        if (ns > 0) {
            int nss = ns > SPILL_MAX ? SPILL_MAX : ns;
            for (int i = 0; i < nss; i++) {
                int4 q = sp[i];
                if (q.y == node) {
                    float f = __int_as_float(q.z);
                    uint4 qv = *(const uint4*)(h2 + (size_t)q.x * 16 + c2 * 8);
                    float2 u0 = __half22float2(as_h2(qv.x));
                    float2 u1 = __half22float2(as_h2(qv.y));
                    float2 u2 = __half22float2(as_h2(qv.z));
                    float2 u3 = __half22float2(as_h2(qv.w));
                    float uv[8] = {u0.x, u0.y, u1.x, u1.y, u2.x, u2.y, u3.x, u3.y};
                    for (int k = 0; k < 8; k++) accf[k] += f * uv[k];
                }
            }
        }
        o0.x += di * accf[0]; o0.y += di * accf[1];
        o0.z += di * accf[2]; o0.w += di * accf[3];
        o1.x += di * accf[4]; o1.y += di * accf[5];
        o1.z += di * accf[6]; o1.w += di * accf[7];
        op[0] = o0; op[1] = o1;
    }
}

// ===================== CSR fallback (round-2) =====================

__global__ void k_init(float* __restrict__ deg, int* __restrict__ cnt) {
    int i = blockIdx.x * blockDim.x + threadIdx.x;
    if (i < N_NODES) { deg[i] = 1.0f; if (cnt) cnt[i] = 0; }
}

__global__ void k_degcnt(const int* __restrict__ dst, const float* __restrict__ w,
                         float* __restrict__ deg, int* __restrict__ cnt) {
    int e = blockIdx.x * blockDim.x + threadIdx.x;
    if (e < N_EDGES) {
        int d = dst[e];
        atomicAdd(&deg[d], w[e]);
        if (cnt) atomicAdd(&cnt[d], 1);
    }
}

__global__ void k_dinv_agg(const float* __restrict__ x, float* __restrict__ deg_dinv,
                           float* __restrict__ agg) {
    int i = blockIdx.x * blockDim.x + threadIdx.x;
    if (i >= N_NODES) return;
    float di = rsqrtf(deg_dinv[i]);
    deg_dinv[i] = di;
    float s = di * di;
    const float4* xr = (const float4*)(x + (size_t)i * 16);
    float4* ar = (float4*)(agg + (size_t)i * 16);
#pragma unroll
    for (int k = 0; k < 4; k++) {
        float4 v = xr[k];
        v.x *= s; v.y *= s; v.z *= s; v.w *= s;
        ar[k] = v;
    }
}

__global__ __launch_bounds__(256) void k_scan1(const int* __restrict__ cnt,
                                               int* __restrict__ rowptr,
                                               int* __restrict__ bsum) {
    __shared__ int ts[256];
    int tid = threadIdx.x;
    int base = blockIdx.x * SCAN_CHUNK + tid * 8;
    int v[8]; int s = 0;
#pragma unroll
    for (int k = 0; k < 8; k++) {
        int idx = base + k;
        v[k] = (idx < N_NODES) ? cnt[idx] : 0;
        s += v[k];
    }
    ts[tid] = s;
    __syncthreads();
    for (int off = 1; off < 256; off <<= 1) {
        int t = (tid >= off) ? ts[tid - off] : 0;
        __syncthreads();
        ts[tid] += t;
        __syncthreads();
    }
    int run = ts[tid] - s;
#pragma unroll
    for (int k = 0; k < 8; k++) {
        int idx = base + k;
        if (idx < N_NODES) rowptr[idx] = run;
        run += v[k];
    }
    if (tid == 255) bsum[blockIdx.x] = ts[255];
}

__global__ void k_scan2(int* __restrict__ bsum) {
    if (threadIdx.x == 0 && blockIdx.x == 0) {
        int run = 0;
        for (int g = 0; g < SCAN_BLOCKS; g++) { int t = bsum[g]; bsum[g] = run; run += t; }
    }
}

__global__ __launch_bounds__(256) void k_scan3(int* __restrict__ rowptr,
                                               const int* __restrict__ bsum) {
    int tid = threadIdx.x;
    int base = blockIdx.x * SCAN_CHUNK + tid * 8;
    int off = bsum[blockIdx.x];
#pragma unroll
    for (int k = 0; k < 8; k++) {
        int idx = base + k;
        if (idx < N_NODES) rowptr[idx] += off;
    }
    if (blockIdx.x == 0 && tid == 0) rowptr[N_NODES] = N_EDGES;
}

__global__ void k_fill(const int* __restrict__ src, const int* __restrict__ dst,
                       const float* __restrict__ w, const float* __restrict__ dinv,
                       const int* __restrict__ rowptr, int* __restrict__ cnt,
                       int2* __restrict__ perm) {
    int e = blockIdx.x * blockDim.x + threadIdx.x;
    if (e >= N_EDGES) return;
    int s = src[e], d = dst[e];
    float nrm = dinv[s] * w[e] * dinv[d];
    int r = atomicSub(&cnt[d], 1) - 1;
    int pos = rowptr[d] + r;
    perm[pos] = make_int2(s, __float_as_int(nrm));
}

__global__ __launch_bounds__(256) void k_gather(const int2* __restrict__ perm,
                                                const int* __restrict__ rowptr,
                                                const float* __restrict__ feat,
                                                float* __restrict__ out) {
    int wave = threadIdx.x >> 6, lane = threadIdx.x & 63;
    int node = blockIdx.x * 4 + wave;
    int c = lane & 15, eo = lane >> 4;
    int beg = rowptr[node], end = rowptr[node + 1];
    float acc = 0.0f;
    for (int j = beg + eo; j < end; j += 4) {
        int2 ed = perm[j];
        acc = fmaf(__int_as_float(ed.y), feat[(size_t)ed.x * 16 + c], acc);
    }
    acc += __shfl_xor(acc, 16, 64);
    acc += __shfl_xor(acc, 32, 64);
    if (lane < 16) out[(size_t)node * 16 + c] += acc;
}

__global__ __launch_bounds__(256) void k_mlp(float* __restrict__ agg,
                                             const float* __restrict__ W1,
                                             const float* __restrict__ b1,
                                             const float* __restrict__ W2,
                                             const float* __restrict__ b2,
                                             const float* __restrict__ dinv,
                                             float* __restrict__ out) {
    __shared__ float o1s[4][128];
    int wave = threadIdx.x >> 6;
    int lane = threadIdx.x & 63;
    int node = blockIdx.x * 4 + wave;
    const float* f = agg + (size_t)node * 16;
    float fv[16];
#pragma unroll
    for (int k = 0; k < 4; k++) {
        float4 v = ((const float4*)f)[k];
        fv[4 * k + 0] = v.x; fv[4 * k + 1] = v.y; fv[4 * k + 2] = v.z; fv[4 * k + 3] = v.w;
    }
    float a = b1[2 * lane], b = b1[2 * lane + 1];
#pragma unroll
    for (int k = 0; k < 16; k++) {
        float2 wv = *(const float2*)(W1 + k * 128 + 2 * lane);
        a = fmaf(fv[k], wv.x, a);
        b = fmaf(fv[k], wv.y, b);
    }
    o1s[wave][2 * lane + 0] = fmaxf(a, 0.0f);
    o1s[wave][2 * lane + 1] = fmaxf(b, 0.0f);
    __syncthreads();
    int c = lane & 15, g = lane >> 4;
    float p = 0.0f;
#pragma unroll
    for (int k = 0; k < 32; k++) {
        int kk = g * 32 + k;
        p = fmaf(o1s[wave][kk], W2[kk * 16 + c], p);
    }
    p += __shfl_down(p, 16, 64);
    p += __shfl_down(p, 32, 64);
    __syncthreads();
    if (lane < 16) {
        float h2v = p;
        agg[(size_t)node * 16 + c] = h2v;
        float di = dinv[node];
        out[(size_t)node * 16 + c] = di * di * h2v + b2[c];
    }
}

__global__ void k_scatter(const int* __restrict__ src, const int* __restrict__ dst,
                          const float* __restrict__ w, const float* __restrict__ dinv,
                          const float* __restrict__ feat, float* __restrict__ out) {
    int t = blockIdx.x * blockDim.x + threadIdx.x;
    int e = t >> 2;
    int c4 = (t & 3) * 4;
    if (e >= N_EDGES) return;
    int s = src[e], d = dst[e];
    float nrm = dinv[s] * w[e] * dinv[d];
    float4 v = *(const float4*)(feat + (size_t)s * 16 + c4);
    float* o = out + (size_t)d * 16 + c4;
    atomicAdd(o + 0, nrm * v.x);
    atomicAdd(o + 1, nrm * v.y);
    atomicAdd(o + 2, nrm * v.z);
    atomicAdd(o + 3, nrm * v.w);
}

// ===================== launch =====================

extern "C" void kernel_launch(void* const* d_in, const int* in_sizes, int n_in,
                              void* d_out, int out_size, void* d_ws, size_t ws_size,
                              hipStream_t stream) {
    const float* x  = (const float*)d_in[0];
    const int*   ei = (const int*)d_in[1];
    const float* w  = (const float*)d_in[2];
    const float* W1 = (const float*)d_in[3];
    const float* b1 = (const float*)d_in[4];
    const float* W2 = (const float*)d_in[5];
    const float* b2 = (const float*)d_in[6];
    float* out = (float*)d_out;

    const int* src = ei;
    const int* dst = ei + N_EDGES;
    const int B = 256;

    // ---- fast-path workspace layout (16B-aligned blocks) ----
    char* p = (char*)d_ws;
    int*    bucket_cnt = (int*)p;        p += (size_t)((NBUCK + 3) & ~3) * 4;
    int*    spill_cnt  = (int*)p;        p += 16;
    float*  dinv       = (float*)p;      p += (size_t)N_PAD * 4;
    __half* y16        = (__half*)p;     p += (size_t)N_NODES * 16 * 2;
    __half* h2         = (__half*)p;     p += (size_t)N_NODES * 16 * 2;
    int4*   sp         = (int4*)p;       p += (size_t)SPILL_MAX * 16;
    uint2*  ebuf       = (uint2*)p;      p += (size_t)NBUCK * BCAP * 8;
    const size_t WS_FAST = (size_t)(p - (char*)d_ws);

    if (ws_size >= WS_FAST) {
        k_pre0<<<(NBUCK + B - 1) / B, B, 0, stream>>>(bucket_cnt, spill_cnt);
        k_bin<<<BIN_BLOCKS, B, 0, stream>>>(src, dst, w, bucket_cnt, ebuf, sp, spill_cnt);
        k_sortz<<<NBUCK, B, 0, stream>>>(ebuf, bucket_cnt, sp, spill_cnt, x, dinv, y16);
        k_gather_mlp<<<GBLK, B, 0, stream>>>((const uint*)ebuf, sp, spill_cnt, dinv,
                                             y16, x, W1, b1, W2, b2, h2, out);
        k_gather2<<<GBLK, B, 0, stream>>>((const uint*)ebuf, sp, spill_cnt, dinv,
                                          h2, out);
        return;
    }

    // ---- CSR fallback (round-2 path) ----
    float* deg_dinv = (float*)d_ws;
    int*   cntb     = (int*)(deg_dinv + N_PAD);
    int*   rowptr   = cntb + N_PAD;
    int*   bsum     = rowptr + N_PAD;
    float* agg      = (float*)(bsum + 64);
    int2*  perm     = (int2*)(agg + (size_t)N_NODES * 16);
    const size_t WS_CSR = ((size_t)N_PAD * 3 + 64 + (size_t)N_NODES * 16) * 4
                          + (size_t)N_EDGES * 8;

    if (ws_size >= WS_CSR) {
        k_init<<<(N_NODES + B - 1) / B, B, 0, stream>>>(deg_dinv, cntb);
        k_degcnt<<<(N_EDGES + B - 1) / B, B, 0, stream>>>(dst, w, deg_dinv, cntb);
        k_dinv_agg<<<(N_NODES + B - 1) / B, B, 0, stream>>>(x, deg_dinv, agg);
        k_scan1<<<SCAN_BLOCKS, 256, 0, stream>>>(cntb, rowptr, bsum);
        k_scan2<<<1, 64, 0, stream>>>(bsum);
        k_scan3<<<SCAN_BLOCKS, 256, 0, stream>>>(rowptr, bsum);
        k_fill<<<(N_EDGES + B - 1) / B, B, 0, stream>>>(src, dst, w, deg_dinv,
                                                        rowptr, cntb, perm);
        k_gather<<<N_NODES / 4, B, 0, stream>>>(perm, rowptr, x, agg);
        k_mlp<<<N_NODES / 4, B, 0, stream>>>(agg, W1, b1, W2, b2, deg_dinv, out);
        k_gather<<<N_NODES / 4, B, 0, stream>>>(perm, rowptr, agg, out);
    } else {
        float* deg = (float*)d_ws;
        float* ag  = (float*)d_ws + N_NODES;
        k_init<<<(N_NODES + B - 1) / B, B, 0, stream>>>(deg, (int*)nullptr);
        k_degcnt<<<(N_EDGES + B - 1) / B, B, 0, stream>>>(dst, w, deg, (int*)nullptr);
        k_dinv_agg<<<(N_NODES + B - 1) / B, B, 0, stream>>>(x, deg, ag);
        k_scatter<<<((size_t)N_EDGES * 4 + B - 1) / B, B, 0, stream>>>(src, dst, w, deg, x, ag);
        k_mlp<<<N_NODES / 4, B, 0, stream>>>(ag, W1, b1, W2, b2, deg, out);
        k_scatter<<<((size_t)N_EDGES * 4 + B - 1) / B, B, 0, stream>>>(src, dst, w, deg, ag, out);
    }
}

// Round 13
// 237.214 us; speedup vs baseline: 1.0942x; 1.0075x over previous
//
#include <hip/hip_runtime.h>
#include <hip/hip_fp16.h>

#define N_NODES 100000
#define N_EDGES 3200000
#define N_PAD   100096
#define BNODES  128
#define NBUCK   ((N_NODES + BNODES - 1) / BNODES)       // 782
#define BCAP    4800                                    // mean 4096, sigma 64 (11 sigma)
#define EPB_BIN 4096                                    // edges per bin block (16/thread)
#define BIN_BLOCKS ((N_EDGES + EPB_BIN - 1) / EPB_BIN)  // 782
#define SPILL_MAX 65536
#define NPX      (N_NODES / 8)                          // 12500 nodes per XCD slab
#define GBLK     (8 * ((NPX + 7) / 8))                  // 12504 gather blocks (8 nodes each)
#define SCAN_CHUNK 2048
#define SCAN_BLOCKS ((N_NODES + SCAN_CHUNK - 1) / SCAN_CHUNK)

typedef unsigned int uint;
typedef unsigned short ushort;
typedef unsigned long long ull;
typedef uint uintx4 __attribute__((ext_vector_type(4)));   // native vector for nontemporal builtin

__device__ __forceinline__ __half2 as_h2(uint u) { return *reinterpret_cast<__half2*>(&u); }
__device__ __forceinline__ uint as_u32(__half2 h) { return *reinterpret_cast<uint*>(&h); }

// fixed-stride row address inside the bucket region (bucket stride BCAP*2 uints)
__device__ __forceinline__ size_t srow(int n) {
    return (size_t)(n >> 7) * (BCAP * 2) + (size_t)(n & 127) * 64;
}

// ===================== fast path: pre0 -> bin -> sortz -> gather =====================

// zero bucket_cnt + spill_cnt only
__global__ __launch_bounds__(256) void k_pre0(int* __restrict__ bucket_cnt,
                                              int* __restrict__ spill_cnt) {
    int i = blockIdx.x * 256 + threadIdx.x;
    if (i < NBUCK) bucket_cnt[i] = 0;
    if (i == 0) *spill_cnt = 0;
}

// counting-sort edges into 782 dst-buckets. Block-local LDS sort, run-ordered
// writeback. LDS diet (39.1KB -> 4 blocks/CU): bucket id packed into entry bits
// 24-31 + positional threshold recovery (no bid[] array); ushort pref/base;
// rank aliases hist. k_bin was occupancy-bound (14%, VALU 4%).
__global__ __launch_bounds__(256) void k_bin(const int* __restrict__ src,
                                             const int* __restrict__ dst,
                                             const float* __restrict__ w,
                                             int* __restrict__ bucket_cnt,
                                             uint2* __restrict__ ebuf,
                                             int4* __restrict__ sp,
                                             int* __restrict__ spill_cnt) {
    __shared__ int    hist[NBUCK];          // 3.1 KB (re-zeroed as rank for pass 2)
    __shared__ ushort pref[NBUCK];          // 1.5 KB  block-local exclusive prefix
    __shared__ ushort base[NBUCK];          // 1.5 KB  global run start for this block
    __shared__ int    psum[256];            // 1 KB
    __shared__ uint2  sorted[EPB_BIN];      // 32 KB   entries, (b&255) in bits 24-31
    int tid = threadIdx.x;
    for (int b = tid; b < NBUCK; b += 256) hist[b] = 0;
    __syncthreads();
    int e0 = blockIdx.x * EPB_BIN;
    // pass 1: histogram (plain loads -> window stays L2-hot for pass 2)
#pragma unroll 4
    for (int k = 0; k < 16; k++) {
        int e = e0 + tid + k * 256;
        if (e < N_EDGES) atomicAdd(&hist[dst[e] >> 7], 1);
    }
    __syncthreads();
    // reserve global bases (positions < BCAP+slack << 65536 -> ushort)
    for (int b = tid; b < NBUCK; b += 256) {
        int c = hist[b];
        base[b] = (ushort)(c ? atomicAdd(&bucket_cnt[b], c) : 0);
    }
    // block-wide exclusive scan of hist -> pref (thread t owns elements 4t..4t+3)
    int loc[4]; int s4 = 0;
#pragma unroll
    for (int j = 0; j < 4; j++) {
        int idx = tid * 4 + j;
        int h = (idx < NBUCK) ? hist[idx] : 0;
        loc[j] = s4; s4 += h;
    }
    psum[tid] = s4;
    __syncthreads();
    for (int off = 1; off < 256; off <<= 1) {
        int t = (tid >= off) ? psum[tid - off] : 0;
        __syncthreads();
        psum[tid] += t;
        __syncthreads();
    }
    int run = psum[tid] - s4;               // exclusive across threads
#pragma unroll
    for (int j = 0; j < 4; j++) {
        int idx = tid * 4 + j;
        if (idx < NBUCK) pref[idx] = (ushort)(run + loc[j]);
    }
    __syncthreads();
    // re-zero hist -> rank
    for (int b = tid; b < NBUCK; b += 256) hist[b] = 0;
    __syncthreads();
    // pass 2: re-read (L2-hot) and scatter into bucket-sorted LDS order
#pragma unroll 4
    for (int k = 0; k < 16; k++) {
        int e = e0 + tid + k * 256;
        if (e < N_EDGES) {
            int s = src[e];
            int d = dst[e];
            float wv = w[e];
            int b = d >> 7;
            int p = (int)pref[b] + atomicAdd(&hist[b], 1);
            sorted[p] = make_uint2(((uint)(b & 255) << 24) |
                                   ((uint)(d & 127) << 17) | (uint)s,
                                   __float_as_uint(wv));
        }
    }
    __syncthreads();
    // run-ordered writeback; recover b = (k<<8)|low8 via positional thresholds
    int t1 = pref[256], t2 = pref[512], t3 = pref[768];
    int nval = N_EDGES - e0; if (nval > EPB_BIN) nval = EPB_BIN;
    for (int p = tid; p < nval; p += 256) {
        uint2 v = sorted[p];
        int b = ((int)(v.x >> 24)) | (((p >= t1) + (p >= t2) + (p >= t3)) << 8);
        int gpos = (int)base[b] + (p - (int)pref[b]);
        uint vx = v.x & 0x00FFFFFF;
        if (gpos < BCAP) {
            ebuf[(size_t)b * BCAP + gpos] = make_uint2(vx, v.y);
        } else {
            int oi = atomicAdd(spill_cnt, 1);
            if (oi < SPILL_MAX)
                sp[oi] = make_int4((int)(vx & 0x1FFFF), b * 128 + (int)(vx >> 17),
                                   (int)v.y, 0);
        }
    }
}

// per-bucket: weighted degree (pass 1), scatter into zero-initialized 32KB LDS
// staging table (pass 2 re-reads the L2-hot bucket), coalesced writeback.
// Also writes dinv and fused y16 = dinv*x fp16 conversion.
__global__ __launch_bounds__(256) void k_sortz(uint2* __restrict__ ebuf,
                                               const int* __restrict__ bucket_cnt,
                                               int4* __restrict__ sp,
                                               int* __restrict__ spill_cnt,
                                               const float* __restrict__ x,
                                               float* __restrict__ dinv,
                                               __half* __restrict__ y16) {
    __shared__ uint  tbl[BNODES * 64];   // 32 KB staging (4B entries, incl. zero pads)
    __shared__ float wacc[BNODES];
    __shared__ int   curs[BNODES];
    int b = blockIdx.x, tid = threadIdx.x;
    int lo = b * BNODES;
    int n = N_NODES - lo; if (n > BNODES) n = BNODES;
    if (tid < BNODES) { wacc[tid] = 0.0f; curs[tid] = 0; }
    {   // zero the staging table (2048 uint4 stores)
        uint4* t4 = (uint4*)tbl;
        for (int i = tid; i < BNODES * 16; i += 256) t4[i] = make_uint4(0, 0, 0, 0);
    }
    __syncthreads();
    int cnt = bucket_cnt[b]; if (cnt > BCAP) cnt = BCAP;
    const uint2* srcrow = ebuf + (size_t)b * BCAP;
    // pass 1: weighted degree
    for (int j = tid; j < cnt; j += 256) {
        uint2 e = srcrow[j];
        atomicAdd(&wacc[e.x >> 17], __uint_as_float(e.y));
    }
    // bucket-overflow spills from k_bin contribute to weighted degree
    int ns0 = *spill_cnt; if (ns0 > SPILL_MAX) ns0 = SPILL_MAX;
    for (int i = tid; i < ns0; i += 256) {
        int4 q = sp[i];
        if ((q.y >> 7) == b) atomicAdd(&wacc[q.y & 127], __int_as_float(q.z));
    }
    __syncthreads();
    // dinv + fused y16 = dinv * x (coalesced, bucket-contiguous)
    if (tid < n) dinv[lo + tid] = rsqrtf(1.0f + wacc[tid]);
    {
        int nl = tid >> 1, half = tid & 1;
        if (nl < n) {
            float di = rsqrtf(1.0f + wacc[nl]);
            const float4* xr = (const float4*)(x + (size_t)(lo + nl) * 16 + half * 8);
            float4 va = xr[0], vb = xr[1];
            __half2 h0 = __floats2half2_rn(di * va.x, di * va.y);
            __half2 h1 = __floats2half2_rn(di * va.z, di * va.w);
            __half2 h2v = __floats2half2_rn(di * vb.x, di * vb.y);
            __half2 h3 = __floats2half2_rn(di * vb.z, di * vb.w);
            uint4* yr = (uint4*)(y16 + (size_t)(lo + nl) * 16 + half * 8);
            yr[0] = make_uint4(as_u32(h0), as_u32(h1), as_u32(h2v), as_u32(h3));
        }
    }
    // pass 2: re-read bucket (L2-hot), scatter into LDS staging
    for (int j = tid; j < cnt; j += 256) {
        uint2 e = srcrow[j];
        int nl = e.x >> 17;
        int pos = atomicAdd(&curs[nl], 1);
        if (pos < 64) {
            uint wh = (uint)__half_as_ushort(__float2half(__uint_as_float(e.y)));
            tbl[nl * 64 + pos] = (wh << 17) | (e.x & 0x1FFFF);
        } else {
            // rare overflow (degree > 64): global spill, handled by gathers
            int oi = atomicAdd(spill_cnt, 1);
            if (oi < SPILL_MAX)
                sp[oi] = make_int4((int)(e.x & 0x1FFFF), lo + nl, (int)e.y, 0);
        }
    }
    __syncthreads();
    // coalesced writeback of the full bucket region (entries + zero pads)
    {
        uint4* o4 = (uint4*)((uint*)ebuf + (size_t)b * (BCAP * 2));
        const uint4* t4 = (const uint4*)tbl;
        for (int i = tid; i < BNODES * 16; i += 256) o4[i] = t4[i];
    }
}

// fused: layer-1 gather (fixed 64-slot rows, 2 nodes/wave, packed fp16) + fp32 self
// + concurrent half-wave MLP with LDS-staged weights (W1s natural, W2T transposed).
__global__ __launch_bounds__(256) void k_gather_mlp(const uint* __restrict__ table,
                                                    const int4* __restrict__ sp,
                                                    const int* __restrict__ spill_cnt,
                                                    const float* __restrict__ dinv,
                                                    const __half* __restrict__ y16,
                                                    const float* __restrict__ x,
                                                    const float* __restrict__ W1,
                                                    const float* __restrict__ b1,
                                                    const float* __restrict__ W2,
                                                    const float* __restrict__ b2,
                                                    __half* __restrict__ h2,
                                                    float* __restrict__ out) {
    __shared__ float W1s[16 * 128];       // 8 KB, natural layout
    __shared__ float W2T[16 * 132];       // 8.25 KB, transposed, +4 pad per row
    __shared__ float fvs[8][16];
    __shared__ float o1s[4][2][128];      // natural layout (conflicts proven harmless)
    int wave = threadIdx.x >> 6, lane = threadIdx.x & 63;
    int tid = threadIdx.x;
    // stage weights once per block (coalesced reads; LDS scatter for transpose)
    {
        const float4* w1g = (const float4*)W1;
        float4* w1l = (float4*)W1s;
        for (int i = tid; i < 512; i += 256) w1l[i] = w1g[i];
        for (int j = tid; j < 2048; j += 256) {
            int kk = j >> 4, c = j & 15;
            W2T[c * 132 + kk] = W2[j];
        }
    }
    __syncthreads();                       // only barrier in the kernel
    int nsel = lane >> 5;            // which node of the wave's pair
    int hl   = lane & 31;            // lane within the node's half-wave
    int c2   = lane & 1;             // feature half (8 halfs each)
    int eo   = (lane >> 1) & 15;     // slot group (4 slots each)
    int bid  = blockIdx.x;
    int local = ((bid >> 3) * 4 + wave) * 2 + nsel;  // node index within XCD slab
    int node  = (bid & 7) * NPX + local;
    bool alive = (local < NPX);
    float di = dinv[node];
    int ns = *spill_cnt;                       // hoisted (uniform scalar)
    // hoisted self-term loads: in flight during the whole gather+reduce
    float4 xa = make_float4(0.f, 0.f, 0.f, 0.f), xb = xa;
    if (hl < 2 && alive) {
        const float4* xr = (const float4*)(x + (size_t)node * 16 + c2 * 8);
        xa = xr[0]; xb = xr[1];
    }
    float4 bv = *(const float4*)(b1 + 4 * hl);  // hoisted bias
    const uint* row = table + srow(node);
    uintx4 ev = __builtin_nontemporal_load(reinterpret_cast<const uintx4*>(row + 4 * eo));
    int s0 = ev.x & 0x1FFFF, s1 = ev.y & 0x1FFFF;
    int s2 = ev.z & 0x1FFFF, s3 = ev.w & 0x1FFFF;
    uint4 hv0 = *(const uint4*)(y16 + (size_t)s0 * 16 + c2 * 8);
    uint4 hv1 = *(const uint4*)(y16 + (size_t)s1 * 16 + c2 * 8);
    uint4 hv2 = *(const uint4*)(y16 + (size_t)s2 * 16 + c2 * 8);
    uint4 hv3 = *(const uint4*)(y16 + (size_t)s3 * 16 + c2 * 8);
    __half2 q0 = __half2half2(__ushort_as_half((ushort)(ev.x >> 17)));
    __half2 q1 = __half2half2(__ushort_as_half((ushort)(ev.y >> 17)));
    __half2 q2 = __half2half2(__ushort_as_half((ushort)(ev.z >> 17)));
    __half2 q3 = __half2half2(__ushort_as_half((ushort)(ev.w >> 17)));
    __half2 acc[4];
    acc[0] = __hmul2(q0, as_h2(hv0.x));
    acc[1] = __hmul2(q0, as_h2(hv0.y));
    acc[2] = __hmul2(q0, as_h2(hv0.z));
    acc[3] = __hmul2(q0, as_h2(hv0.w));
    acc[0] = __hfma2(q1, as_h2(hv1.x), acc[0]);
    acc[1] = __hfma2(q1, as_h2(hv1.y), acc[1]);
    acc[2] = __hfma2(q1, as_h2(hv1.z), acc[2]);
    acc[3] = __hfma2(q1, as_h2(hv1.w), acc[3]);
    acc[0] = __hfma2(q2, as_h2(hv2.x), acc[0]);
    acc[1] = __hfma2(q2, as_h2(hv2.y), acc[1]);
    acc[2] = __hfma2(q2, as_h2(hv2.z), acc[2]);
    acc[3] = __hfma2(q2, as_h2(hv2.w), acc[3]);
    acc[0] = __hfma2(q3, as_h2(hv3.x), acc[0]);
    acc[1] = __hfma2(q3, as_h2(hv3.y), acc[1]);
    acc[2] = __hfma2(q3, as_h2(hv3.z), acc[2]);
    acc[3] = __hfma2(q3, as_h2(hv3.w), acc[3]);
    // reduce across 16 slot-groups (lane bits 1..4); stays within 32-lane node half
#pragma unroll
    for (int m = 2; m < 32; m <<= 1) {
#pragma unroll
        for (int k = 0; k < 4; k++)
            acc[k] = __hadd2(acc[k], as_h2(__shfl_xor(as_u32(acc[k]), m, 64)));
    }
    if ((hl < 2) && alive) {
        float accf[8];
#pragma unroll
        for (int k = 0; k < 4; k++) {
            float2 f = __half22float2(acc[k]);
            accf[2 * k + 0] = f.x;
            accf[2 * k + 1] = f.y;
        }
        float slf[8] = {xa.x, xa.y, xa.z, xa.w, xb.x, xb.y, xb.z, xb.w};
        float r[8];
#pragma unroll
        for (int k = 0; k < 8; k++) r[k] = accf[k] + di * slf[k];
        if (ns > 0) {
            int nss = ns > SPILL_MAX ? SPILL_MAX : ns;
            for (int i = 0; i < nss; i++) {
                int4 q = sp[i];
                if (q.y == node) {
                    float f = __int_as_float(q.z);     // raw w; dinv_s already in y16
                    uint4 qv = *(const uint4*)(y16 + (size_t)q.x * 16 + c2 * 8);
                    float2 u0 = __half22float2(as_h2(qv.x));
                    float2 u1 = __half22float2(as_h2(qv.y));
                    float2 u2 = __half22float2(as_h2(qv.z));
                    float2 u3 = __half22float2(as_h2(qv.w));
                    float uv[8] = {u0.x, u0.y, u1.x, u1.y, u2.x, u2.y, u3.x, u3.y};
                    for (int k = 0; k < 8; k++) r[k] += f * uv[k];
                }
            }
        }
#pragma unroll
        for (int k = 0; k < 8; k++) fvs[wave * 2 + nsel][c2 * 8 + k] = r[k] * di;
    }
    // no barrier: fvs[wave*2+nsel] is wave-private, wave64 lockstep
    // MLP: both nodes concurrently; each half-wave owns its node.
    float fv[16];
#pragma unroll
    for (int k = 0; k < 16; k++) fv[k] = fvs[wave * 2 + nsel][k];
    // W1 from LDS: lane computes hidden outputs o = 4*hl + j
    float a0 = bv.x, a1 = bv.y, a2 = bv.z, a3 = bv.w;
#pragma unroll
    for (int k = 0; k < 16; k++) {
        float4 wv = *(const float4*)(W1s + k * 128 + 4 * hl);
        a0 = fmaf(fv[k], wv.x, a0);
        a1 = fmaf(fv[k], wv.y, a1);
        a2 = fmaf(fv[k], wv.z, a2);
        a3 = fmaf(fv[k], wv.w, a3);
    }
    // natural layout, single float4 store (contiguous across lanes)
    float* o1p = &o1s[wave][nsel][0];     // wave-private
    *(float4*)(o1p + 4 * hl) = make_float4(fmaxf(a0, 0.0f), fmaxf(a1, 0.0f),
                                           fmaxf(a2, 0.0f), fmaxf(a3, 0.0f));
    // W2 from LDS (transposed): output c = hl&15, K-half g = hl>>4
    int c = hl & 15, g = hl >> 4;
    const float4* o1v = (const float4*)(o1p + g * 64);        // broadcast reads
    const float4* w2v = (const float4*)(W2T + c * 132 + g * 64);
    float p = 0.0f;
#pragma unroll
    for (int k = 0; k < 16; k++) {
        float4 hv = o1v[k];
        float4 wv = w2v[k];
        p = fmaf(hv.x, wv.x, p);
        p = fmaf(hv.y, wv.y, p);
        p = fmaf(hv.z, wv.z, p);
        p = fmaf(hv.w, wv.w, p);
    }
    p += __shfl_down(p, 16, 64);          // combine the two K-halves (stays in node half)
    if (hl < 16 && alive) {
        h2[(size_t)node * 16 + c] = __float2half(di * p);   // pre-scaled by dinv_s
        out[(size_t)node * 16 + c] = di * di * p + b2[c];
    }
}

// layer-2 gather: out[node] += di * sum w*h2[s] (+spill); h2 pre-scaled by dinv_s.
// out RMW loads hoisted to entry.
__global__ __launch_bounds__(256) void k_gather2(const uint* __restrict__ table,
                                                 const int4* __restrict__ sp,
                                                 const int* __restrict__ spill_cnt,
                                                 const float* __restrict__ dinv,
                                                 const __half* __restrict__ h2,
                                                 float* __restrict__ out) {
    int wave = threadIdx.x >> 6, lane = threadIdx.x & 63;
    int nsel = lane >> 5;
    int hl   = lane & 31;
    int c2   = lane & 1;
    int eo   = (lane >> 1) & 15;
    int bid  = blockIdx.x;
    int local = ((bid >> 3) * 4 + wave) * 2 + nsel;
    int node  = (bid & 7) * NPX + local;
    bool alive = (local < NPX);
    float di = dinv[node];
    int ns = *spill_cnt;                       // hoisted (uniform scalar)
    // hoisted out RMW loads: in flight during the whole gather+reduce
    float4 o0 = make_float4(0.f, 0.f, 0.f, 0.f), o1 = o0;
    float4* op = (float4*)(out + (size_t)node * 16 + c2 * 8);
    if (hl < 2 && alive) { o0 = op[0]; o1 = op[1]; }
    const uint* row = table + srow(node);
    uintx4 ev = __builtin_nontemporal_load(reinterpret_cast<const uintx4*>(row + 4 * eo));
    int s0 = ev.x & 0x1FFFF, s1 = ev.y & 0x1FFFF;
    int s2 = ev.z & 0x1FFFF, s3 = ev.w & 0x1FFFF;
    uint4 hv0 = *(const uint4*)(h2 + (size_t)s0 * 16 + c2 * 8);
    uint4 hv1 = *(const uint4*)(h2 + (size_t)s1 * 16 + c2 * 8);
    uint4 hv2 = *(const uint4*)(h2 + (size_t)s2 * 16 + c2 * 8);
    uint4 hv3 = *(const uint4*)(h2 + (size_t)s3 * 16 + c2 * 8);
    __half2 q0 = __half2half2(__ushort_as_half((ushort)(ev.x >> 17)));
    __half2 q1 = __half2half2(__ushort_as_half((ushort)(ev.y >> 17)));
    __half2 q2 = __half2half2(__ushort_as_half((ushort)(ev.z >> 17)));
    __half2 q3 = __half2half2(__ushort_as_half((ushort)(ev.w >> 17)));
    __half2 acc[4];
    acc[0] = __hmul2(q0, as_h2(hv0.x));
    acc[1] = __hmul2(q0, as_h2(hv0.y));
    acc[2] = __hmul2(q0, as_h2(hv0.z));
    acc[3] = __hmul2(q0, as_h2(hv0.w));
    acc[0] = __hfma2(q1, as_h2(hv1.x), acc[0]);
    acc[1] = __hfma2(q1, as_h2(hv1.y), acc[1]);
    acc[2] = __hfma2(q1, as_h2(hv1.z), acc[2]);
    acc[3] = __hfma2(q1, as_h2(hv1.w), acc[3]);
    acc[0] = __hfma2(q2, as_h2(hv2.x), acc[0]);
    acc[1] = __hfma2(q2, as_h2(hv2.y), acc[1]);
    acc[2] = __hfma2(q2, as_h2(hv2.z), acc[2]);
    acc[3] = __hfma2(q2, as_h2(hv2.w), acc[3]);
    acc[0] = __hfma2(q3, as_h2(hv3.x), acc[0]);
    acc[1] = __hfma2(q3, as_h2(hv3.y), acc[1]);
    acc[2] = __hfma2(q3, as_h2(hv3.z), acc[2]);
    acc[3] = __hfma2(q3, as_h2(hv3.w), acc[3]);
#pragma unroll
    for (int m = 2; m < 32; m <<= 1) {
#pragma unroll
        for (int k = 0; k < 4; k++)
            acc[k] = __hadd2(acc[k], as_h2(__shfl_xor(as_u32(acc[k]), m, 64)));
    }
    if ((hl < 2) && alive) {
        float accf[8];
#pragma unroll
        for (int k = 0; k < 4; k++) {
            float2 f = __half22float2(acc[k]);
            accf[2 * k + 0] = f.x;
            accf[2 * k + 1] = f.y;
        }
        if (ns > 0) {
            int nss = ns > SPILL_MAX ? SPILL_MAX : ns;
            for (int i = 0; i < nss; i++) {
                int4 q = sp[i];
                if (q.y == node) {
                    float f = __int_as_float(q.z);
                    uint4 qv = *(const uint4*)(h2 + (size_t)q.x * 16 + c2 * 8);
                    float2 u0 = __half22float2(as_h2(qv.x));
                    float2 u1 = __half22float2(as_h2(qv.y));
                    float2 u2 = __half22float2(as_h2(qv.z));
                    float2 u3 = __half22float2(as_h2(qv.w));
                    float uv[8] = {u0.x, u0.y, u1.x, u1.y, u2.x, u2.y, u3.x, u3.y};
                    for (int k = 0; k < 8; k++) accf[k] += f * uv[k];
                }
            }
        }
        o0.x += di * accf[0]; o0.y += di * accf[1];
        o0.z += di * accf[2]; o0.w += di * accf[3];
        o1.x += di * accf[4]; o1.y += di * accf[5];
        o1.z += di * accf[6]; o1.w += di * accf[7];
        op[0] = o0; op[1] = o1;
    }
}

// ===================== CSR fallback (round-2) =====================

__global__ void k_init(float* __restrict__ deg, int* __restrict__ cnt) {
    int i = blockIdx.x * blockDim.x + threadIdx.x;
    if (i < N_NODES) { deg[i] = 1.0f; if (cnt) cnt[i] = 0; }
}

__global__ void k_degcnt(const int* __restrict__ dst, const float* __restrict__ w,
                         float* __restrict__ deg, int* __restrict__ cnt) {
    int e = blockIdx.x * blockDim.x + threadIdx.x;
    if (e < N_EDGES) {
        int d = dst[e];
        atomicAdd(&deg[d], w[e]);
        if (cnt) atomicAdd(&cnt[d], 1);
    }
}

__global__ void k_dinv_agg(const float* __restrict__ x, float* __restrict__ deg_dinv,
                           float* __restrict__ agg) {
    int i = blockIdx.x * blockDim.x + threadIdx.x;
    if (i >= N_NODES) return;
    float di = rsqrtf(deg_dinv[i]);
    deg_dinv[i] = di;
    float s = di * di;
    const float4* xr = (const float4*)(x + (size_t)i * 16);
    float4* ar = (float4*)(agg + (size_t)i * 16);
#pragma unroll
    for (int k = 0; k < 4; k++) {
        float4 v = xr[k];
        v.x *= s; v.y *= s; v.z *= s; v.w *= s;
        ar[k] = v;
    }
}

__global__ __launch_bounds__(256) void k_scan1(const int* __restrict__ cnt,
                                               int* __restrict__ rowptr,
                                               int* __restrict__ bsum) {
    __shared__ int ts[256];
    int tid = threadIdx.x;
    int base = blockIdx.x * SCAN_CHUNK + tid * 8;
    int v[8]; int s = 0;
#pragma unroll
    for (int k = 0; k < 8; k++) {
        int idx = base + k;
        v[k] = (idx < N_NODES) ? cnt[idx] : 0;
        s += v[k];
    }
    ts[tid] = s;
    __syncthreads();
    for (int off = 1; off < 256; off <<= 1) {
        int t = (tid >= off) ? ts[tid - off] : 0;
        __syncthreads();
        ts[tid] += t;
        __syncthreads();
    }
    int run = ts[tid] - s;
#pragma unroll
    for (int k = 0; k < 8; k++) {
        int idx = base + k;
        if (idx < N_NODES) rowptr[idx] = run;
        run += v[k];
    }
    if (tid == 255) bsum[blockIdx.x] = ts[255];
}

__global__ void k_scan2(int* __restrict__ bsum) {
    if (threadIdx.x == 0 && blockIdx.x == 0) {
        int run = 0;
        for (int g = 0; g < SCAN_BLOCKS; g++) { int t = bsum[g]; bsum[g] = run; run += t; }
    }
}

__global__ __launch_bounds__(256) void k_scan3(int* __restrict__ rowptr,
                                               const int* __restrict__ bsum) {
    int tid = threadIdx.x;
    int base = blockIdx.x * SCAN_CHUNK + tid * 8;
    int off = bsum[blockIdx.x];
#pragma unroll
    for (int k = 0; k < 8; k++) {
        int idx = base + k;
        if (idx < N_NODES) rowptr[idx] += off;
    }
    if (blockIdx.x == 0 && tid == 0) rowptr[N_NODES] = N_EDGES;
}

__global__ void k_fill(const int* __restrict__ src, const int* __restrict__ dst,
                       const float* __restrict__ w, const float* __restrict__ dinv,
                       const int* __restrict__ rowptr, int* __restrict__ cnt,
                       int2* __restrict__ perm) {
    int e = blockIdx.x * blockDim.x + threadIdx.x;
    if (e >= N_EDGES) return;
    int s = src[e], d = dst[e];
    float nrm = dinv[s] * w[e] * dinv[d];
    int r = atomicSub(&cnt[d], 1) - 1;
    int pos = rowptr[d] + r;
    perm[pos] = make_int2(s, __float_as_int(nrm));
}

__global__ __launch_bounds__(256) void k_gather(const int2* __restrict__ perm,
                                                const int* __restrict__ rowptr,
                                                const float* __restrict__ feat,
                                                float* __restrict__ out) {
    int wave = threadIdx.x >> 6, lane = threadIdx.x & 63;
    int node = blockIdx.x * 4 + wave;
    int c = lane & 15, eo = lane >> 4;
    int beg = rowptr[node], end = rowptr[node + 1];
    float acc = 0.0f;
    for (int j = beg + eo; j < end; j += 4) {
        int2 ed = perm[j];
        acc = fmaf(__int_as_float(ed.y), feat[(size_t)ed.x * 16 + c], acc);
    }
    acc += __shfl_xor(acc, 16, 64);
    acc += __shfl_xor(acc, 32, 64);
    if (lane < 16) out[(size_t)node * 16 + c] += acc;
}

__global__ __launch_bounds__(256) void k_mlp(float* __restrict__ agg,
                                             const float* __restrict__ W1,
                                             const float* __restrict__ b1,
                                             const float* __restrict__ W2,
                                             const float* __restrict__ b2,
                                             const float* __restrict__ dinv,
                                             float* __restrict__ out) {
    __shared__ float o1s[4][128];
    int wave = threadIdx.x >> 6;
    int lane = threadIdx.x & 63;
    int node = blockIdx.x * 4 + wave;
    const float* f = agg + (size_t)node * 16;
    float fv[16];
#pragma unroll
    for (int k = 0; k < 4; k++) {
        float4 v = ((const float4*)f)[k];
        fv[4 * k + 0] = v.x; fv[4 * k + 1] = v.y; fv[4 * k + 2] = v.z; fv[4 * k + 3] = v.w;
    }
    float a = b1[2 * lane], b = b1[2 * lane + 1];
#pragma unroll
    for (int k = 0; k < 16; k++) {
        float2 wv = *(const float2*)(W1 + k * 128 + 2 * lane);
        a = fmaf(fv[k], wv.x, a);
        b = fmaf(fv[k], wv.y, b);
    }
    o1s[wave][2 * lane + 0] = fmaxf(a, 0.0f);
    o1s[wave][2 * lane + 1] = fmaxf(b, 0.0f);
    __syncthreads();
    int c = lane & 15, g = lane >> 4;
    float p = 0.0f;
#pragma unroll
    for (int k = 0; k < 32; k++) {
        int kk = g * 32 + k;
        p = fmaf(o1s[wave][kk], W2[kk * 16 + c], p);
    }
    p += __shfl_down(p, 16, 64);
    p += __shfl_down(p, 32, 64);
    __syncthreads();
    if (lane < 16) {
        float h2v = p;
        agg[(size_t)node * 16 + c] = h2v;
        float di = dinv[node];
        out[(size_t)node * 16 + c] = di * di * h2v + b2[c];
    }
}

__global__ void k_scatter(const int* __restrict__ src, const int* __restrict__ dst,
                          const float* __restrict__ w, const float* __restrict__ dinv,
                          const float* __restrict__ feat, float* __restrict__ out) {
    int t = blockIdx.x * blockDim.x + threadIdx.x;
    int e = t >> 2;
    int c4 = (t & 3) * 4;
    if (e >= N_EDGES) return;
    int s = src[e], d = dst[e];
    float nrm = dinv[s] * w[e] * dinv[d];
    float4 v = *(const float4*)(feat + (size_t)s * 16 + c4);
    float* o = out + (size_t)d * 16 + c4;
    atomicAdd(o + 0, nrm * v.x);
    atomicAdd(o + 1, nrm * v.y);
    atomicAdd(o + 2, nrm * v.z);
    atomicAdd(o + 3, nrm * v.w);
}

// ===================== launch =====================

extern "C" void kernel_launch(void* const* d_in, const int* in_sizes, int n_in,
                              void* d_out, int out_size, void* d_ws, size_t ws_size,
                              hipStream_t stream) {
    const float* x  = (const float*)d_in[0];
    const int*   ei = (const int*)d_in[1];
    const float* w  = (const float*)d_in[2];
    const float* W1 = (const float*)d_in[3];
    const float* b1 = (const float*)d_in[4];
    const float* W2 = (const float*)d_in[5];
    const float* b2 = (const float*)d_in[6];
    float* out = (float*)d_out;

    const int* src = ei;
    const int* dst = ei + N_EDGES;
    const int B = 256;

    // ---- fast-path workspace layout (16B-aligned blocks) ----
    char* p = (char*)d_ws;
    int*    bucket_cnt = (int*)p;        p += (size_t)((NBUCK + 3) & ~3) * 4;
    int*    spill_cnt  = (int*)p;        p += 16;
    float*  dinv       = (float*)p;      p += (size_t)N_PAD * 4;
    __half* y16        = (__half*)p;     p += (size_t)N_NODES * 16 * 2;
    __half* h2         = (__half*)p;     p += (size_t)N_NODES * 16 * 2;
    int4*   sp         = (int4*)p;       p += (size_t)SPILL_MAX * 16;
    uint2*  ebuf       = (uint2*)p;      p += (size_t)NBUCK * BCAP * 8;
    const size_t WS_FAST = (size_t)(p - (char*)d_ws);

    if (ws_size >= WS_FAST) {
        k_pre0<<<(NBUCK + B - 1) / B, B, 0, stream>>>(bucket_cnt, spill_cnt);
        k_bin<<<BIN_BLOCKS, B, 0, stream>>>(src, dst, w, bucket_cnt, ebuf, sp, spill_cnt);
        k_sortz<<<NBUCK, B, 0, stream>>>(ebuf, bucket_cnt, sp, spill_cnt, x, dinv, y16);
        k_gather_mlp<<<GBLK, B, 0, stream>>>((const uint*)ebuf, sp, spill_cnt, dinv,
                                             y16, x, W1, b1, W2, b2, h2, out);
        k_gather2<<<GBLK, B, 0, stream>>>((const uint*)ebuf, sp, spill_cnt, dinv,
                                          h2, out);
        return;
    }

    // ---- CSR fallback (round-2 path) ----
    float* deg_dinv = (float*)d_ws;
    int*   cntb     = (int*)(deg_dinv + N_PAD);
    int*   rowptr   = cntb + N_PAD;
    int*   bsum     = rowptr + N_PAD;
    float* agg      = (float*)(bsum + 64);
    int2*  perm     = (int2*)(agg + (size_t)N_NODES * 16);
    const size_t WS_CSR = ((size_t)N_PAD * 3 + 64 + (size_t)N_NODES * 16) * 4
                          + (size_t)N_EDGES * 8;

    if (ws_size >= WS_CSR) {
        k_init<<<(N_NODES + B - 1) / B, B, 0, stream>>>(deg_dinv, cntb);
        k_degcnt<<<(N_EDGES + B - 1) / B, B, 0, stream>>>(dst, w, deg_dinv, cntb);
        k_dinv_agg<<<(N_NODES + B - 1) / B, B, 0, stream>>>(x, deg_dinv, agg);
        k_scan1<<<SCAN_BLOCKS, 256, 0, stream>>>(cntb, rowptr, bsum);
        k_scan2<<<1, 64, 0, stream>>>(bsum);
        k_scan3<<<SCAN_BLOCKS, 256, 0, stream>>>(rowptr, bsum);
        k_fill<<<(N_EDGES + B - 1) / B, B, 0, stream>>>(src, dst, w, deg_dinv,
                                                        rowptr, cntb, perm);
        k_gather<<<N_NODES / 4, B, 0, stream>>>(perm, rowptr, x, agg);
        k_mlp<<<N_NODES / 4, B, 0, stream>>>(agg, W1, b1, W2, b2, deg_dinv, out);
        k_gather<<<N_NODES / 4, B, 0, stream>>>(perm, rowptr, agg, out);
    } else {
        float* deg = (float*)d_ws;
        float* ag  = (float*)d_ws + N_NODES;
        k_init<<<(N_NODES + B - 1) / B, B, 0, stream>>>(deg, (int*)nullptr);
        k_degcnt<<<(N_EDGES + B - 1) / B, B, 0, stream>>>(dst, w, deg, (int*)nullptr);
        k_dinv_agg<<<(N_NODES + B - 1) / B, B, 0, stream>>>(x, deg, ag);
        k_scatter<<<((size_t)N_EDGES * 4 + B - 1) / B, B, 0, stream>>>(src, dst, w, deg, x, ag);
        k_mlp<<<N_NODES / 4, B, 0, stream>>>(ag, W1, b1, W2, b2, deg, out);
        k_scatter<<<((size_t)N_EDGES * 4 + B - 1) / B, B, 0, stream>>>(src, dst, w, deg, ag, out);
    }
}

// Round 14
// 236.888 us; speedup vs baseline: 1.0957x; 1.0014x over previous
//
#include <hip/hip_runtime.h>
#include <hip/hip_fp16.h>

#define N_NODES 100000
#define N_EDGES 3200000
#define N_PAD   100096
#define BNODES  128
#define NBUCK   ((N_NODES + BNODES - 1) / BNODES)       // 782
#define BCAP    4800                                    // mean 4096, sigma 64 (11 sigma)
#define EPB_BIN 8192                                    // edges per bin block (32/thread)
#define BIN_BLOCKS ((N_EDGES + EPB_BIN - 1) / EPB_BIN)  // 391
#define SPILL_MAX 65536
#define NPX      (N_NODES / 8)                          // 12500 nodes per XCD slab
#define GBLK     (8 * ((NPX + 7) / 8))                  // 12504 gather blocks (8 nodes each)
#define SCAN_CHUNK 2048
#define SCAN_BLOCKS ((N_NODES + SCAN_CHUNK - 1) / SCAN_CHUNK)

typedef unsigned int uint;
typedef unsigned short ushort;
typedef unsigned long long ull;
typedef uint uintx4 __attribute__((ext_vector_type(4)));   // native vector for nontemporal builtin

__device__ __forceinline__ __half2 as_h2(uint u) { return *reinterpret_cast<__half2*>(&u); }
__device__ __forceinline__ uint as_u32(__half2 h) { return *reinterpret_cast<uint*>(&h); }

// fixed-stride row address inside the bucket region (bucket stride BCAP*2 uints)
__device__ __forceinline__ size_t srow(int n) {
    return (size_t)(n >> 7) * (BCAP * 2) + (size_t)(n & 127) * 64;
}

// ===================== fast path: pre0 -> bin -> sortz -> gather =====================

// zero bucket_cnt + spill_cnt only
__global__ __launch_bounds__(256) void k_pre0(int* __restrict__ bucket_cnt,
                                              int* __restrict__ spill_cnt) {
    int i = blockIdx.x * 256 + threadIdx.x;
    if (i < NBUCK) bucket_cnt[i] = 0;
    if (i == 0) *spill_cnt = 0;
}

// counting-sort edges into 782 dst-buckets. Block-local LDS sort, run-ordered
// writeback. EPB=8192 (391 blocks): halves the per-block fixed costs that bind
// this kernel (global bucket_cnt atomics 611k->306k, scan/barrier per edge /2)
// and doubles mean run length (5.2->10.5) to cut cross-XCD boundary write-amp.
// Occupancy proven non-binding (r13: 14%->24% gave ~0).
__global__ __launch_bounds__(256) void k_bin(const int* __restrict__ src,
                                             const int* __restrict__ dst,
                                             const float* __restrict__ w,
                                             int* __restrict__ bucket_cnt,
                                             uint2* __restrict__ ebuf,
                                             int4* __restrict__ sp,
                                             int* __restrict__ spill_cnt) {
    __shared__ int    hist[NBUCK];          // 3.1 KB (re-zeroed as rank for pass 2)
    __shared__ ushort pref[NBUCK];          // 1.5 KB  block-local exclusive prefix
    __shared__ ushort base[NBUCK];          // 1.5 KB  global run start for this block
    __shared__ int    psum[256];            // 1 KB
    __shared__ uint2  sorted[EPB_BIN];      // 64 KB   entries, (b&255) in bits 24-31
    int tid = threadIdx.x;
    for (int b = tid; b < NBUCK; b += 256) hist[b] = 0;
    __syncthreads();
    int e0 = blockIdx.x * EPB_BIN;
    // pass 1: histogram (plain loads -> window stays L2-hot for pass 2)
#pragma unroll 4
    for (int k = 0; k < 32; k++) {
        int e = e0 + tid + k * 256;
        if (e < N_EDGES) atomicAdd(&hist[dst[e] >> 7], 1);
    }
    __syncthreads();
    // reserve global bases (positions < BCAP << 65536 -> ushort)
    for (int b = tid; b < NBUCK; b += 256) {
        int c = hist[b];
        base[b] = (ushort)(c ? atomicAdd(&bucket_cnt[b], c) : 0);
    }
    // block-wide exclusive scan of hist -> pref (thread t owns elements 4t..4t+3)
    int loc[4]; int s4 = 0;
#pragma unroll
    for (int j = 0; j < 4; j++) {
        int idx = tid * 4 + j;
        int h = (idx < NBUCK) ? hist[idx] : 0;
        loc[j] = s4; s4 += h;
    }
    psum[tid] = s4;
    __syncthreads();
    for (int off = 1; off < 256; off <<= 1) {
        int t = (tid >= off) ? psum[tid - off] : 0;
        __syncthreads();
        psum[tid] += t;
        __syncthreads();
    }
    int run = psum[tid] - s4;               // exclusive across threads
#pragma unroll
    for (int j = 0; j < 4; j++) {
        int idx = tid * 4 + j;
        if (idx < NBUCK) pref[idx] = (ushort)(run + loc[j]);
    }
    __syncthreads();
    // re-zero hist -> rank
    for (int b = tid; b < NBUCK; b += 256) hist[b] = 0;
    __syncthreads();
    // pass 2: re-read (L2-hot) and scatter into bucket-sorted LDS order
#pragma unroll 4
    for (int k = 0; k < 32; k++) {
        int e = e0 + tid + k * 256;
        if (e < N_EDGES) {
            int s = src[e];
            int d = dst[e];
            float wv = w[e];
            int b = d >> 7;
            int p = (int)pref[b] + atomicAdd(&hist[b], 1);
            sorted[p] = make_uint2(((uint)(b & 255) << 24) |
                                   ((uint)(d & 127) << 17) | (uint)s,
                                   __float_as_uint(wv));
        }
    }
    __syncthreads();
    // run-ordered writeback; recover b = (k<<8)|low8 via positional thresholds
    int t1 = pref[256], t2 = pref[512], t3 = pref[768];
    int nval = N_EDGES - e0; if (nval > EPB_BIN) nval = EPB_BIN;
    for (int p = tid; p < nval; p += 256) {
        uint2 v = sorted[p];
        int b = ((int)(v.x >> 24)) | (((p >= t1) + (p >= t2) + (p >= t3)) << 8);
        int gpos = (int)base[b] + (p - (int)pref[b]);
        uint vx = v.x & 0x00FFFFFF;
        if (gpos < BCAP) {
            ebuf[(size_t)b * BCAP + gpos] = make_uint2(vx, v.y);
        } else {
            int oi = atomicAdd(spill_cnt, 1);
            if (oi < SPILL_MAX)
                sp[oi] = make_int4((int)(vx & 0x1FFFF), b * 128 + (int)(vx >> 17),
                                   (int)v.y, 0);
        }
    }
}

// per-bucket: weighted degree (pass 1), scatter into zero-initialized 32KB LDS
// staging table (pass 2 re-reads the L2-hot bucket), coalesced writeback.
// Also writes dinv and fused y16 = dinv*x fp16 conversion.
__global__ __launch_bounds__(256) void k_sortz(uint2* __restrict__ ebuf,
                                               const int* __restrict__ bucket_cnt,
                                               int4* __restrict__ sp,
                                               int* __restrict__ spill_cnt,
                                               const float* __restrict__ x,
                                               float* __restrict__ dinv,
                                               __half* __restrict__ y16) {
    __shared__ uint  tbl[BNODES * 64];   // 32 KB staging (4B entries, incl. zero pads)
    __shared__ float wacc[BNODES];
    __shared__ int   curs[BNODES];
    int b = blockIdx.x, tid = threadIdx.x;
    int lo = b * BNODES;
    int n = N_NODES - lo; if (n > BNODES) n = BNODES;
    if (tid < BNODES) { wacc[tid] = 0.0f; curs[tid] = 0; }
    {   // zero the staging table (2048 uint4 stores)
        uint4* t4 = (uint4*)tbl;
        for (int i = tid; i < BNODES * 16; i += 256) t4[i] = make_uint4(0, 0, 0, 0);
    }
    __syncthreads();
    int cnt = bucket_cnt[b]; if (cnt > BCAP) cnt = BCAP;
    const uint2* srcrow = ebuf + (size_t)b * BCAP;
    // pass 1: weighted degree
    for (int j = tid; j < cnt; j += 256) {
        uint2 e = srcrow[j];
        atomicAdd(&wacc[e.x >> 17], __uint_as_float(e.y));
    }
    // bucket-overflow spills from k_bin contribute to weighted degree
    int ns0 = *spill_cnt; if (ns0 > SPILL_MAX) ns0 = SPILL_MAX;
    for (int i = tid; i < ns0; i += 256) {
        int4 q = sp[i];
        if ((q.y >> 7) == b) atomicAdd(&wacc[q.y & 127], __int_as_float(q.z));
    }
    __syncthreads();
    // dinv + fused y16 = dinv * x (coalesced, bucket-contiguous)
    if (tid < n) dinv[lo + tid] = rsqrtf(1.0f + wacc[tid]);
    {
        int nl = tid >> 1, half = tid & 1;
        if (nl < n) {
            float di = rsqrtf(1.0f + wacc[nl]);
            const float4* xr = (const float4*)(x + (size_t)(lo + nl) * 16 + half * 8);
            float4 va = xr[0], vb = xr[1];
            __half2 h0 = __floats2half2_rn(di * va.x, di * va.y);
            __half2 h1 = __floats2half2_rn(di * va.z, di * va.w);
            __half2 h2v = __floats2half2_rn(di * vb.x, di * vb.y);
            __half2 h3 = __floats2half2_rn(di * vb.z, di * vb.w);
            uint4* yr = (uint4*)(y16 + (size_t)(lo + nl) * 16 + half * 8);
            yr[0] = make_uint4(as_u32(h0), as_u32(h1), as_u32(h2v), as_u32(h3));
        }
    }
    // pass 2: re-read bucket (L2-hot), scatter into LDS staging
    for (int j = tid; j < cnt; j += 256) {
        uint2 e = srcrow[j];
        int nl = e.x >> 17;
        int pos = atomicAdd(&curs[nl], 1);
        if (pos < 64) {
            uint wh = (uint)__half_as_ushort(__float2half(__uint_as_float(e.y)));
            tbl[nl * 64 + pos] = (wh << 17) | (e.x & 0x1FFFF);
        } else {
            // rare overflow (degree > 64): global spill, handled by gathers
            int oi = atomicAdd(spill_cnt, 1);
            if (oi < SPILL_MAX)
                sp[oi] = make_int4((int)(e.x & 0x1FFFF), lo + nl, (int)e.y, 0);
        }
    }
    __syncthreads();
    // coalesced writeback of the full bucket region (entries + zero pads)
    {
        uint4* o4 = (uint4*)((uint*)ebuf + (size_t)b * (BCAP * 2));
        const uint4* t4 = (const uint4*)tbl;
        for (int i = tid; i < BNODES * 16; i += 256) o4[i] = t4[i];
    }
}

// fused: layer-1 gather (fixed 64-slot rows, 2 nodes/wave, packed fp16) + fp32 self
// + concurrent half-wave MLP with LDS-staged weights (W1s natural, W2T transposed).
__global__ __launch_bounds__(256) void k_gather_mlp(const uint* __restrict__ table,
                                                    const int4* __restrict__ sp,
                                                    const int* __restrict__ spill_cnt,
                                                    const float* __restrict__ dinv,
                                                    const __half* __restrict__ y16,
                                                    const float* __restrict__ x,
                                                    const float* __restrict__ W1,
                                                    const float* __restrict__ b1,
                                                    const float* __restrict__ W2,
                                                    const float* __restrict__ b2,
                                                    __half* __restrict__ h2,
                                                    float* __restrict__ out) {
    __shared__ float W1s[16 * 128];       // 8 KB, natural layout
    __shared__ float W2T[16 * 132];       // 8.25 KB, transposed, +4 pad per row
    __shared__ float fvs[8][16];
    __shared__ float o1s[4][2][128];      // natural layout (conflicts proven harmless)
    int wave = threadIdx.x >> 6, lane = threadIdx.x & 63;
    int tid = threadIdx.x;
    // stage weights once per block (coalesced reads; LDS scatter for transpose)
    {
        const float4* w1g = (const float4*)W1;
        float4* w1l = (float4*)W1s;
        for (int i = tid; i < 512; i += 256) w1l[i] = w1g[i];
        for (int j = tid; j < 2048; j += 256) {
            int kk = j >> 4, c = j & 15;
            W2T[c * 132 + kk] = W2[j];
        }
    }
    __syncthreads();                       // only barrier in the kernel
    int nsel = lane >> 5;            // which node of the wave's pair
    int hl   = lane & 31;            // lane within the node's half-wave
    int c2   = lane & 1;             // feature half (8 halfs each)
    int eo   = (lane >> 1) & 15;     // slot group (4 slots each)
    int bid  = blockIdx.x;
    int local = ((bid >> 3) * 4 + wave) * 2 + nsel;  // node index within XCD slab
    int node  = (bid & 7) * NPX + local;
    bool alive = (local < NPX);
    float di = dinv[node];
    int ns = *spill_cnt;                       // hoisted (uniform scalar)
    // hoisted self-term loads: in flight during the whole gather+reduce
    float4 xa = make_float4(0.f, 0.f, 0.f, 0.f), xb = xa;
    if (hl < 2 && alive) {
        const float4* xr = (const float4*)(x + (size_t)node * 16 + c2 * 8);
        xa = xr[0]; xb = xr[1];
    }
    float4 bv = *(const float4*)(b1 + 4 * hl);  // hoisted bias
    const uint* row = table + srow(node);
    uintx4 ev = __builtin_nontemporal_load(reinterpret_cast<const uintx4*>(row + 4 * eo));
    int s0 = ev.x & 0x1FFFF, s1 = ev.y & 0x1FFFF;
    int s2 = ev.z & 0x1FFFF, s3 = ev.w & 0x1FFFF;
    uint4 hv0 = *(const uint4*)(y16 + (size_t)s0 * 16 + c2 * 8);
    uint4 hv1 = *(const uint4*)(y16 + (size_t)s1 * 16 + c2 * 8);
    uint4 hv2 = *(const uint4*)(y16 + (size_t)s2 * 16 + c2 * 8);
    uint4 hv3 = *(const uint4*)(y16 + (size_t)s3 * 16 + c2 * 8);
    __half2 q0 = __half2half2(__ushort_as_half((ushort)(ev.x >> 17)));
    __half2 q1 = __half2half2(__ushort_as_half((ushort)(ev.y >> 17)));
    __half2 q2 = __half2half2(__ushort_as_half((ushort)(ev.z >> 17)));
    __half2 q3 = __half2half2(__ushort_as_half((ushort)(ev.w >> 17)));
    __half2 acc[4];
    acc[0] = __hmul2(q0, as_h2(hv0.x));
    acc[1] = __hmul2(q0, as_h2(hv0.y));
    acc[2] = __hmul2(q0, as_h2(hv0.z));
    acc[3] = __hmul2(q0, as_h2(hv0.w));
    acc[0] = __hfma2(q1, as_h2(hv1.x), acc[0]);
    acc[1] = __hfma2(q1, as_h2(hv1.y), acc[1]);
    acc[2] = __hfma2(q1, as_h2(hv1.z), acc[2]);
    acc[3] = __hfma2(q1, as_h2(hv1.w), acc[3]);
    acc[0] = __hfma2(q2, as_h2(hv2.x), acc[0]);
    acc[1] = __hfma2(q2, as_h2(hv2.y), acc[1]);
    acc[2] = __hfma2(q2, as_h2(hv2.z), acc[2]);
    acc[3] = __hfma2(q2, as_h2(hv2.w), acc[3]);
    acc[0] = __hfma2(q3, as_h2(hv3.x), acc[0]);
    acc[1] = __hfma2(q3, as_h2(hv3.y), acc[1]);
    acc[2] = __hfma2(q3, as_h2(hv3.z), acc[2]);
    acc[3] = __hfma2(q3, as_h2(hv3.w), acc[3]);
    // reduce across 16 slot-groups (lane bits 1..4); stays within 32-lane node half
#pragma unroll
    for (int m = 2; m < 32; m <<= 1) {
#pragma unroll
        for (int k = 0; k < 4; k++)
            acc[k] = __hadd2(acc[k], as_h2(__shfl_xor(as_u32(acc[k]), m, 64)));
    }
    if ((hl < 2) && alive) {
        float accf[8];
#pragma unroll
        for (int k = 0; k < 4; k++) {
            float2 f = __half22float2(acc[k]);
            accf[2 * k + 0] = f.x;
            accf[2 * k + 1] = f.y;
        }
        float slf[8] = {xa.x, xa.y, xa.z, xa.w, xb.x, xb.y, xb.z, xb.w};
        float r[8];
#pragma unroll
        for (int k = 0; k < 8; k++) r[k] = accf[k] + di * slf[k];
        if (ns > 0) {
            int nss = ns > SPILL_MAX ? SPILL_MAX : ns;
            for (int i = 0; i < nss; i++) {
                int4 q = sp[i];
                if (q.y == node) {
                    float f = __int_as_float(q.z);     // raw w; dinv_s already in y16
                    uint4 qv = *(const uint4*)(y16 + (size_t)q.x * 16 + c2 * 8);
                    float2 u0 = __half22float2(as_h2(qv.x));
                    float2 u1 = __half22float2(as_h2(qv.y));
                    float2 u2 = __half22float2(as_h2(qv.z));
                    float2 u3 = __half22float2(as_h2(qv.w));
                    float uv[8] = {u0.x, u0.y, u1.x, u1.y, u2.x, u2.y, u3.x, u3.y};
                    for (int k = 0; k < 8; k++) r[k] += f * uv[k];
                }
            }
        }
#pragma unroll
        for (int k = 0; k < 8; k++) fvs[wave * 2 + nsel][c2 * 8 + k] = r[k] * di;
    }
    // no barrier: fvs[wave*2+nsel] is wave-private, wave64 lockstep
    // MLP: both nodes concurrently; each half-wave owns its node.
    float fv[16];
#pragma unroll
    for (int k = 0; k < 16; k++) fv[k] = fvs[wave * 2 + nsel][k];
    // W1 from LDS: lane computes hidden outputs o = 4*hl + j
    float a0 = bv.x, a1 = bv.y, a2 = bv.z, a3 = bv.w;
#pragma unroll
    for (int k = 0; k < 16; k++) {
        float4 wv = *(const float4*)(W1s + k * 128 + 4 * hl);
        a0 = fmaf(fv[k], wv.x, a0);
        a1 = fmaf(fv[k], wv.y, a1);
        a2 = fmaf(fv[k], wv.z, a2);
        a3 = fmaf(fv[k], wv.w, a3);
    }
    // natural layout, single float4 store (contiguous across lanes)
    float* o1p = &o1s[wave][nsel][0];     // wave-private
    *(float4*)(o1p + 4 * hl) = make_float4(fmaxf(a0, 0.0f), fmaxf(a1, 0.0f),
                                           fmaxf(a2, 0.0f), fmaxf(a3, 0.0f));
    // W2 from LDS (transposed): output c = hl&15, K-half g = hl>>4
    int c = hl & 15, g = hl >> 4;
    const float4* o1v = (const float4*)(o1p + g * 64);        // broadcast reads
    const float4* w2v = (const float4*)(W2T + c * 132 + g * 64);
    float p = 0.0f;
#pragma unroll
    for (int k = 0; k < 16; k++) {
        float4 hv = o1v[k];
        float4 wv = w2v[k];
        p = fmaf(hv.x, wv.x, p);
        p = fmaf(hv.y, wv.y, p);
        p = fmaf(hv.z, wv.z, p);
        p = fmaf(hv.w, wv.w, p);
    }
    p += __shfl_down(p, 16, 64);          // combine the two K-halves (stays in node half)
    if (hl < 16 && alive) {
        h2[(size_t)node * 16 + c] = __float2half(di * p);   // pre-scaled by dinv_s
        out[(size_t)node * 16 + c] = di * di * p + b2[c];
    }
}

// layer-2 gather: out[node] += di * sum w*h2[s] (+spill); h2 pre-scaled by dinv_s.
// out RMW loads hoisted to entry.
__global__ __launch_bounds__(256) void k_gather2(const uint* __restrict__ table,
                                                 const int4* __restrict__ sp,
                                                 const int* __restrict__ spill_cnt,
                                                 const float* __restrict__ dinv,
                                                 const __half* __restrict__ h2,
                                                 float* __restrict__ out) {
    int wave = threadIdx.x >> 6, lane = threadIdx.x & 63;
    int nsel = lane >> 5;
    int hl   = lane & 31;
    int c2   = lane & 1;
    int eo   = (lane >> 1) & 15;
    int bid  = blockIdx.x;
    int local = ((bid >> 3) * 4 + wave) * 2 + nsel;
    int node  = (bid & 7) * NPX + local;
    bool alive = (local < NPX);
    float di = dinv[node];
    int ns = *spill_cnt;                       // hoisted (uniform scalar)
    // hoisted out RMW loads: in flight during the whole gather+reduce
    float4 o0 = make_float4(0.f, 0.f, 0.f, 0.f), o1 = o0;
    float4* op = (float4*)(out + (size_t)node * 16 + c2 * 8);
    if (hl < 2 && alive) { o0 = op[0]; o1 = op[1]; }
    const uint* row = table + srow(node);
    uintx4 ev = __builtin_nontemporal_load(reinterpret_cast<const uintx4*>(row + 4 * eo));
    int s0 = ev.x & 0x1FFFF, s1 = ev.y & 0x1FFFF;
    int s2 = ev.z & 0x1FFFF, s3 = ev.w & 0x1FFFF;
    uint4 hv0 = *(const uint4*)(h2 + (size_t)s0 * 16 + c2 * 8);
    uint4 hv1 = *(const uint4*)(h2 + (size_t)s1 * 16 + c2 * 8);
    uint4 hv2 = *(const uint4*)(h2 + (size_t)s2 * 16 + c2 * 8);
    uint4 hv3 = *(const uint4*)(h2 + (size_t)s3 * 16 + c2 * 8);
    __half2 q0 = __half2half2(__ushort_as_half((ushort)(ev.x >> 17)));
    __half2 q1 = __half2half2(__ushort_as_half((ushort)(ev.y >> 17)));
    __half2 q2 = __half2half2(__ushort_as_half((ushort)(ev.z >> 17)));
    __half2 q3 = __half2half2(__ushort_as_half((ushort)(ev.w >> 17)));
    __half2 acc[4];
    acc[0] = __hmul2(q0, as_h2(hv0.x));
    acc[1] = __hmul2(q0, as_h2(hv0.y));
    acc[2] = __hmul2(q0, as_h2(hv0.z));
    acc[3] = __hmul2(q0, as_h2(hv0.w));
    acc[0] = __hfma2(q1, as_h2(hv1.x), acc[0]);
    acc[1] = __hfma2(q1, as_h2(hv1.y), acc[1]);
    acc[2] = __hfma2(q1, as_h2(hv1.z), acc[2]);
    acc[3] = __hfma2(q1, as_h2(hv1.w), acc[3]);
    acc[0] = __hfma2(q2, as_h2(hv2.x), acc[0]);
    acc[1] = __hfma2(q2, as_h2(hv2.y), acc[1]);
    acc[2] = __hfma2(q2, as_h2(hv2.z), acc[2]);
    acc[3] = __hfma2(q2, as_h2(hv2.w), acc[3]);
    acc[0] = __hfma2(q3, as_h2(hv3.x), acc[0]);
    acc[1] = __hfma2(q3, as_h2(hv3.y), acc[1]);
    acc[2] = __hfma2(q3, as_h2(hv3.z), acc[2]);
    acc[3] = __hfma2(q3, as_h2(hv3.w), acc[3]);
#pragma unroll
    for (int m = 2; m < 32; m <<= 1) {
#pragma unroll
        for (int k = 0; k < 4; k++)
            acc[k] = __hadd2(acc[k], as_h2(__shfl_xor(as_u32(acc[k]), m, 64)));
    }
    if ((hl < 2) && alive) {
        float accf[8];
#pragma unroll
        for (int k = 0; k < 4; k++) {
            float2 f = __half22float2(acc[k]);
            accf[2 * k + 0] = f.x;
            accf[2 * k + 1] = f.y;
        }
        if (ns > 0) {
            int nss = ns > SPILL_MAX ? SPILL_MAX : ns;
            for (int i = 0; i < nss; i++) {
                int4 q = sp[i];
                if (q.y == node) {
                    float f = __int_as_float(q.z);
                    uint4 qv = *(const uint4*)(h2 + (size_t)q.x * 16 + c2 * 8);
                    float2 u0 = __half22float2(as_h2(qv.x));
                    float2 u1 = __half22float2(as_h2(qv.y));
                    float2 u2 = __half22float2(as_h2(qv.z));
                    float2 u3 = __half22float2(as_h2(qv.w));
                    float uv[8] = {u0.x, u0.y, u1.x, u1.y, u2.x, u2.y, u3.x, u3.y};
                    for (int k = 0; k < 8; k++) accf[k] += f * uv[k];
                }
            }
        }
        o0.x += di * accf[0]; o0.y += di * accf[1];
        o0.z += di * accf[2]; o0.w += di * accf[3];
        o1.x += di * accf[4]; o1.y += di * accf[5];
        o1.z += di * accf[6]; o1.w += di * accf[7];
        op[0] = o0; op[1] = o1;
    }
}

// ===================== CSR fallback (round-2) =====================

__global__ void k_init(float* __restrict__ deg, int* __restrict__ cnt) {
    int i = blockIdx.x * blockDim.x + threadIdx.x;
    if (i < N_NODES) { deg[i] = 1.0f; if (cnt) cnt[i] = 0; }
}

__global__ void k_degcnt(const int* __restrict__ dst, const float* __restrict__ w,
                         float* __restrict__ deg, int* __restrict__ cnt) {
    int e = blockIdx.x * blockDim.x + threadIdx.x;
    if (e < N_EDGES) {
        int d = dst[e];
        atomicAdd(&deg[d], w[e]);
        if (cnt) atomicAdd(&cnt[d], 1);
    }
}

__global__ void k_dinv_agg(const float* __restrict__ x, float* __restrict__ deg_dinv,
                           float* __restrict__ agg) {
    int i = blockIdx.x * blockDim.x + threadIdx.x;
    if (i >= N_NODES) return;
    float di = rsqrtf(deg_dinv[i]);
    deg_dinv[i] = di;
    float s = di * di;
    const float4* xr = (const float4*)(x + (size_t)i * 16);
    float4* ar = (float4*)(agg + (size_t)i * 16);
#pragma unroll
    for (int k = 0; k < 4; k++) {
        float4 v = xr[k];
        v.x *= s; v.y *= s; v.z *= s; v.w *= s;
        ar[k] = v;
    }
}

__global__ __launch_bounds__(256) void k_scan1(const int* __restrict__ cnt,
                                               int* __restrict__ rowptr,
                                               int* __restrict__ bsum) {
    __shared__ int ts[256];
    int tid = threadIdx.x;
    int base = blockIdx.x * SCAN_CHUNK + tid * 8;
    int v[8]; int s = 0;
#pragma unroll
    for (int k = 0; k < 8; k++) {
        int idx = base + k;
        v[k] = (idx < N_NODES) ? cnt[idx] : 0;
        s += v[k];
    }
    ts[tid] = s;
    __syncthreads();
    for (int off = 1; off < 256; off <<= 1) {
        int t = (tid >= off) ? ts[tid - off] : 0;
        __syncthreads();
        ts[tid] += t;
        __syncthreads();
    }
    int run = ts[tid] - s;
#pragma unroll
    for (int k = 0; k < 8; k++) {
        int idx = base + k;
        if (idx < N_NODES) rowptr[idx] = run;
        run += v[k];
    }
    if (tid == 255) bsum[blockIdx.x] = ts[255];
}

__global__ void k_scan2(int* __restrict__ bsum) {
    if (threadIdx.x == 0 && blockIdx.x == 0) {
        int run = 0;
        for (int g = 0; g < SCAN_BLOCKS; g++) { int t = bsum[g]; bsum[g] = run; run += t; }
    }
}

__global__ __launch_bounds__(256) void k_scan3(int* __restrict__ rowptr,
                                               const int* __restrict__ bsum) {
    int tid = threadIdx.x;
    int base = blockIdx.x * SCAN_CHUNK + tid * 8;
    int off = bsum[blockIdx.x];
#pragma unroll
    for (int k = 0; k < 8; k++) {
        int idx = base + k;
        if (idx < N_NODES) rowptr[idx] += off;
    }
    if (blockIdx.x == 0 && tid == 0) rowptr[N_NODES] = N_EDGES;
}

__global__ void k_fill(const int* __restrict__ src, const int* __restrict__ dst,
                       const float* __restrict__ w, const float* __restrict__ dinv,
                       const int* __restrict__ rowptr, int* __restrict__ cnt,
                       int2* __restrict__ perm) {
    int e = blockIdx.x * blockDim.x + threadIdx.x;
    if (e >= N_EDGES) return;
    int s = src[e], d = dst[e];
    float nrm = dinv[s] * w[e] * dinv[d];
    int r = atomicSub(&cnt[d], 1) - 1;
    int pos = rowptr[d] + r;
    perm[pos] = make_int2(s, __float_as_int(nrm));
}

__global__ __launch_bounds__(256) void k_gather(const int2* __restrict__ perm,
                                                const int* __restrict__ rowptr,
                                                const float* __restrict__ feat,
                                                float* __restrict__ out) {
    int wave = threadIdx.x >> 6, lane = threadIdx.x & 63;
    int node = blockIdx.x * 4 + wave;
    int c = lane & 15, eo = lane >> 4;
    int beg = rowptr[node], end = rowptr[node + 1];
    float acc = 0.0f;
    for (int j = beg + eo; j < end; j += 4) {
        int2 ed = perm[j];
        acc = fmaf(__int_as_float(ed.y), feat[(size_t)ed.x * 16 + c], acc);
    }
    acc += __shfl_xor(acc, 16, 64);
    acc += __shfl_xor(acc, 32, 64);
    if (lane < 16) out[(size_t)node * 16 + c] += acc;
}

__global__ __launch_bounds__(256) void k_mlp(float* __restrict__ agg,
                                             const float* __restrict__ W1,
                                             const float* __restrict__ b1,
                                             const float* __restrict__ W2,
                                             const float* __restrict__ b2,
                                             const float* __restrict__ dinv,
                                             float* __restrict__ out) {
    __shared__ float o1s[4][128];
    int wave = threadIdx.x >> 6;
    int lane = threadIdx.x & 63;
    int node = blockIdx.x * 4 + wave;
    const float* f = agg + (size_t)node * 16;
    float fv[16];
#pragma unroll
    for (int k = 0; k < 4; k++) {
        float4 v = ((const float4*)f)[k];
        fv[4 * k + 0] = v.x; fv[4 * k + 1] = v.y; fv[4 * k + 2] = v.z; fv[4 * k + 3] = v.w;
    }
    float a = b1[2 * lane], b = b1[2 * lane + 1];
#pragma unroll
    for (int k = 0; k < 16; k++) {
        float2 wv = *(const float2*)(W1 + k * 128 + 2 * lane);
        a = fmaf(fv[k], wv.x, a);
        b = fmaf(fv[k], wv.y, b);
    }
    o1s[wave][2 * lane + 0] = fmaxf(a, 0.0f);
    o1s[wave][2 * lane + 1] = fmaxf(b, 0.0f);
    __syncthreads();
    int c = lane & 15, g = lane >> 4;
    float p = 0.0f;
#pragma unroll
    for (int k = 0; k < 32; k++) {
        int kk = g * 32 + k;
        p = fmaf(o1s[wave][kk], W2[kk * 16 + c], p);
    }
    p += __shfl_down(p, 16, 64);
    p += __shfl_down(p, 32, 64);
    __syncthreads();
    if (lane < 16) {
        float h2v = p;
        agg[(size_t)node * 16 + c] = h2v;
        float di = dinv[node];
        out[(size_t)node * 16 + c] = di * di * h2v + b2[c];
    }
}

__global__ void k_scatter(const int* __restrict__ src, const int* __restrict__ dst,
                          const float* __restrict__ w, const float* __restrict__ dinv,
                          const float* __restrict__ feat, float* __restrict__ out) {
    int t = blockIdx.x * blockDim.x + threadIdx.x;
    int e = t >> 2;
    int c4 = (t & 3) * 4;
    if (e >= N_EDGES) return;
    int s = src[e], d = dst[e];
    float nrm = dinv[s] * w[e] * dinv[d];
    float4 v = *(const float4*)(feat + (size_t)s * 16 + c4);
    float* o = out + (size_t)d * 16 + c4;
    atomicAdd(o + 0, nrm * v.x);
    atomicAdd(o + 1, nrm * v.y);
    atomicAdd(o + 2, nrm * v.z);
    atomicAdd(o + 3, nrm * v.w);
}

// ===================== launch =====================

extern "C" void kernel_launch(void* const* d_in, const int* in_sizes, int n_in,
                              void* d_out, int out_size, void* d_ws, size_t ws_size,
                              hipStream_t stream) {
    const float* x  = (const float*)d_in[0];
    const int*   ei = (const int*)d_in[1];
    const float* w  = (const float*)d_in[2];
    const float* W1 = (const float*)d_in[3];
    const float* b1 = (const float*)d_in[4];
    const float* W2 = (const float*)d_in[5];
    const float* b2 = (const float*)d_in[6];
    float* out = (float*)d_out;

    const int* src = ei;
    const int* dst = ei + N_EDGES;
    const int B = 256;

    // ---- fast-path workspace layout (16B-aligned blocks) ----
    char* p = (char*)d_ws;
    int*    bucket_cnt = (int*)p;        p += (size_t)((NBUCK + 3) & ~3) * 4;
    int*    spill_cnt  = (int*)p;        p += 16;
    float*  dinv       = (float*)p;      p += (size_t)N_PAD * 4;
    __half* y16        = (__half*)p;     p += (size_t)N_NODES * 16 * 2;
    __half* h2         = (__half*)p;     p += (size_t)N_NODES * 16 * 2;
    int4*   sp         = (int4*)p;       p += (size_t)SPILL_MAX * 16;
    uint2*  ebuf       = (uint2*)p;      p += (size_t)NBUCK * BCAP * 8;
    const size_t WS_FAST = (size_t)(p - (char*)d_ws);

    if (ws_size >= WS_FAST) {
        k_pre0<<<(NBUCK + B - 1) / B, B, 0, stream>>>(bucket_cnt, spill_cnt);
        k_bin<<<BIN_BLOCKS, B, 0, stream>>>(src, dst, w, bucket_cnt, ebuf, sp, spill_cnt);
        k_sortz<<<NBUCK, B, 0, stream>>>(ebuf, bucket_cnt, sp, spill_cnt, x, dinv, y16);
        k_gather_mlp<<<GBLK, B, 0, stream>>>((const uint*)ebuf, sp, spill_cnt, dinv,
                                             y16, x, W1, b1, W2, b2, h2, out);
        k_gather2<<<GBLK, B, 0, stream>>>((const uint*)ebuf, sp, spill_cnt, dinv,
                                          h2, out);
        return;
    }

    // ---- CSR fallback (round-2 path) ----
    float* deg_dinv = (float*)d_ws;
    int*   cntb     = (int*)(deg_dinv + N_PAD);
    int*   rowptr   = cntb + N_PAD;
    int*   bsum     = rowptr + N_PAD;
    float* agg      = (float*)(bsum + 64);
    int2*  perm     = (int2*)(agg + (size_t)N_NODES * 16);
    const size_t WS_CSR = ((size_t)N_PAD * 3 + 64 + (size_t)N_NODES * 16) * 4
                          + (size_t)N_EDGES * 8;

    if (ws_size >= WS_CSR) {
        k_init<<<(N_NODES + B - 1) / B, B, 0, stream>>>(deg_dinv, cntb);
        k_degcnt<<<(N_EDGES + B - 1) / B, B, 0, stream>>>(dst, w, deg_dinv, cntb);
        k_dinv_agg<<<(N_NODES + B - 1) / B, B, 0, stream>>>(x, deg_dinv, agg);
        k_scan1<<<SCAN_BLOCKS, 256, 0, stream>>>(cntb, rowptr, bsum);
        k_scan2<<<1, 64, 0, stream>>>(bsum);
        k_scan3<<<SCAN_BLOCKS, 256, 0, stream>>>(rowptr, bsum);
        k_fill<<<(N_EDGES + B - 1) / B, B, 0, stream>>>(src, dst, w, deg_dinv,
                                                        rowptr, cntb, perm);
        k_gather<<<N_NODES / 4, B, 0, stream>>>(perm, rowptr, x, agg);
        k_mlp<<<N_NODES / 4, B, 0, stream>>>(agg, W1, b1, W2, b2, deg_dinv, out);
        k_gather<<<N_NODES / 4, B, 0, stream>>>(perm, rowptr, agg, out);
    } else {
        float* deg = (float*)d_ws;
        float* ag  = (float*)d_ws + N_NODES;
        k_init<<<(N_NODES + B - 1) / B, B, 0, stream>>>(deg, (int*)nullptr);
        k_degcnt<<<(N_EDGES + B - 1) / B, B, 0, stream>>>(dst, w, deg, (int*)nullptr);
        k_dinv_agg<<<(N_NODES + B - 1) / B, B, 0, stream>>>(x, deg, ag);
        k_scatter<<<((size_t)N_EDGES * 4 + B - 1) / B, B, 0, stream>>>(src, dst, w, deg, x, ag);
        k_mlp<<<N_NODES / 4, B, 0, stream>>>(ag, W1, b1, W2, b2, deg, out);
        k_scatter<<<((size_t)N_EDGES * 4 + B - 1) / B, B, 0, stream>>>(src, dst, w, deg, ag, out);
    }
}

// Round 15
// 217.932 us; speedup vs baseline: 1.1910x; 1.0870x over previous
//
#include <hip/hip_runtime.h>
#include <hip/hip_fp16.h>

#define N_NODES 100000
#define N_EDGES 3200000
#define N_PAD   100096
#define BNODES  128
#define NBUCK   ((N_NODES + BNODES - 1) / BNODES)       // 782
#define BCAP    4800                                    // mean 4096, sigma 64 (11 sigma)
#define EPB_BIN 8192                                    // edges per bin block (32/thread)
#define BIN_BLOCKS ((N_EDGES + EPB_BIN - 1) / EPB_BIN)  // 391
#define SPILL_MAX 65536
#define NPX      (N_NODES / 8)                          // 12500 nodes per XCD slab
#define GBLK     (8 * ((NPX + 7) / 8))                  // 12504 gather blocks (8 nodes each)
#define SCAN_CHUNK 2048
#define SCAN_BLOCKS ((N_NODES + SCAN_CHUNK - 1) / SCAN_CHUNK)

typedef unsigned int uint;
typedef unsigned short ushort;
typedef unsigned long long ull;
typedef uint uintx4 __attribute__((ext_vector_type(4)));   // native vector for nontemporal builtin

__device__ __forceinline__ __half2 as_h2(uint u) { return *reinterpret_cast<__half2*>(&u); }
__device__ __forceinline__ uint as_u32(__half2 h) { return *reinterpret_cast<uint*>(&h); }

// fixed-stride row address inside the bucket region (bucket stride BCAP*2 uints)
__device__ __forceinline__ size_t srow(int n) {
    return (size_t)(n >> 7) * (BCAP * 2) + (size_t)(n & 127) * 64;
}

// ===================== fast path: pre0 -> bin -> sortz -> gather =====================

// zero bucket_cnt + spill_cnt only
__global__ __launch_bounds__(256) void k_pre0(int* __restrict__ bucket_cnt,
                                              int* __restrict__ spill_cnt) {
    int i = blockIdx.x * 256 + threadIdx.x;
    if (i < NBUCK) bucket_cnt[i] = 0;
    if (i == 0) *spill_cnt = 0;
}

// counting-sort edges into 782 dst-buckets. Block-local LDS sort, run-ordered
// writeback. (k_bin plateaued at ~55us across EPB/occupancy/atomic-count knobs;
// parked.)
__global__ __launch_bounds__(256) void k_bin(const int* __restrict__ src,
                                             const int* __restrict__ dst,
                                             const float* __restrict__ w,
                                             int* __restrict__ bucket_cnt,
                                             uint2* __restrict__ ebuf,
                                             int4* __restrict__ sp,
                                             int* __restrict__ spill_cnt) {
    __shared__ int    hist[NBUCK];          // 3.1 KB (re-zeroed as rank for pass 2)
    __shared__ ushort pref[NBUCK];          // 1.5 KB  block-local exclusive prefix
    __shared__ ushort base[NBUCK];          // 1.5 KB  global run start for this block
    __shared__ int    psum[256];            // 1 KB
    __shared__ uint2  sorted[EPB_BIN];      // 64 KB   entries, (b&255) in bits 24-31
    int tid = threadIdx.x;
    for (int b = tid; b < NBUCK; b += 256) hist[b] = 0;
    __syncthreads();
    int e0 = blockIdx.x * EPB_BIN;
    // pass 1: histogram (plain loads -> window stays L2-hot for pass 2)
#pragma unroll 4
    for (int k = 0; k < 32; k++) {
        int e = e0 + tid + k * 256;
        if (e < N_EDGES) atomicAdd(&hist[dst[e] >> 7], 1);
    }
    __syncthreads();
    // reserve global bases (positions < BCAP << 65536 -> ushort)
    for (int b = tid; b < NBUCK; b += 256) {
        int c = hist[b];
        base[b] = (ushort)(c ? atomicAdd(&bucket_cnt[b], c) : 0);
    }
    // block-wide exclusive scan of hist -> pref (thread t owns elements 4t..4t+3)
    int loc[4]; int s4 = 0;
#pragma unroll
    for (int j = 0; j < 4; j++) {
        int idx = tid * 4 + j;
        int h = (idx < NBUCK) ? hist[idx] : 0;
        loc[j] = s4; s4 += h;
    }
    psum[tid] = s4;
    __syncthreads();
    for (int off = 1; off < 256; off <<= 1) {
        int t = (tid >= off) ? psum[tid - off] : 0;
        __syncthreads();
        psum[tid] += t;
        __syncthreads();
    }
    int run = psum[tid] - s4;               // exclusive across threads
#pragma unroll
    for (int j = 0; j < 4; j++) {
        int idx = tid * 4 + j;
        if (idx < NBUCK) pref[idx] = (ushort)(run + loc[j]);
    }
    __syncthreads();
    // re-zero hist -> rank
    for (int b = tid; b < NBUCK; b += 256) hist[b] = 0;
    __syncthreads();
    // pass 2: re-read (L2-hot) and scatter into bucket-sorted LDS order
#pragma unroll 4
    for (int k = 0; k < 32; k++) {
        int e = e0 + tid + k * 256;
        if (e < N_EDGES) {
            int s = src[e];
            int d = dst[e];
            float wv = w[e];
            int b = d >> 7;
            int p = (int)pref[b] + atomicAdd(&hist[b], 1);
            sorted[p] = make_uint2(((uint)(b & 255) << 24) |
                                   ((uint)(d & 127) << 17) | (uint)s,
                                   __float_as_uint(wv));
        }
    }
    __syncthreads();
    // run-ordered writeback; recover b = (k<<8)|low8 via positional thresholds
    int t1 = pref[256], t2 = pref[512], t3 = pref[768];
    int nval = N_EDGES - e0; if (nval > EPB_BIN) nval = EPB_BIN;
    for (int p = tid; p < nval; p += 256) {
        uint2 v = sorted[p];
        int b = ((int)(v.x >> 24)) | (((p >= t1) + (p >= t2) + (p >= t3)) << 8);
        int gpos = (int)base[b] + (p - (int)pref[b]);
        uint vx = v.x & 0x00FFFFFF;
        if (gpos < BCAP) {
            ebuf[(size_t)b * BCAP + gpos] = make_uint2(vx, v.y);
        } else {
            int oi = atomicAdd(spill_cnt, 1);
            if (oi < SPILL_MAX)
                sp[oi] = make_int4((int)(vx & 0x1FFFF), b * 128 + (int)(vx >> 17),
                                   (int)v.y, 0);
        }
    }
}

// per-bucket: SINGLE pass over the bucket: scatter into zero-initialized 32KB LDS
// staging (curs int-atomics only, fp16 conversion at scatter), then per-node
// weighted degree WITHOUT atomics (2 threads/node sum 32 slots each, rotated
// index -> conflict-free; zero pads decode as 0.0). Kills 3.2M FP LDS atomics
// + one full 25.6MB bucket re-read. dinv + fused y16 + coalesced writeback.
__global__ __launch_bounds__(256) void k_sortz(uint2* __restrict__ ebuf,
                                               const int* __restrict__ bucket_cnt,
                                               int4* __restrict__ sp,
                                               int* __restrict__ spill_cnt,
                                               const float* __restrict__ x,
                                               float* __restrict__ dinv,
                                               __half* __restrict__ y16) {
    __shared__ uint  tbl[BNODES * 64];   // 32 KB staging (4B entries, incl. zero pads)
    __shared__ float wacc[BNODES];
    __shared__ int   curs[BNODES];
    int b = blockIdx.x, tid = threadIdx.x;
    int lo = b * BNODES;
    int n = N_NODES - lo; if (n > BNODES) n = BNODES;
    if (tid < BNODES) curs[tid] = 0;
    {   // zero the staging table (2048 uint4 stores)
        uint4* t4 = (uint4*)tbl;
        for (int i = tid; i < BNODES * 16; i += 256) t4[i] = make_uint4(0, 0, 0, 0);
    }
    __syncthreads();
    int cnt = bucket_cnt[b]; if (cnt > BCAP) cnt = BCAP;
    const uint2* srcrow = ebuf + (size_t)b * BCAP;
    // single pass: scatter into LDS staging; entry = (fp16(w)<<17)|src
    for (int j = tid; j < cnt; j += 256) {
        uint2 e = srcrow[j];
        int nl = e.x >> 17;
        int pos = atomicAdd(&curs[nl], 1);
        if (pos < 64) {
            uint wh = (uint)__half_as_ushort(__float2half(__uint_as_float(e.y)));
            tbl[nl * 64 + pos] = (wh << 17) | (e.x & 0x1FFFF);
        } else {
            // rare overflow (degree > 64): global spill, handled by gathers
            int oi = atomicAdd(spill_cnt, 1);
            if (oi < SPILL_MAX)
                sp[oi] = make_int4((int)(e.x & 0x1FFFF), lo + nl, (int)e.y, 0);
        }
    }
    __syncthreads();
    // per-node weighted degree from staged table, no atomics:
    // thread tid sums half (tid&1) of node (tid>>1); rotated slot index keeps
    // banks distinct across lanes (bank = (k+tid)%32, 2-way = free).
    {
        int nl = tid >> 1, half = tid & 1;
        float s = 0.0f;
        int basei = nl * 64 + half * 32;
#pragma unroll 8
        for (int k = 0; k < 32; k++) {
            uint e = tbl[basei + ((k + tid) & 31)];
            s += __half2float(__ushort_as_half((ushort)(e >> 17)));
        }
        s += __shfl_xor(s, 1, 64);          // combine the two halves (adjacent lanes)
        if (half == 0) wacc[nl] = s;
    }
    __syncthreads();
    // rare spills (bucket overflow from k_bin, or degree>64 above) add to wacc
    int ns0 = *spill_cnt; if (ns0 > SPILL_MAX) ns0 = SPILL_MAX;
    if (ns0 > 0) {
        if (tid < BNODES) {
            float s = wacc[tid];
            for (int i = 0; i < ns0; i++) {
                int4 q = sp[i];
                if (q.y == lo + tid) s += __int_as_float(q.z);
            }
            wacc[tid] = s;
        }
        __syncthreads();
    }
    // dinv + fused y16 = dinv * x (coalesced, bucket-contiguous)
    if (tid < n) dinv[lo + tid] = rsqrtf(1.0f + wacc[tid]);
    {
        int nl = tid >> 1, half = tid & 1;
        if (nl < n) {
            float di = rsqrtf(1.0f + wacc[nl]);
            const float4* xr = (const float4*)(x + (size_t)(lo + nl) * 16 + half * 8);
            float4 va = xr[0], vb = xr[1];
            __half2 h0 = __floats2half2_rn(di * va.x, di * va.y);
            __half2 h1 = __floats2half2_rn(di * va.z, di * va.w);
            __half2 h2v = __floats2half2_rn(di * vb.x, di * vb.y);
            __half2 h3 = __floats2half2_rn(di * vb.z, di * vb.w);
            uint4* yr = (uint4*)(y16 + (size_t)(lo + nl) * 16 + half * 8);
            yr[0] = make_uint4(as_u32(h0), as_u32(h1), as_u32(h2v), as_u32(h3));
        }
    }
    // coalesced writeback of the full bucket region (entries + zero pads)
    {
        uint4* o4 = (uint4*)((uint*)ebuf + (size_t)b * (BCAP * 2));
        const uint4* t4 = (const uint4*)tbl;
        for (int i = tid; i < BNODES * 16; i += 256) o4[i] = t4[i];
    }
}

// fused: layer-1 gather (fixed 64-slot rows, 2 nodes/wave, packed fp16) + fp32 self
// + concurrent half-wave MLP with LDS-staged weights (W1s natural, W2T transposed).
__global__ __launch_bounds__(256) void k_gather_mlp(const uint* __restrict__ table,
                                                    const int4* __restrict__ sp,
                                                    const int* __restrict__ spill_cnt,
                                                    const float* __restrict__ dinv,
                                                    const __half* __restrict__ y16,
                                                    const float* __restrict__ x,
                                                    const float* __restrict__ W1,
                                                    const float* __restrict__ b1,
                                                    const float* __restrict__ W2,
                                                    const float* __restrict__ b2,
                                                    __half* __restrict__ h2,
                                                    float* __restrict__ out) {
    __shared__ float W1s[16 * 128];       // 8 KB, natural layout
    __shared__ float W2T[16 * 132];       // 8.25 KB, transposed, +4 pad per row
    __shared__ float fvs[8][16];
    __shared__ float o1s[4][2][128];      // natural layout (conflicts proven harmless)
    int wave = threadIdx.x >> 6, lane = threadIdx.x & 63;
    int tid = threadIdx.x;
    // stage weights once per block (coalesced reads; LDS scatter for transpose)
    {
        const float4* w1g = (const float4*)W1;
        float4* w1l = (float4*)W1s;
        for (int i = tid; i < 512; i += 256) w1l[i] = w1g[i];
        for (int j = tid; j < 2048; j += 256) {
            int kk = j >> 4, c = j & 15;
            W2T[c * 132 + kk] = W2[j];
        }
    }
    __syncthreads();                       // only barrier in the kernel
    int nsel = lane >> 5;            // which node of the wave's pair
    int hl   = lane & 31;            // lane within the node's half-wave
    int c2   = lane & 1;             // feature half (8 halfs each)
    int eo   = (lane >> 1) & 15;     // slot group (4 slots each)
    int bid  = blockIdx.x;
    int local = ((bid >> 3) * 4 + wave) * 2 + nsel;  // node index within XCD slab
    int node  = (bid & 7) * NPX + local;
    bool alive = (local < NPX);
    float di = dinv[node];
    int ns = *spill_cnt;                       // hoisted (uniform scalar)
    // hoisted self-term loads: in flight during the whole gather+reduce
    float4 xa = make_float4(0.f, 0.f, 0.f, 0.f), xb = xa;
    if (hl < 2 && alive) {
        const float4* xr = (const float4*)(x + (size_t)node * 16 + c2 * 8);
        xa = xr[0]; xb = xr[1];
    }
    float4 bv = *(const float4*)(b1 + 4 * hl);  // hoisted bias
    const uint* row = table + srow(node);
    uintx4 ev = __builtin_nontemporal_load(reinterpret_cast<const uintx4*>(row + 4 * eo));
    int s0 = ev.x & 0x1FFFF, s1 = ev.y & 0x1FFFF;
    int s2 = ev.z & 0x1FFFF, s3 = ev.w & 0x1FFFF;
    uint4 hv0 = *(const uint4*)(y16 + (size_t)s0 * 16 + c2 * 8);
    uint4 hv1 = *(const uint4*)(y16 + (size_t)s1 * 16 + c2 * 8);
    uint4 hv2 = *(const uint4*)(y16 + (size_t)s2 * 16 + c2 * 8);
    uint4 hv3 = *(const uint4*)(y16 + (size_t)s3 * 16 + c2 * 8);
    __half2 q0 = __half2half2(__ushort_as_half((ushort)(ev.x >> 17)));
    __half2 q1 = __half2half2(__ushort_as_half((ushort)(ev.y >> 17)));
    __half2 q2 = __half2half2(__ushort_as_half((ushort)(ev.z >> 17)));
    __half2 q3 = __half2half2(__ushort_as_half((ushort)(ev.w >> 17)));
    __half2 acc[4];
    acc[0] = __hmul2(q0, as_h2(hv0.x));
    acc[1] = __hmul2(q0, as_h2(hv0.y));
    acc[2] = __hmul2(q0, as_h2(hv0.z));
    acc[3] = __hmul2(q0, as_h2(hv0.w));
    acc[0] = __hfma2(q1, as_h2(hv1.x), acc[0]);
    acc[1] = __hfma2(q1, as_h2(hv1.y), acc[1]);
    acc[2] = __hfma2(q1, as_h2(hv1.z), acc[2]);
    acc[3] = __hfma2(q1, as_h2(hv1.w), acc[3]);
    acc[0] = __hfma2(q2, as_h2(hv2.x), acc[0]);
    acc[1] = __hfma2(q2, as_h2(hv2.y), acc[1]);
    acc[2] = __hfma2(q2, as_h2(hv2.z), acc[2]);
    acc[3] = __hfma2(q2, as_h2(hv2.w), acc[3]);
    acc[0] = __hfma2(q3, as_h2(hv3.x), acc[0]);
    acc[1] = __hfma2(q3, as_h2(hv3.y), acc[1]);
    acc[2] = __hfma2(q3, as_h2(hv3.z), acc[2]);
    acc[3] = __hfma2(q3, as_h2(hv3.w), acc[3]);
    // reduce across 16 slot-groups (lane bits 1..4); stays within 32-lane node half
#pragma unroll
    for (int m = 2; m < 32; m <<= 1) {
#pragma unroll
        for (int k = 0; k < 4; k++)
            acc[k] = __hadd2(acc[k], as_h2(__shfl_xor(as_u32(acc[k]), m, 64)));
    }
    if ((hl < 2) && alive) {
        float accf[8];
#pragma unroll
        for (int k = 0; k < 4; k++) {
            float2 f = __half22float2(acc[k]);
            accf[2 * k + 0] = f.x;
            accf[2 * k + 1] = f.y;
        }
        float slf[8] = {xa.x, xa.y, xa.z, xa.w, xb.x, xb.y, xb.z, xb.w};
        float r[8];
#pragma unroll
        for (int k = 0; k < 8; k++) r[k] = accf[k] + di * slf[k];
        if (ns > 0) {
            int nss = ns > SPILL_MAX ? SPILL_MAX : ns;
            for (int i = 0; i < nss; i++) {
                int4 q = sp[i];
                if (q.y == node) {
                    float f = __int_as_float(q.z);     // raw w; dinv_s already in y16
                    uint4 qv = *(const uint4*)(y16 + (size_t)q.x * 16 + c2 * 8);
                    float2 u0 = __half22float2(as_h2(qv.x));
                    float2 u1 = __half22float2(as_h2(qv.y));
                    float2 u2 = __half22float2(as_h2(qv.z));
                    float2 u3 = __half22float2(as_h2(qv.w));
                    float uv[8] = {u0.x, u0.y, u1.x, u1.y, u2.x, u2.y, u3.x, u3.y};
                    for (int k = 0; k < 8; k++) r[k] += f * uv[k];
                }
            }
        }
#pragma unroll
        for (int k = 0; k < 8; k++) fvs[wave * 2 + nsel][c2 * 8 + k] = r[k] * di;
    }
    // no barrier: fvs[wave*2+nsel] is wave-private, wave64 lockstep
    // MLP: both nodes concurrently; each half-wave owns its node.
    float fv[16];
#pragma unroll
    for (int k = 0; k < 16; k++) fv[k] = fvs[wave * 2 + nsel][k];
    // W1 from LDS: lane computes hidden outputs o = 4*hl + j
    float a0 = bv.x, a1 = bv.y, a2 = bv.z, a3 = bv.w;
#pragma unroll
    for (int k = 0; k < 16; k++) {
        float4 wv = *(const float4*)(W1s + k * 128 + 4 * hl);
        a0 = fmaf(fv[k], wv.x, a0);
        a1 = fmaf(fv[k], wv.y, a1);
        a2 = fmaf(fv[k], wv.z, a2);
        a3 = fmaf(fv[k], wv.w, a3);
    }
    // natural layout, single float4 store (contiguous across lanes)
    float* o1p = &o1s[wave][nsel][0];     // wave-private
    *(float4*)(o1p + 4 * hl) = make_float4(fmaxf(a0, 0.0f), fmaxf(a1, 0.0f),
                                           fmaxf(a2, 0.0f), fmaxf(a3, 0.0f));
    // W2 from LDS (transposed): output c = hl&15, K-half g = hl>>4
    int c = hl & 15, g = hl >> 4;
    const float4* o1v = (const float4*)(o1p + g * 64);        // broadcast reads
    const float4* w2v = (const float4*)(W2T + c * 132 + g * 64);
    float p = 0.0f;
#pragma unroll
    for (int k = 0; k < 16; k++) {
        float4 hv = o1v[k];
        float4 wv = w2v[k];
        p = fmaf(hv.x, wv.x, p);
        p = fmaf(hv.y, wv.y, p);
        p = fmaf(hv.z, wv.z, p);
        p = fmaf(hv.w, wv.w, p);
    }
    p += __shfl_down(p, 16, 64);          // combine the two K-halves (stays in node half)
    if (hl < 16 && alive) {
        h2[(size_t)node * 16 + c] = __float2half(di * p);   // pre-scaled by dinv_s
        out[(size_t)node * 16 + c] = di * di * p + b2[c];
    }
}

// layer-2 gather: out[node] += di * sum w*h2[s] (+spill); h2 pre-scaled by dinv_s.
// out RMW loads hoisted to entry.
__global__ __launch_bounds__(256) void k_gather2(const uint* __restrict__ table,
                                                 const int4* __restrict__ sp,
                                                 const int* __restrict__ spill_cnt,
                                                 const float* __restrict__ dinv,
                                                 const __half* __restrict__ h2,
                                                 float* __restrict__ out) {
    int wave = threadIdx.x >> 6, lane = threadIdx.x & 63;
    int nsel = lane >> 5;
    int hl   = lane & 31;
    int c2   = lane & 1;
    int eo   = (lane >> 1) & 15;
    int bid  = blockIdx.x;
    int local = ((bid >> 3) * 4 + wave) * 2 + nsel;
    int node  = (bid & 7) * NPX + local;
    bool alive = (local < NPX);
    float di = dinv[node];
    int ns = *spill_cnt;                       // hoisted (uniform scalar)
    // hoisted out RMW loads: in flight during the whole gather+reduce
    float4 o0 = make_float4(0.f, 0.f, 0.f, 0.f), o1 = o0;
    float4* op = (float4*)(out + (size_t)node * 16 + c2 * 8);
    if (hl < 2 && alive) { o0 = op[0]; o1 = op[1]; }
    const uint* row = table + srow(node);
    uintx4 ev = __builtin_nontemporal_load(reinterpret_cast<const uintx4*>(row + 4 * eo));
    int s0 = ev.x & 0x1FFFF, s1 = ev.y & 0x1FFFF;
    int s2 = ev.z & 0x1FFFF, s3 = ev.w & 0x1FFFF;
    uint4 hv0 = *(const uint4*)(h2 + (size_t)s0 * 16 + c2 * 8);
    uint4 hv1 = *(const uint4*)(h2 + (size_t)s1 * 16 + c2 * 8);
    uint4 hv2 = *(const uint4*)(h2 + (size_t)s2 * 16 + c2 * 8);
    uint4 hv3 = *(const uint4*)(h2 + (size_t)s3 * 16 + c2 * 8);
    __half2 q0 = __half2half2(__ushort_as_half((ushort)(ev.x >> 17)));
    __half2 q1 = __half2half2(__ushort_as_half((ushort)(ev.y >> 17)));
    __half2 q2 = __half2half2(__ushort_as_half((ushort)(ev.z >> 17)));
    __half2 q3 = __half2half2(__ushort_as_half((ushort)(ev.w >> 17)));
    __half2 acc[4];
    acc[0] = __hmul2(q0, as_h2(hv0.x));
    acc[1] = __hmul2(q0, as_h2(hv0.y));
    acc[2] = __hmul2(q0, as_h2(hv0.z));
    acc[3] = __hmul2(q0, as_h2(hv0.w));
    acc[0] = __hfma2(q1, as_h2(hv1.x), acc[0]);
    acc[1] = __hfma2(q1, as_h2(hv1.y), acc[1]);
    acc[2] = __hfma2(q1, as_h2(hv1.z), acc[2]);
    acc[3] = __hfma2(q1, as_h2(hv1.w), acc[3]);
    acc[0] = __hfma2(q2, as_h2(hv2.x), acc[0]);
    acc[1] = __hfma2(q2, as_h2(hv2.y), acc[1]);
    acc[2] = __hfma2(q2, as_h2(hv2.z), acc[2]);
    acc[3] = __hfma2(q2, as_h2(hv2.w), acc[3]);
    acc[0] = __hfma2(q3, as_h2(hv3.x), acc[0]);
    acc[1] = __hfma2(q3, as_h2(hv3.y), acc[1]);
    acc[2] = __hfma2(q3, as_h2(hv3.z), acc[2]);
    acc[3] = __hfma2(q3, as_h2(hv3.w), acc[3]);
#pragma unroll
    for (int m = 2; m < 32; m <<= 1) {
#pragma unroll
        for (int k = 0; k < 4; k++)
            acc[k] = __hadd2(acc[k], as_h2(__shfl_xor(as_u32(acc[k]), m, 64)));
    }
    if ((hl < 2) && alive) {
        float accf[8];
#pragma unroll
        for (int k = 0; k < 4; k++) {
            float2 f = __half22float2(acc[k]);
            accf[2 * k + 0] = f.x;
            accf[2 * k + 1] = f.y;
        }
        if (ns > 0) {
            int nss = ns > SPILL_MAX ? SPILL_MAX : ns;
            for (int i = 0; i < nss; i++) {
                int4 q = sp[i];
                if (q.y == node) {
                    float f = __int_as_float(q.z);
                    uint4 qv = *(const uint4*)(h2 + (size_t)q.x * 16 + c2 * 8);
                    float2 u0 = __half22float2(as_h2(qv.x));
                    float2 u1 = __half22float2(as_h2(qv.y));
                    float2 u2 = __half22float2(as_h2(qv.z));
                    float2 u3 = __half22float2(as_h2(qv.w));
                    float uv[8] = {u0.x, u0.y, u1.x, u1.y, u2.x, u2.y, u3.x, u3.y};
                    for (int k = 0; k < 8; k++) accf[k] += f * uv[k];
                }
            }
        }
        o0.x += di * accf[0]; o0.y += di * accf[1];
        o0.z += di * accf[2]; o0.w += di * accf[3];
        o1.x += di * accf[4]; o1.y += di * accf[5];
        o1.z += di * accf[6]; o1.w += di * accf[7];
        op[0] = o0; op[1] = o1;
    }
}

// ===================== CSR fallback (round-2) =====================

__global__ void k_init(float* __restrict__ deg, int* __restrict__ cnt) {
    int i = blockIdx.x * blockDim.x + threadIdx.x;
    if (i < N_NODES) { deg[i] = 1.0f; if (cnt) cnt[i] = 0; }
}

__global__ void k_degcnt(const int* __restrict__ dst, const float* __restrict__ w,
                         float* __restrict__ deg, int* __restrict__ cnt) {
    int e = blockIdx.x * blockDim.x + threadIdx.x;
    if (e < N_EDGES) {
        int d = dst[e];
        atomicAdd(&deg[d], w[e]);
        if (cnt) atomicAdd(&cnt[d], 1);
    }
}

__global__ void k_dinv_agg(const float* __restrict__ x, float* __restrict__ deg_dinv,
                           float* __restrict__ agg) {
    int i = blockIdx.x * blockDim.x + threadIdx.x;
    if (i >= N_NODES) return;
    float di = rsqrtf(deg_dinv[i]);
    deg_dinv[i] = di;
    float s = di * di;
    const float4* xr = (const float4*)(x + (size_t)i * 16);
    float4* ar = (float4*)(agg + (size_t)i * 16);
#pragma unroll
    for (int k = 0; k < 4; k++) {
        float4 v = xr[k];
        v.x *= s; v.y *= s; v.z *= s; v.w *= s;
        ar[k] = v;
    }
}

__global__ __launch_bounds__(256) void k_scan1(const int* __restrict__ cnt,
                                               int* __restrict__ rowptr,
                                               int* __restrict__ bsum) {
    __shared__ int ts[256];
    int tid = threadIdx.x;
    int base = blockIdx.x * SCAN_CHUNK + tid * 8;
    int v[8]; int s = 0;
#pragma unroll
    for (int k = 0; k < 8; k++) {
        int idx = base + k;
        v[k] = (idx < N_NODES) ? cnt[idx] : 0;
        s += v[k];
    }
    ts[tid] = s;
    __syncthreads();
    for (int off = 1; off < 256; off <<= 1) {
        int t = (tid >= off) ? ts[tid - off] : 0;
        __syncthreads();
        ts[tid] += t;
        __syncthreads();
    }
    int run = ts[tid] - s;
#pragma unroll
    for (int k = 0; k < 8; k++) {
        int idx = base + k;
        if (idx < N_NODES) rowptr[idx] = run;
        run += v[k];
    }
    if (tid == 255) bsum[blockIdx.x] = ts[255];
}

__global__ void k_scan2(int* __restrict__ bsum) {
    if (threadIdx.x == 0 && blockIdx.x == 0) {
        int run = 0;
        for (int g = 0; g < SCAN_BLOCKS; g++) { int t = bsum[g]; bsum[g] = run; run += t; }
    }
}

__global__ __launch_bounds__(256) void k_scan3(int* __restrict__ rowptr,
                                               const int* __restrict__ bsum) {
    int tid = threadIdx.x;
    int base = blockIdx.x * SCAN_CHUNK + tid * 8;
    int off = bsum[blockIdx.x];
#pragma unroll
    for (int k = 0; k < 8; k++) {
        int idx = base + k;
        if (idx < N_NODES) rowptr[idx] += off;
    }
    if (blockIdx.x == 0 && tid == 0) rowptr[N_NODES] = N_EDGES;
}

__global__ void k_fill(const int* __restrict__ src, const int* __restrict__ dst,
                       const float* __restrict__ w, const float* __restrict__ dinv,
                       const int* __restrict__ rowptr, int* __restrict__ cnt,
                       int2* __restrict__ perm) {
    int e = blockIdx.x * blockDim.x + threadIdx.x;
    if (e >= N_EDGES) return;
    int s = src[e], d = dst[e];
    float nrm = dinv[s] * w[e] * dinv[d];
    int r = atomicSub(&cnt[d], 1) - 1;
    int pos = rowptr[d] + r;
    perm[pos] = make_int2(s, __float_as_int(nrm));
}

__global__ __launch_bounds__(256) void k_gather(const int2* __restrict__ perm,
                                                const int* __restrict__ rowptr,
                                                const float* __restrict__ feat,
                                                float* __restrict__ out) {
    int wave = threadIdx.x >> 6, lane = threadIdx.x & 63;
    int node = blockIdx.x * 4 + wave;
    int c = lane & 15, eo = lane >> 4;
    int beg = rowptr[node], end = rowptr[node + 1];
    float acc = 0.0f;
    for (int j = beg + eo; j < end; j += 4) {
        int2 ed = perm[j];
        acc = fmaf(__int_as_float(ed.y), feat[(size_t)ed.x * 16 + c], acc);
    }
    acc += __shfl_xor(acc, 16, 64);
    acc += __shfl_xor(acc, 32, 64);
    if (lane < 16) out[(size_t)node * 16 + c] += acc;
}

__global__ __launch_bounds__(256) void k_mlp(float* __restrict__ agg,
                                             const float* __restrict__ W1,
                                             const float* __restrict__ b1,
                                             const float* __restrict__ W2,
                                             const float* __restrict__ b2,
                                             const float* __restrict__ dinv,
                                             float* __restrict__ out) {
    __shared__ float o1s[4][128];
    int wave = threadIdx.x >> 6;
    int lane = threadIdx.x & 63;
    int node = blockIdx.x * 4 + wave;
    const float* f = agg + (size_t)node * 16;
    float fv[16];
#pragma unroll
    for (int k = 0; k < 4; k++) {
        float4 v = ((const float4*)f)[k];
        fv[4 * k + 0] = v.x; fv[4 * k + 1] = v.y; fv[4 * k + 2] = v.z; fv[4 * k + 3] = v.w;
    }
    float a = b1[2 * lane], b = b1[2 * lane + 1];
#pragma unroll
    for (int k = 0; k < 16; k++) {
        float2 wv = *(const float2*)(W1 + k * 128 + 2 * lane);
        a = fmaf(fv[k], wv.x, a);
        b = fmaf(fv[k], wv.y, b);
    }
    o1s[wave][2 * lane + 0] = fmaxf(a, 0.0f);
    o1s[wave][2 * lane + 1] = fmaxf(b, 0.0f);
    __syncthreads();
    int c = lane & 15, g = lane >> 4;
    float p = 0.0f;
#pragma unroll
    for (int k = 0; k < 32; k++) {
        int kk = g * 32 + k;
        p = fmaf(o1s[wave][kk], W2[kk * 16 + c], p);
    }
    p += __shfl_down(p, 16, 64);
    p += __shfl_down(p, 32, 64);
    __syncthreads();
    if (lane < 16) {
        float h2v = p;
        agg[(size_t)node * 16 + c] = h2v;
        float di = dinv[node];
        out[(size_t)node * 16 + c] = di * di * h2v + b2[c];
    }
}

__global__ void k_scatter(const int* __restrict__ src, const int* __restrict__ dst,
                          const float* __restrict__ w, const float* __restrict__ dinv,
                          const float* __restrict__ feat, float* __restrict__ out) {
    int t = blockIdx.x * blockDim.x + threadIdx.x;
    int e = t >> 2;
    int c4 = (t & 3) * 4;
    if (e >= N_EDGES) return;
    int s = src[e], d = dst[e];
    float nrm = dinv[s] * w[e] * dinv[d];
    float4 v = *(const float4*)(feat + (size_t)s * 16 + c4);
    float* o = out + (size_t)d * 16 + c4;
    atomicAdd(o + 0, nrm * v.x);
    atomicAdd(o + 1, nrm * v.y);
    atomicAdd(o + 2, nrm * v.z);
    atomicAdd(o + 3, nrm * v.w);
}

// ===================== launch =====================

extern "C" void kernel_launch(void* const* d_in, const int* in_sizes, int n_in,
                              void* d_out, int out_size, void* d_ws, size_t ws_size,
                              hipStream_t stream) {
    const float* x  = (const float*)d_in[0];
    const int*   ei = (const int*)d_in[1];
    const float* w  = (const float*)d_in[2];
    const float* W1 = (const float*)d_in[3];
    const float* b1 = (const float*)d_in[4];
    const float* W2 = (const float*)d_in[5];
    const float* b2 = (const float*)d_in[6];
    float* out = (float*)d_out;

    const int* src = ei;
    const int* dst = ei + N_EDGES;
    const int B = 256;

    // ---- fast-path workspace layout (16B-aligned blocks) ----
    char* p = (char*)d_ws;
    int*    bucket_cnt = (int*)p;        p += (size_t)((NBUCK + 3) & ~3) * 4;
    int*    spill_cnt  = (int*)p;        p += 16;
    float*  dinv       = (float*)p;      p += (size_t)N_PAD * 4;
    __half* y16        = (__half*)p;     p += (size_t)N_NODES * 16 * 2;
    __half* h2         = (__half*)p;     p += (size_t)N_NODES * 16 * 2;
    int4*   sp         = (int4*)p;       p += (size_t)SPILL_MAX * 16;
    uint2*  ebuf       = (uint2*)p;      p += (size_t)NBUCK * BCAP * 8;
    const size_t WS_FAST = (size_t)(p - (char*)d_ws);

    if (ws_size >= WS_FAST) {
        k_pre0<<<(NBUCK + B - 1) / B, B, 0, stream>>>(bucket_cnt, spill_cnt);
        k_bin<<<BIN_BLOCKS, B, 0, stream>>>(src, dst, w, bucket_cnt, ebuf, sp, spill_cnt);
        k_sortz<<<NBUCK, B, 0, stream>>>(ebuf, bucket_cnt, sp, spill_cnt, x, dinv, y16);
        k_gather_mlp<<<GBLK, B, 0, stream>>>((const uint*)ebuf, sp, spill_cnt, dinv,
                                             y16, x, W1, b1, W2, b2, h2, out);
        k_gather2<<<GBLK, B, 0, stream>>>((const uint*)ebuf, sp, spill_cnt, dinv,
                                          h2, out);
        return;
    }

    // ---- CSR fallback (round-2 path) ----
    float* deg_dinv = (float*)d_ws;
    int*   cntb     = (int*)(deg_dinv + N_PAD);
    int*   rowptr   = cntb + N_PAD;
    int*   bsum     = rowptr + N_PAD;
    float* agg      = (float*)(bsum + 64);
    int2*  perm     = (int2*)(agg + (size_t)N_NODES * 16);
    const size_t WS_CSR = ((size_t)N_PAD * 3 + 64 + (size_t)N_NODES * 16) * 4
                          + (size_t)N_EDGES * 8;

    if (ws_size >= WS_CSR) {
        k_init<<<(N_NODES + B - 1) / B, B, 0, stream>>>(deg_dinv, cntb);
        k_degcnt<<<(N_EDGES + B - 1) / B, B, 0, stream>>>(dst, w, deg_dinv, cntb);
        k_dinv_agg<<<(N_NODES + B - 1) / B, B, 0, stream>>>(x, deg_dinv, agg);
        k_scan1<<<SCAN_BLOCKS, 256, 0, stream>>>(cntb, rowptr, bsum);
        k_scan2<<<1, 64, 0, stream>>>(bsum);
        k_scan3<<<SCAN_BLOCKS, 256, 0, stream>>>(rowptr, bsum);
        k_fill<<<(N_EDGES + B - 1) / B, B, 0, stream>>>(src, dst, w, deg_dinv,
                                                        rowptr, cntb, perm);
        k_gather<<<N_NODES / 4, B, 0, stream>>>(perm, rowptr, x, agg);
        k_mlp<<<N_NODES / 4, B, 0, stream>>>(agg, W1, b1, W2, b2, deg_dinv, out);
        k_gather<<<N_NODES / 4, B, 0, stream>>>(perm, rowptr, agg, out);
    } else {
        float* deg = (float*)d_ws;
        float* ag  = (float*)d_ws + N_NODES;
        k_init<<<(N_NODES + B - 1) / B, B, 0, stream>>>(deg, (int*)nullptr);
        k_degcnt<<<(N_EDGES + B - 1) / B, B, 0, stream>>>(dst, w, deg, (int*)nullptr);
        k_dinv_agg<<<(N_NODES + B - 1) / B, B, 0, stream>>>(x, deg, ag);
        k_scatter<<<((size_t)N_EDGES * 4 + B - 1) / B, B, 0, stream>>>(src, dst, w, deg, x, ag);
        k_mlp<<<N_NODES / 4, B, 0, stream>>>(ag, W1, b1, W2, b2, deg, out);
        k_scatter<<<((size_t)N_EDGES * 4 + B - 1) / B, B, 0, stream>>>(src, dst, w, deg, ag, out);
    }
}

// Round 16
// 213.799 us; speedup vs baseline: 1.2140x; 1.0193x over previous
//
#include <hip/hip_runtime.h>
#include <hip/hip_fp16.h>

#define N_NODES 100000
#define N_EDGES 3200000
#define N_PAD   100096
#define BNODES  128
#define NBUCK   ((N_NODES + BNODES - 1) / BNODES)       // 782
#define BCAP    4800                                    // mean 4096, sigma 64 (11 sigma)
#define EPB_BIN 4096                                    // edges per bin block (16/thread)
#define BIN_BLOCKS ((N_EDGES + EPB_BIN - 1) / EPB_BIN)  // 782
#define SPILL_MAX 65536
#define NPX      (N_NODES / 8)                          // 12500 nodes per XCD slab
#define GBLK     (8 * ((NPX + 7) / 8))                  // 12504 gather blocks (8 nodes each)
#define SCAN_CHUNK 2048
#define SCAN_BLOCKS ((N_NODES + SCAN_CHUNK - 1) / SCAN_CHUNK)

typedef unsigned int uint;
typedef unsigned short ushort;
typedef unsigned long long ull;
typedef uint uintx4 __attribute__((ext_vector_type(4)));   // native vector for nontemporal builtin

__device__ __forceinline__ __half2 as_h2(uint u) { return *reinterpret_cast<__half2*>(&u); }
__device__ __forceinline__ uint as_u32(__half2 h) { return *reinterpret_cast<uint*>(&h); }

// fixed-stride row address inside the bucket region (bucket stride BCAP*2 uints)
__device__ __forceinline__ size_t srow(int n) {
    return (size_t)(n >> 7) * (BCAP * 2) + (size_t)(n & 127) * 64;
}

// ===================== fast path: pre0 -> bin -> sortz -> gather =====================

// zero bucket_cnt + spill_cnt only
__global__ __launch_bounds__(256) void k_pre0(int* __restrict__ bucket_cnt,
                                              int* __restrict__ spill_cnt) {
    int i = blockIdx.x * 256 + threadIdx.x;
    if (i < NBUCK) bucket_cnt[i] = 0;
    if (i == 0) *spill_cnt = 0;
}

// counting-sort edges into 782 dst-buckets. REGISTER-STAGED single global pass:
// pass 1 loads dst+src+w once, builds the packed entry in registers, histograms.
// Pass 2 is then pure {LDS-atomic -> LDS store} (no global loads) -- attacks the
// load->atomic->store latency chain that survived all occupancy/block/atomic knobs.
__global__ __launch_bounds__(256) void k_bin(const int* __restrict__ src,
                                             const int* __restrict__ dst,
                                             const float* __restrict__ w,
                                             int* __restrict__ bucket_cnt,
                                             uint2* __restrict__ ebuf,
                                             int4* __restrict__ sp,
                                             int* __restrict__ spill_cnt) {
    __shared__ int    hist[NBUCK];          // 3.1 KB (re-zeroed as rank for pass 2)
    __shared__ ushort pref[NBUCK];          // 1.5 KB  block-local exclusive prefix
    __shared__ ushort base[NBUCK];          // 1.5 KB  global run start for this block
    __shared__ int    psum[256];            // 1 KB
    __shared__ uint2  sorted[EPB_BIN];      // 32 KB   entries, (b&255) in bits 24-31
    int tid = threadIdx.x;
    for (int b = tid; b < NBUCK; b += 256) hist[b] = 0;
    __syncthreads();
    int e0 = blockIdx.x * EPB_BIN;
    // pass 1: single global read; stage entries in registers; histogram dst
    uint ent[16]; uint wv[16]; ushort bb[16];
#pragma unroll
    for (int k = 0; k < 16; k++) {
        int e = e0 + tid + k * 256;
        if (e < N_EDGES) {
            int d = dst[e];
            int s = src[e];
            float wf = w[e];
            int b = d >> 7;
            ent[k] = ((uint)(b & 255) << 24) | ((uint)(d & 127) << 17) | (uint)s;
            wv[k] = __float_as_uint(wf);
            bb[k] = (ushort)b;
            atomicAdd(&hist[b], 1);
        } else {
            bb[k] = 0xFFFF;
        }
    }
    __syncthreads();
    // reserve global bases (positions < BCAP << 65536 -> ushort)
    for (int b = tid; b < NBUCK; b += 256) {
        int c = hist[b];
        base[b] = (ushort)(c ? atomicAdd(&bucket_cnt[b], c) : 0);
    }
    // block-wide exclusive scan of hist -> pref (thread t owns elements 4t..4t+3)
    int loc[4]; int s4 = 0;
#pragma unroll
    for (int j = 0; j < 4; j++) {
        int idx = tid * 4 + j;
        int h = (idx < NBUCK) ? hist[idx] : 0;
        loc[j] = s4; s4 += h;
    }
    psum[tid] = s4;
    __syncthreads();
    for (int off = 1; off < 256; off <<= 1) {
        int t = (tid >= off) ? psum[tid - off] : 0;
        __syncthreads();
        psum[tid] += t;
        __syncthreads();
    }
    int run = psum[tid] - s4;               // exclusive across threads
#pragma unroll
    for (int j = 0; j < 4; j++) {
        int idx = tid * 4 + j;
        if (idx < NBUCK) pref[idx] = (ushort)(run + loc[j]);
    }
    __syncthreads();
    // re-zero hist -> rank
    for (int b = tid; b < NBUCK; b += 256) hist[b] = 0;
    __syncthreads();
    // pass 2 (register-resident): pure LDS-atomic + LDS store, no global loads
#pragma unroll
    for (int k = 0; k < 16; k++) {
        if (bb[k] != 0xFFFF) {
            int b = (int)bb[k];
            int p = (int)pref[b] + atomicAdd(&hist[b], 1);
            sorted[p] = make_uint2(ent[k], wv[k]);
        }
    }
    __syncthreads();
    // run-ordered writeback; recover b = (k<<8)|low8 via positional thresholds
    int t1 = pref[256], t2 = pref[512], t3 = pref[768];
    int nval = N_EDGES - e0; if (nval > EPB_BIN) nval = EPB_BIN;
    for (int p = tid; p < nval; p += 256) {
        uint2 v = sorted[p];
        int b = ((int)(v.x >> 24)) | (((p >= t1) + (p >= t2) + (p >= t3)) << 8);
        int gpos = (int)base[b] + (p - (int)pref[b]);
        uint vx = v.x & 0x00FFFFFF;
        if (gpos < BCAP) {
            ebuf[(size_t)b * BCAP + gpos] = make_uint2(vx, v.y);
        } else {
            int oi = atomicAdd(spill_cnt, 1);
            if (oi < SPILL_MAX)
                sp[oi] = make_int4((int)(vx & 0x1FFFF), b * 128 + (int)(vx >> 17),
                                   (int)v.y, 0);
        }
    }
}

// per-bucket: SINGLE pass over the bucket: scatter into zero-initialized 32KB LDS
// staging (curs int-atomics only, fp16 conversion at scatter), then per-node
// weighted degree WITHOUT atomics (2 threads/node sum 32 slots each, rotated
// index -> conflict-free; zero pads decode as 0.0). dinv + fused y16 + writeback.
__global__ __launch_bounds__(256) void k_sortz(uint2* __restrict__ ebuf,
                                               const int* __restrict__ bucket_cnt,
                                               int4* __restrict__ sp,
                                               int* __restrict__ spill_cnt,
                                               const float* __restrict__ x,
                                               float* __restrict__ dinv,
                                               __half* __restrict__ y16) {
    __shared__ uint  tbl[BNODES * 64];   // 32 KB staging (4B entries, incl. zero pads)
    __shared__ float wacc[BNODES];
    __shared__ int   curs[BNODES];
    int b = blockIdx.x, tid = threadIdx.x;
    int lo = b * BNODES;
    int n = N_NODES - lo; if (n > BNODES) n = BNODES;
    if (tid < BNODES) curs[tid] = 0;
    {   // zero the staging table (2048 uint4 stores)
        uint4* t4 = (uint4*)tbl;
        for (int i = tid; i < BNODES * 16; i += 256) t4[i] = make_uint4(0, 0, 0, 0);
    }
    __syncthreads();
    int cnt = bucket_cnt[b]; if (cnt > BCAP) cnt = BCAP;
    const uint2* srcrow = ebuf + (size_t)b * BCAP;
    // single pass: scatter into LDS staging; entry = (fp16(w)<<17)|src
    for (int j = tid; j < cnt; j += 256) {
        uint2 e = srcrow[j];
        int nl = e.x >> 17;
        int pos = atomicAdd(&curs[nl], 1);
        if (pos < 64) {
            uint wh = (uint)__half_as_ushort(__float2half(__uint_as_float(e.y)));
            tbl[nl * 64 + pos] = (wh << 17) | (e.x & 0x1FFFF);
        } else {
            // rare overflow (degree > 64): global spill, handled by gathers
            int oi = atomicAdd(spill_cnt, 1);
            if (oi < SPILL_MAX)
                sp[oi] = make_int4((int)(e.x & 0x1FFFF), lo + nl, (int)e.y, 0);
        }
    }
    __syncthreads();
    // per-node weighted degree from staged table, no atomics
    {
        int nl = tid >> 1, half = tid & 1;
        float s = 0.0f;
        int basei = nl * 64 + half * 32;
#pragma unroll 8
        for (int k = 0; k < 32; k++) {
            uint e = tbl[basei + ((k + tid) & 31)];
            s += __half2float(__ushort_as_half((ushort)(e >> 17)));
        }
        s += __shfl_xor(s, 1, 64);          // combine the two halves (adjacent lanes)
        if (half == 0) wacc[nl] = s;
    }
    __syncthreads();
    // rare spills add to wacc
    int ns0 = *spill_cnt; if (ns0 > SPILL_MAX) ns0 = SPILL_MAX;
    if (ns0 > 0) {
        if (tid < BNODES) {
            float s = wacc[tid];
            for (int i = 0; i < ns0; i++) {
                int4 q = sp[i];
                if (q.y == lo + tid) s += __int_as_float(q.z);
            }
            wacc[tid] = s;
        }
        __syncthreads();
    }
    // dinv + fused y16 = dinv * x (coalesced, bucket-contiguous)
    if (tid < n) dinv[lo + tid] = rsqrtf(1.0f + wacc[tid]);
    {
        int nl = tid >> 1, half = tid & 1;
        if (nl < n) {
            float di = rsqrtf(1.0f + wacc[nl]);
            const float4* xr = (const float4*)(x + (size_t)(lo + nl) * 16 + half * 8);
            float4 va = xr[0], vb = xr[1];
            __half2 h0 = __floats2half2_rn(di * va.x, di * va.y);
            __half2 h1 = __floats2half2_rn(di * va.z, di * va.w);
            __half2 h2v = __floats2half2_rn(di * vb.x, di * vb.y);
            __half2 h3 = __floats2half2_rn(di * vb.z, di * vb.w);
            uint4* yr = (uint4*)(y16 + (size_t)(lo + nl) * 16 + half * 8);
            yr[0] = make_uint4(as_u32(h0), as_u32(h1), as_u32(h2v), as_u32(h3));
        }
    }
    // coalesced writeback of the full bucket region (entries + zero pads)
    {
        uint4* o4 = (uint4*)((uint*)ebuf + (size_t)b * (BCAP * 2));
        const uint4* t4 = (const uint4*)tbl;
        for (int i = tid; i < BNODES * 16; i += 256) o4[i] = t4[i];
    }
}

// fused: layer-1 gather (fixed 64-slot rows, 2 nodes/wave, packed fp16) + fp32 self
// + concurrent half-wave MLP with LDS-staged weights (W1s natural, W2T transposed).
__global__ __launch_bounds__(256) void k_gather_mlp(const uint* __restrict__ table,
                                                    const int4* __restrict__ sp,
                                                    const int* __restrict__ spill_cnt,
                                                    const float* __restrict__ dinv,
                                                    const __half* __restrict__ y16,
                                                    const float* __restrict__ x,
                                                    const float* __restrict__ W1,
                                                    const float* __restrict__ b1,
                                                    const float* __restrict__ W2,
                                                    const float* __restrict__ b2,
                                                    __half* __restrict__ h2,
                                                    float* __restrict__ out) {
    __shared__ float W1s[16 * 128];       // 8 KB, natural layout
    __shared__ float W2T[16 * 132];       // 8.25 KB, transposed, +4 pad per row
    __shared__ float fvs[8][16];
    __shared__ float o1s[4][2][128];      // natural layout (conflicts proven harmless)
    int wave = threadIdx.x >> 6, lane = threadIdx.x & 63;
    int tid = threadIdx.x;
    // stage weights once per block (coalesced reads; LDS scatter for transpose)
    {
        const float4* w1g = (const float4*)W1;
        float4* w1l = (float4*)W1s;
        for (int i = tid; i < 512; i += 256) w1l[i] = w1g[i];
        for (int j = tid; j < 2048; j += 256) {
            int kk = j >> 4, c = j & 15;
            W2T[c * 132 + kk] = W2[j];
        }
    }
    __syncthreads();                       // only barrier in the kernel
    int nsel = lane >> 5;            // which node of the wave's pair
    int hl   = lane & 31;            // lane within the node's half-wave
    int c2   = lane & 1;             // feature half (8 halfs each)
    int eo   = (lane >> 1) & 15;     // slot group (4 slots each)
    int bid  = blockIdx.x;
    int local = ((bid >> 3) * 4 + wave) * 2 + nsel;  // node index within XCD slab
    int node  = (bid & 7) * NPX + local;
    bool alive = (local < NPX);
    float di = dinv[node];
    int ns = *spill_cnt;                       // hoisted (uniform scalar)
    // hoisted self-term loads: in flight during the whole gather+reduce
    float4 xa = make_float4(0.f, 0.f, 0.f, 0.f), xb = xa;
    if (hl < 2 && alive) {
        const float4* xr = (const float4*)(x + (size_t)node * 16 + c2 * 8);
        xa = xr[0]; xb = xr[1];
    }
    float4 bv = *(const float4*)(b1 + 4 * hl);  // hoisted bias
    const uint* row = table + srow(node);
    uintx4 ev = __builtin_nontemporal_load(reinterpret_cast<const uintx4*>(row + 4 * eo));
    int s0 = ev.x & 0x1FFFF, s1 = ev.y & 0x1FFFF;
    int s2 = ev.z & 0x1FFFF, s3 = ev.w & 0x1FFFF;
    uint4 hv0 = *(const uint4*)(y16 + (size_t)s0 * 16 + c2 * 8);
    uint4 hv1 = *(const uint4*)(y16 + (size_t)s1 * 16 + c2 * 8);
    uint4 hv2 = *(const uint4*)(y16 + (size_t)s2 * 16 + c2 * 8);
    uint4 hv3 = *(const uint4*)(y16 + (size_t)s3 * 16 + c2 * 8);
    __half2 q0 = __half2half2(__ushort_as_half((ushort)(ev.x >> 17)));
    __half2 q1 = __half2half2(__ushort_as_half((ushort)(ev.y >> 17)));
    __half2 q2 = __half2half2(__ushort_as_half((ushort)(ev.z >> 17)));
    __half2 q3 = __half2half2(__ushort_as_half((ushort)(ev.w >> 17)));
    __half2 acc[4];
    acc[0] = __hmul2(q0, as_h2(hv0.x));
    acc[1] = __hmul2(q0, as_h2(hv0.y));
    acc[2] = __hmul2(q0, as_h2(hv0.z));
    acc[3] = __hmul2(q0, as_h2(hv0.w));
    acc[0] = __hfma2(q1, as_h2(hv1.x), acc[0]);
    acc[1] = __hfma2(q1, as_h2(hv1.y), acc[1]);
    acc[2] = __hfma2(q1, as_h2(hv1.z), acc[2]);
    acc[3] = __hfma2(q1, as_h2(hv1.w), acc[3]);
    acc[0] = __hfma2(q2, as_h2(hv2.x), acc[0]);
    acc[1] = __hfma2(q2, as_h2(hv2.y), acc[1]);
    acc[2] = __hfma2(q2, as_h2(hv2.z), acc[2]);
    acc[3] = __hfma2(q2, as_h2(hv2.w), acc[3]);
    acc[0] = __hfma2(q3, as_h2(hv3.x), acc[0]);
    acc[1] = __hfma2(q3, as_h2(hv3.y), acc[1]);
    acc[2] = __hfma2(q3, as_h2(hv3.z), acc[2]);
    acc[3] = __hfma2(q3, as_h2(hv3.w), acc[3]);
    // reduce across 16 slot-groups (lane bits 1..4); stays within 32-lane node half
#pragma unroll
    for (int m = 2; m < 32; m <<= 1) {
#pragma unroll
        for (int k = 0; k < 4; k++)
            acc[k] = __hadd2(acc[k], as_h2(__shfl_xor(as_u32(acc[k]), m, 64)));
    }
    if ((hl < 2) && alive) {
        float accf[8];
#pragma unroll
        for (int k = 0; k < 4; k++) {
            float2 f = __half22float2(acc[k]);
            accf[2 * k + 0] = f.x;
            accf[2 * k + 1] = f.y;
        }
        float slf[8] = {xa.x, xa.y, xa.z, xa.w, xb.x, xb.y, xb.z, xb.w};
        float r[8];
#pragma unroll
        for (int k = 0; k < 8; k++) r[k] = accf[k] + di * slf[k];
        if (ns > 0) {
            int nss = ns > SPILL_MAX ? SPILL_MAX : ns;
            for (int i = 0; i < nss; i++) {
                int4 q = sp[i];
                if (q.y == node) {
                    float f = __int_as_float(q.z);     // raw w; dinv_s already in y16
                    uint4 qv = *(const uint4*)(y16 + (size_t)q.x * 16 + c2 * 8);
                    float2 u0 = __half22float2(as_h2(qv.x));
                    float2 u1 = __half22float2(as_h2(qv.y));
                    float2 u2 = __half22float2(as_h2(qv.z));
                    float2 u3 = __half22float2(as_h2(qv.w));
                    float uv[8] = {u0.x, u0.y, u1.x, u1.y, u2.x, u2.y, u3.x, u3.y};
                    for (int k = 0; k < 8; k++) r[k] += f * uv[k];
                }
            }
        }
#pragma unroll
        for (int k = 0; k < 8; k++) fvs[wave * 2 + nsel][c2 * 8 + k] = r[k] * di;
    }
    // no barrier: fvs[wave*2+nsel] is wave-private, wave64 lockstep
    // MLP: both nodes concurrently; each half-wave owns its node.
    float fv[16];
#pragma unroll
    for (int k = 0; k < 16; k++) fv[k] = fvs[wave * 2 + nsel][k];
    // W1 from LDS: lane computes hidden outputs o = 4*hl + j
    float a0 = bv.x, a1 = bv.y, a2 = bv.z, a3 = bv.w;
#pragma unroll
    for (int k = 0; k < 16; k++) {
        float4 wv = *(const float4*)(W1s + k * 128 + 4 * hl);
        a0 = fmaf(fv[k], wv.x, a0);
        a1 = fmaf(fv[k], wv.y, a1);
        a2 = fmaf(fv[k], wv.z, a2);
        a3 = fmaf(fv[k], wv.w, a3);
    }
    // natural layout, single float4 store (contiguous across lanes)
    float* o1p = &o1s[wave][nsel][0];     // wave-private
    *(float4*)(o1p + 4 * hl) = make_float4(fmaxf(a0, 0.0f), fmaxf(a1, 0.0f),
                                           fmaxf(a2, 0.0f), fmaxf(a3, 0.0f));
    // W2 from LDS (transposed): output c = hl&15, K-half g = hl>>4
    int c = hl & 15, g = hl >> 4;
    const float4* o1v = (const float4*)(o1p + g * 64);        // broadcast reads
    const float4* w2v = (const float4*)(W2T + c * 132 + g * 64);
    float p = 0.0f;
#pragma unroll
    for (int k = 0; k < 16; k++) {
        float4 hv = o1v[k];
        float4 wv = w2v[k];
        p = fmaf(hv.x, wv.x, p);
        p = fmaf(hv.y, wv.y, p);
        p = fmaf(hv.z, wv.z, p);
        p = fmaf(hv.w, wv.w, p);
    }
    p += __shfl_down(p, 16, 64);          // combine the two K-halves (stays in node half)
    if (hl < 16 && alive) {
        h2[(size_t)node * 16 + c] = __float2half(di * p);   // pre-scaled by dinv_s
        out[(size_t)node * 16 + c] = di * di * p + b2[c];
    }
}

// layer-2 gather: out[node] += di * sum w*h2[s] (+spill); h2 pre-scaled by dinv_s.
// out RMW loads hoisted to entry.
__global__ __launch_bounds__(256) void k_gather2(const uint* __restrict__ table,
                                                 const int4* __restrict__ sp,
                                                 const int* __restrict__ spill_cnt,
                                                 const float* __restrict__ dinv,
                                                 const __half* __restrict__ h2,
                                                 float* __restrict__ out) {
    int wave = threadIdx.x >> 6, lane = threadIdx.x & 63;
    int nsel = lane >> 5;
    int hl   = lane & 31;
    int c2   = lane & 1;
    int eo   = (lane >> 1) & 15;
    int bid  = blockIdx.x;
    int local = ((bid >> 3) * 4 + wave) * 2 + nsel;
    int node  = (bid & 7) * NPX + local;
    bool alive = (local < NPX);
    float di = dinv[node];
    int ns = *spill_cnt;                       // hoisted (uniform scalar)
    // hoisted out RMW loads: in flight during the whole gather+reduce
    float4 o0 = make_float4(0.f, 0.f, 0.f, 0.f), o1 = o0;
    float4* op = (float4*)(out + (size_t)node * 16 + c2 * 8);
    if (hl < 2 && alive) { o0 = op[0]; o1 = op[1]; }
    const uint* row = table + srow(node);
    uintx4 ev = __builtin_nontemporal_load(reinterpret_cast<const uintx4*>(row + 4 * eo));
    int s0 = ev.x & 0x1FFFF, s1 = ev.y & 0x1FFFF;
    int s2 = ev.z & 0x1FFFF, s3 = ev.w & 0x1FFFF;
    uint4 hv0 = *(const uint4*)(h2 + (size_t)s0 * 16 + c2 * 8);
    uint4 hv1 = *(const uint4*)(h2 + (size_t)s1 * 16 + c2 * 8);
    uint4 hv2 = *(const uint4*)(h2 + (size_t)s2 * 16 + c2 * 8);
    uint4 hv3 = *(const uint4*)(h2 + (size_t)s3 * 16 + c2 * 8);
    __half2 q0 = __half2half2(__ushort_as_half((ushort)(ev.x >> 17)));
    __half2 q1 = __half2half2(__ushort_as_half((ushort)(ev.y >> 17)));
    __half2 q2 = __half2half2(__ushort_as_half((ushort)(ev.z >> 17)));
    __half2 q3 = __half2half2(__ushort_as_half((ushort)(ev.w >> 17)));
    __half2 acc[4];
    acc[0] = __hmul2(q0, as_h2(hv0.x));
    acc[1] = __hmul2(q0, as_h2(hv0.y));
    acc[2] = __hmul2(q0, as_h2(hv0.z));
    acc[3] = __hmul2(q0, as_h2(hv0.w));
    acc[0] = __hfma2(q1, as_h2(hv1.x), acc[0]);
    acc[1] = __hfma2(q1, as_h2(hv1.y), acc[1]);
    acc[2] = __hfma2(q1, as_h2(hv1.z), acc[2]);
    acc[3] = __hfma2(q1, as_h2(hv1.w), acc[3]);
    acc[0] = __hfma2(q2, as_h2(hv2.x), acc[0]);
    acc[1] = __hfma2(q2, as_h2(hv2.y), acc[1]);
    acc[2] = __hfma2(q2, as_h2(hv2.z), acc[2]);
    acc[3] = __hfma2(q2, as_h2(hv2.w), acc[3]);
    acc[0] = __hfma2(q3, as_h2(hv3.x), acc[0]);
    acc[1] = __hfma2(q3, as_h2(hv3.y), acc[1]);
    acc[2] = __hfma2(q3, as_h2(hv3.z), acc[2]);
    acc[3] = __hfma2(q3, as_h2(hv3.w), acc[3]);
#pragma unroll
    for (int m = 2; m < 32; m <<= 1) {
#pragma unroll
        for (int k = 0; k < 4; k++)
            acc[k] = __hadd2(acc[k], as_h2(__shfl_xor(as_u32(acc[k]), m, 64)));
    }
    if ((hl < 2) && alive) {
        float accf[8];
#pragma unroll
        for (int k = 0; k < 4; k++) {
            float2 f = __half22float2(acc[k]);
            accf[2 * k + 0] = f.x;
            accf[2 * k + 1] = f.y;
        }
        if (ns > 0) {
            int nss = ns > SPILL_MAX ? SPILL_MAX : ns;
            for (int i = 0; i < nss; i++) {
                int4 q = sp[i];
                if (q.y == node) {
                    float f = __int_as_float(q.z);
                    uint4 qv = *(const uint4*)(h2 + (size_t)q.x * 16 + c2 * 8);
                    float2 u0 = __half22float2(as_h2(qv.x));
                    float2 u1 = __half22float2(as_h2(qv.y));
                    float2 u2 = __half22float2(as_h2(qv.z));
                    float2 u3 = __half22float2(as_h2(qv.w));
                    float uv[8] = {u0.x, u0.y, u1.x, u1.y, u2.x, u2.y, u3.x, u3.y};
                    for (int k = 0; k < 8; k++) accf[k] += f * uv[k];
                }
            }
        }
        o0.x += di * accf[0]; o0.y += di * accf[1];
        o0.z += di * accf[2]; o0.w += di * accf[3];
        o1.x += di * accf[4]; o1.y += di * accf[5];
        o1.z += di * accf[6]; o1.w += di * accf[7];
        op[0] = o0; op[1] = o1;
    }
}

// ===================== CSR fallback (round-2) =====================

__global__ void k_init(float* __restrict__ deg, int* __restrict__ cnt) {
    int i = blockIdx.x * blockDim.x + threadIdx.x;
    if (i < N_NODES) { deg[i] = 1.0f; if (cnt) cnt[i] = 0; }
}

__global__ void k_degcnt(const int* __restrict__ dst, const float* __restrict__ w,
                         float* __restrict__ deg, int* __restrict__ cnt) {
    int e = blockIdx.x * blockDim.x + threadIdx.x;
    if (e < N_EDGES) {
        int d = dst[e];
        atomicAdd(&deg[d], w[e]);
        if (cnt) atomicAdd(&cnt[d], 1);
    }
}

__global__ void k_dinv_agg(const float* __restrict__ x, float* __restrict__ deg_dinv,
                           float* __restrict__ agg) {
    int i = blockIdx.x * blockDim.x + threadIdx.x;
    if (i >= N_NODES) return;
    float di = rsqrtf(deg_dinv[i]);
    deg_dinv[i] = di;
    float s = di * di;
    const float4* xr = (const float4*)(x + (size_t)i * 16);
    float4* ar = (float4*)(agg + (size_t)i * 16);
#pragma unroll
    for (int k = 0; k < 4; k++) {
        float4 v = xr[k];
        v.x *= s; v.y *= s; v.z *= s; v.w *= s;
        ar[k] = v;
    }
}

__global__ __launch_bounds__(256) void k_scan1(const int* __restrict__ cnt,
                                               int* __restrict__ rowptr,
                                               int* __restrict__ bsum) {
    __shared__ int ts[256];
    int tid = threadIdx.x;
    int base = blockIdx.x * SCAN_CHUNK + tid * 8;
    int v[8]; int s = 0;
#pragma unroll
    for (int k = 0; k < 8; k++) {
        int idx = base + k;
        v[k] = (idx < N_NODES) ? cnt[idx] : 0;
        s += v[k];
    }
    ts[tid] = s;
    __syncthreads();
    for (int off = 1; off < 256; off <<= 1) {
        int t = (tid >= off) ? ts[tid - off] : 0;
        __syncthreads();
        ts[tid] += t;
        __syncthreads();
    }
    int run = ts[tid] - s;
#pragma unroll
    for (int k = 0; k < 8; k++) {
        int idx = base + k;
        if (idx < N_NODES) rowptr[idx] = run;
        run += v[k];
    }
    if (tid == 255) bsum[blockIdx.x] = ts[255];
}

__global__ void k_scan2(int* __restrict__ bsum) {
    if (threadIdx.x == 0 && blockIdx.x == 0) {
        int run = 0;
        for (int g = 0; g < SCAN_BLOCKS; g++) { int t = bsum[g]; bsum[g] = run; run += t; }
    }
}

__global__ __launch_bounds__(256) void k_scan3(int* __restrict__ rowptr,
                                               const int* __restrict__ bsum) {
    int tid = threadIdx.x;
    int base = blockIdx.x * SCAN_CHUNK + tid * 8;
    int off = bsum[blockIdx.x];
#pragma unroll
    for (int k = 0; k < 8; k++) {
        int idx = base + k;
        if (idx < N_NODES) rowptr[idx] += off;
    }
    if (blockIdx.x == 0 && tid == 0) rowptr[N_NODES] = N_EDGES;
}

__global__ void k_fill(const int* __restrict__ src, const int* __restrict__ dst,
                       const float* __restrict__ w, const float* __restrict__ dinv,
                       const int* __restrict__ rowptr, int* __restrict__ cnt,
                       int2* __restrict__ perm) {
    int e = blockIdx.x * blockDim.x + threadIdx.x;
    if (e >= N_EDGES) return;
    int s = src[e], d = dst[e];
    float nrm = dinv[s] * w[e] * dinv[d];
    int r = atomicSub(&cnt[d], 1) - 1;
    int pos = rowptr[d] + r;
    perm[pos] = make_int2(s, __float_as_int(nrm));
}

__global__ __launch_bounds__(256) void k_gather(const int2* __restrict__ perm,
                                                const int* __restrict__ rowptr,
                                                const float* __restrict__ feat,
                                                float* __restrict__ out) {
    int wave = threadIdx.x >> 6, lane = threadIdx.x & 63;
    int node = blockIdx.x * 4 + wave;
    int c = lane & 15, eo = lane >> 4;
    int beg = rowptr[node], end = rowptr[node + 1];
    float acc = 0.0f;
    for (int j = beg + eo; j < end; j += 4) {
        int2 ed = perm[j];
        acc = fmaf(__int_as_float(ed.y), feat[(size_t)ed.x * 16 + c], acc);
    }
    acc += __shfl_xor(acc, 16, 64);
    acc += __shfl_xor(acc, 32, 64);
    if (lane < 16) out[(size_t)node * 16 + c] += acc;
}

__global__ __launch_bounds__(256) void k_mlp(float* __restrict__ agg,
                                             const float* __restrict__ W1,
                                             const float* __restrict__ b1,
                                             const float* __restrict__ W2,
                                             const float* __restrict__ b2,
                                             const float* __restrict__ dinv,
                                             float* __restrict__ out) {
    __shared__ float o1s[4][128];
    int wave = threadIdx.x >> 6;
    int lane = threadIdx.x & 63;
    int node = blockIdx.x * 4 + wave;
    const float* f = agg + (size_t)node * 16;
    float fv[16];
#pragma unroll
    for (int k = 0; k < 4; k++) {
        float4 v = ((const float4*)f)[k];
        fv[4 * k + 0] = v.x; fv[4 * k + 1] = v.y; fv[4 * k + 2] = v.z; fv[4 * k + 3] = v.w;
    }
    float a = b1[2 * lane], b = b1[2 * lane + 1];
#pragma unroll
    for (int k = 0; k < 16; k++) {
        float2 wv = *(const float2*)(W1 + k * 128 + 2 * lane);
        a = fmaf(fv[k], wv.x, a);
        b = fmaf(fv[k], wv.y, b);
    }
    o1s[wave][2 * lane + 0] = fmaxf(a, 0.0f);
    o1s[wave][2 * lane + 1] = fmaxf(b, 0.0f);
    __syncthreads();
    int c = lane & 15, g = lane >> 4;
    float p = 0.0f;
#pragma unroll
    for (int k = 0; k < 32; k++) {
        int kk = g * 32 + k;
        p = fmaf(o1s[wave][kk], W2[kk * 16 + c], p);
    }
    p += __shfl_down(p, 16, 64);
    p += __shfl_down(p, 32, 64);
    __syncthreads();
    if (lane < 16) {
        float h2v = p;
        agg[(size_t)node * 16 + c] = h2v;
        float di = dinv[node];
        out[(size_t)node * 16 + c] = di * di * h2v + b2[c];
    }
}

__global__ void k_scatter(const int* __restrict__ src, const int* __restrict__ dst,
                          const float* __restrict__ w, const float* __restrict__ dinv,
                          const float* __restrict__ feat, float* __restrict__ out) {
    int t = blockIdx.x * blockDim.x + threadIdx.x;
    int e = t >> 2;
    int c4 = (t & 3) * 4;
    if (e >= N_EDGES) return;
    int s = src[e], d = dst[e];
    float nrm = dinv[s] * w[e] * dinv[d];
    float4 v = *(const float4*)(feat + (size_t)s * 16 + c4);
    float* o = out + (size_t)d * 16 + c4;
    atomicAdd(o + 0, nrm * v.x);
    atomicAdd(o + 1, nrm * v.y);
    atomicAdd(o + 2, nrm * v.z);
    atomicAdd(o + 3, nrm * v.w);
}

// ===================== launch =====================

extern "C" void kernel_launch(void* const* d_in, const int* in_sizes, int n_in,
                              void* d_out, int out_size, void* d_ws, size_t ws_size,
                              hipStream_t stream) {
    const float* x  = (const float*)d_in[0];
    const int*   ei = (const int*)d_in[1];
    const float* w  = (const float*)d_in[2];
    const float* W1 = (const float*)d_in[3];
    const float* b1 = (const float*)d_in[4];
    const float* W2 = (const float*)d_in[5];
    const float* b2 = (const float*)d_in[6];
    float* out = (float*)d_out;

    const int* src = ei;
    const int* dst = ei + N_EDGES;
    const int B = 256;

    // ---- fast-path workspace layout (16B-aligned blocks) ----
    char* p = (char*)d_ws;
    int*    bucket_cnt = (int*)p;        p += (size_t)((NBUCK + 3) & ~3) * 4;
    int*    spill_cnt  = (int*)p;        p += 16;
    float*  dinv       = (float*)p;      p += (size_t)N_PAD * 4;
    __half* y16        = (__half*)p;     p += (size_t)N_NODES * 16 * 2;
    __half* h2         = (__half*)p;     p += (size_t)N_NODES * 16 * 2;
    int4*   sp         = (int4*)p;       p += (size_t)SPILL_MAX * 16;
    uint2*  ebuf       = (uint2*)p;      p += (size_t)NBUCK * BCAP * 8;
    const size_t WS_FAST = (size_t)(p - (char*)d_ws);

    if (ws_size >= WS_FAST) {
        k_pre0<<<(NBUCK + B - 1) / B, B, 0, stream>>>(bucket_cnt, spill_cnt);
        k_bin<<<BIN_BLOCKS, B, 0, stream>>>(src, dst, w, bucket_cnt, ebuf, sp, spill_cnt);
        k_sortz<<<NBUCK, B, 0, stream>>>(ebuf, bucket_cnt, sp, spill_cnt, x, dinv, y16);
        k_gather_mlp<<<GBLK, B, 0, stream>>>((const uint*)ebuf, sp, spill_cnt, dinv,
                                             y16, x, W1, b1, W2, b2, h2, out);
        k_gather2<<<GBLK, B, 0, stream>>>((const uint*)ebuf, sp, spill_cnt, dinv,
                                          h2, out);
        return;
    }

    // ---- CSR fallback (round-2 path) ----
    float* deg_dinv = (float*)d_ws;
    int*   cntb     = (int*)(deg_dinv + N_PAD);
    int*   rowptr   = cntb + N_PAD;
    int*   bsum     = rowptr + N_PAD;
    float* agg      = (float*)(bsum + 64);
    int2*  perm     = (int2*)(agg + (size_t)N_NODES * 16);
    const size_t WS_CSR = ((size_t)N_PAD * 3 + 64 + (size_t)N_NODES * 16) * 4
                          + (size_t)N_EDGES * 8;

    if (ws_size >= WS_CSR) {
        k_init<<<(N_NODES + B - 1) / B, B, 0, stream>>>(deg_dinv, cntb);
        k_degcnt<<<(N_EDGES + B - 1) / B, B, 0, stream>>>(dst, w, deg_dinv, cntb);
        k_dinv_agg<<<(N_NODES + B - 1) / B, B, 0, stream>>>(x, deg_dinv, agg);
        k_scan1<<<SCAN_BLOCKS, 256, 0, stream>>>(cntb, rowptr, bsum);
        k_scan2<<<1, 64, 0, stream>>>(bsum);
        k_scan3<<<SCAN_BLOCKS, 256, 0, stream>>>(rowptr, bsum);
        k_fill<<<(N_EDGES + B - 1) / B, B, 0, stream>>>(src, dst, w, deg_dinv,
                                                        rowptr, cntb, perm);
        k_gather<<<N_NODES / 4, B, 0, stream>>>(perm, rowptr, x, agg);
        k_mlp<<<N_NODES / 4, B, 0, stream>>>(agg, W1, b1, W2, b2, deg_dinv, out);
        k_gather<<<N_NODES / 4, B, 0, stream>>>(perm, rowptr, agg, out);
    } else {
        float* deg = (float*)d_ws;
        float* ag  = (float*)d_ws + N_NODES;
        k_init<<<(N_NODES + B - 1) / B, B, 0, stream>>>(deg, (int*)nullptr);
        k_degcnt<<<(N_EDGES + B - 1) / B, B, 0, stream>>>(dst, w, deg, (int*)nullptr);
        k_dinv_agg<<<(N_NODES + B - 1) / B, B, 0, stream>>>(x, deg, ag);
        k_scatter<<<((size_t)N_EDGES * 4 + B - 1) / B, B, 0, stream>>>(src, dst, w, deg, x, ag);
        k_mlp<<<N_NODES / 4, B, 0, stream>>>(ag, W1, b1, W2, b2, deg, out);
        k_scatter<<<((size_t)N_EDGES * 4 + B - 1) / B, B, 0, stream>>>(src, dst, w, deg, ag, out);
    }
}

// Round 17
// 213.477 us; speedup vs baseline: 1.2159x; 1.0015x over previous
//
#include <hip/hip_runtime.h>
#include <hip/hip_fp16.h>

#define N_NODES 100000
#define N_EDGES 3200000
#define N_PAD   100096
#define BNODES  128
#define NBUCK   ((N_NODES + BNODES - 1) / BNODES)       // 782
#define BCAP    4800                                    // mean 4096, sigma 64 (11 sigma)
#define EPB_BIN 4096                                    // edges per bin block (16/thread)
#define BIN_BLOCKS ((N_EDGES + EPB_BIN - 1) / EPB_BIN)  // 782
#define SPILL_MAX 65536
#define NPX      (N_NODES / 8)                          // 12500 nodes per XCD slab
#define GBLK     (8 * ((NPX + 7) / 8))                  // 12504 gather blocks (8 nodes each)
#define SCAN_CHUNK 2048
#define SCAN_BLOCKS ((N_NODES + SCAN_CHUNK - 1) / SCAN_CHUNK)

typedef unsigned int uint;
typedef unsigned short ushort;
typedef unsigned long long ull;
typedef uint uintx4 __attribute__((ext_vector_type(4)));   // native vector for nontemporal builtin

__device__ __forceinline__ __half2 as_h2(uint u) { return *reinterpret_cast<__half2*>(&u); }
__device__ __forceinline__ uint as_u32(__half2 h) { return *reinterpret_cast<uint*>(&h); }

// fixed-stride row address inside the bucket region (bucket stride BCAP*2 uints)
__device__ __forceinline__ size_t srow(int n) {
    return (size_t)(n >> 7) * (BCAP * 2) + (size_t)(n & 127) * 64;
}

// ===================== fast path: pre0 -> bin -> sortz -> gather =====================

// zero bucket_cnt + spill_cnt only
__global__ __launch_bounds__(256) void k_pre0(int* __restrict__ bucket_cnt,
                                              int* __restrict__ spill_cnt) {
    int i = blockIdx.x * 256 + threadIdx.x;
    if (i < NBUCK) bucket_cnt[i] = 0;
    if (i == 0) *spill_cnt = 0;
}

// counting-sort edges into 782 dst-buckets. REGISTER-STAGED single global pass.
__global__ __launch_bounds__(256) void k_bin(const int* __restrict__ src,
                                             const int* __restrict__ dst,
                                             const float* __restrict__ w,
                                             int* __restrict__ bucket_cnt,
                                             uint2* __restrict__ ebuf,
                                             int4* __restrict__ sp,
                                             int* __restrict__ spill_cnt) {
    __shared__ int    hist[NBUCK];          // 3.1 KB (re-zeroed as rank for pass 2)
    __shared__ ushort pref[NBUCK];          // 1.5 KB  block-local exclusive prefix
    __shared__ ushort base[NBUCK];          // 1.5 KB  global run start for this block
    __shared__ int    psum[256];            // 1 KB
    __shared__ uint2  sorted[EPB_BIN];      // 32 KB   entries, (b&255) in bits 24-31
    int tid = threadIdx.x;
    for (int b = tid; b < NBUCK; b += 256) hist[b] = 0;
    __syncthreads();
    int e0 = blockIdx.x * EPB_BIN;
    // pass 1: single global read; stage entries in registers; histogram dst
    uint ent[16]; uint wv[16]; ushort bb[16];
#pragma unroll
    for (int k = 0; k < 16; k++) {
        int e = e0 + tid + k * 256;
        if (e < N_EDGES) {
            int d = dst[e];
            int s = src[e];
            float wf = w[e];
            int b = d >> 7;
            ent[k] = ((uint)(b & 255) << 24) | ((uint)(d & 127) << 17) | (uint)s;
            wv[k] = __float_as_uint(wf);
            bb[k] = (ushort)b;
            atomicAdd(&hist[b], 1);
        } else {
            bb[k] = 0xFFFF;
        }
    }
    __syncthreads();
    // reserve global bases (positions < BCAP << 65536 -> ushort)
    for (int b = tid; b < NBUCK; b += 256) {
        int c = hist[b];
        base[b] = (ushort)(c ? atomicAdd(&bucket_cnt[b], c) : 0);
    }
    // block-wide exclusive scan of hist -> pref (thread t owns elements 4t..4t+3)
    int loc[4]; int s4 = 0;
#pragma unroll
    for (int j = 0; j < 4; j++) {
        int idx = tid * 4 + j;
        int h = (idx < NBUCK) ? hist[idx] : 0;
        loc[j] = s4; s4 += h;
    }
    psum[tid] = s4;
    __syncthreads();
    for (int off = 1; off < 256; off <<= 1) {
        int t = (tid >= off) ? psum[tid - off] : 0;
        __syncthreads();
        psum[tid] += t;
        __syncthreads();
    }
    int run = psum[tid] - s4;               // exclusive across threads
#pragma unroll
    for (int j = 0; j < 4; j++) {
        int idx = tid * 4 + j;
        if (idx < NBUCK) pref[idx] = (ushort)(run + loc[j]);
    }
    __syncthreads();
    // re-zero hist -> rank
    for (int b = tid; b < NBUCK; b += 256) hist[b] = 0;
    __syncthreads();
    // pass 2 (register-resident): pure LDS-atomic + LDS store, no global loads
#pragma unroll
    for (int k = 0; k < 16; k++) {
        if (bb[k] != 0xFFFF) {
            int b = (int)bb[k];
            int p = (int)pref[b] + atomicAdd(&hist[b], 1);
            sorted[p] = make_uint2(ent[k], wv[k]);
        }
    }
    __syncthreads();
    // run-ordered writeback; recover b = (k<<8)|low8 via positional thresholds
    int t1 = pref[256], t2 = pref[512], t3 = pref[768];
    int nval = N_EDGES - e0; if (nval > EPB_BIN) nval = EPB_BIN;
    for (int p = tid; p < nval; p += 256) {
        uint2 v = sorted[p];
        int b = ((int)(v.x >> 24)) | (((p >= t1) + (p >= t2) + (p >= t3)) << 8);
        int gpos = (int)base[b] + (p - (int)pref[b]);
        uint vx = v.x & 0x00FFFFFF;
        if (gpos < BCAP) {
            ebuf[(size_t)b * BCAP + gpos] = make_uint2(vx, v.y);
        } else {
            int oi = atomicAdd(spill_cnt, 1);
            if (oi < SPILL_MAX)
                sp[oi] = make_int4((int)(vx & 0x1FFFF), b * 128 + (int)(vx >> 17),
                                   (int)v.y, 0);
        }
    }
}

// per-bucket: SINGLE pass: scatter into zero-initialized 32KB LDS staging,
// per-node weighted degree without atomics, dinv + fused y16, coalesced writeback.
__global__ __launch_bounds__(256) void k_sortz(uint2* __restrict__ ebuf,
                                               const int* __restrict__ bucket_cnt,
                                               int4* __restrict__ sp,
                                               int* __restrict__ spill_cnt,
                                               const float* __restrict__ x,
                                               float* __restrict__ dinv,
                                               __half* __restrict__ y16) {
    __shared__ uint  tbl[BNODES * 64];   // 32 KB staging (4B entries, incl. zero pads)
    __shared__ float wacc[BNODES];
    __shared__ int   curs[BNODES];
    int b = blockIdx.x, tid = threadIdx.x;
    int lo = b * BNODES;
    int n = N_NODES - lo; if (n > BNODES) n = BNODES;
    if (tid < BNODES) curs[tid] = 0;
    {   // zero the staging table (2048 uint4 stores)
        uint4* t4 = (uint4*)tbl;
        for (int i = tid; i < BNODES * 16; i += 256) t4[i] = make_uint4(0, 0, 0, 0);
    }
    __syncthreads();
    int cnt = bucket_cnt[b]; if (cnt > BCAP) cnt = BCAP;
    const uint2* srcrow = ebuf + (size_t)b * BCAP;
    // single pass: scatter into LDS staging; entry = (fp16(w)<<17)|src
    for (int j = tid; j < cnt; j += 256) {
        uint2 e = srcrow[j];
        int nl = e.x >> 17;
        int pos = atomicAdd(&curs[nl], 1);
        if (pos < 64) {
            uint wh = (uint)__half_as_ushort(__float2half(__uint_as_float(e.y)));
            tbl[nl * 64 + pos] = (wh << 17) | (e.x & 0x1FFFF);
        } else {
            // rare overflow (degree > 64): global spill, handled by gathers
            int oi = atomicAdd(spill_cnt, 1);
            if (oi < SPILL_MAX)
                sp[oi] = make_int4((int)(e.x & 0x1FFFF), lo + nl, (int)e.y, 0);
        }
    }
    __syncthreads();
    // per-node weighted degree from staged table, no atomics
    {
        int nl = tid >> 1, half = tid & 1;
        float s = 0.0f;
        int basei = nl * 64 + half * 32;
#pragma unroll 8
        for (int k = 0; k < 32; k++) {
            uint e = tbl[basei + ((k + tid) & 31)];
            s += __half2float(__ushort_as_half((ushort)(e >> 17)));
        }
        s += __shfl_xor(s, 1, 64);          // combine the two halves (adjacent lanes)
        if (half == 0) wacc[nl] = s;
    }
    __syncthreads();
    // rare spills add to wacc
    int ns0 = *spill_cnt; if (ns0 > SPILL_MAX) ns0 = SPILL_MAX;
    if (ns0 > 0) {
        if (tid < BNODES) {
            float s = wacc[tid];
            for (int i = 0; i < ns0; i++) {
                int4 q = sp[i];
                if (q.y == lo + tid) s += __int_as_float(q.z);
            }
            wacc[tid] = s;
        }
        __syncthreads();
    }
    // dinv + fused y16 = dinv * x (coalesced, bucket-contiguous)
    if (tid < n) dinv[lo + tid] = rsqrtf(1.0f + wacc[tid]);
    {
        int nl = tid >> 1, half = tid & 1;
        if (nl < n) {
            float di = rsqrtf(1.0f + wacc[nl]);
            const float4* xr = (const float4*)(x + (size_t)(lo + nl) * 16 + half * 8);
            float4 va = xr[0], vb = xr[1];
            __half2 h0 = __floats2half2_rn(di * va.x, di * va.y);
            __half2 h1 = __floats2half2_rn(di * va.z, di * va.w);
            __half2 h2v = __floats2half2_rn(di * vb.x, di * vb.y);
            __half2 h3 = __floats2half2_rn(di * vb.z, di * vb.w);
            uint4* yr = (uint4*)(y16 + (size_t)(lo + nl) * 16 + half * 8);
            yr[0] = make_uint4(as_u32(h0), as_u32(h1), as_u32(h2v), as_u32(h3));
        }
    }
    // coalesced writeback of the full bucket region (entries + zero pads)
    {
        uint4* o4 = (uint4*)((uint*)ebuf + (size_t)b * (BCAP * 2));
        const uint4* t4 = (const uint4*)tbl;
        for (int i = tid; i < BNODES * 16; i += 256) o4[i] = t4[i];
    }
}

// fused: layer-1 gather (fixed 64-slot rows, 2 nodes/wave, packed fp16) + fp32 self
// + concurrent half-wave MLP. W2 staged transposed in LDS; W1 read DIRECTLY from
// global (coalesced float4, L1/L2-hot after first block) -> LDS 21.5->13.25KB ->
// occupancy ceiling 7 blocks(28 waves) -> 8 blocks(32 waves)/CU.
__global__ __launch_bounds__(256) void k_gather_mlp(const uint* __restrict__ table,
                                                    const int4* __restrict__ sp,
                                                    const int* __restrict__ spill_cnt,
                                                    const float* __restrict__ dinv,
                                                    const __half* __restrict__ y16,
                                                    const float* __restrict__ x,
                                                    const float* __restrict__ W1,
                                                    const float* __restrict__ b1,
                                                    const float* __restrict__ W2,
                                                    const float* __restrict__ b2,
                                                    __half* __restrict__ h2,
                                                    float* __restrict__ out) {
    __shared__ float W2T[16 * 132];       // 8.25 KB, transposed, +4 pad per row
    __shared__ float fvs[8][16];
    __shared__ float o1s[4][2][128];      // natural layout (conflicts proven harmless)
    int wave = threadIdx.x >> 6, lane = threadIdx.x & 63;
    int tid = threadIdx.x;
    // stage W2 transposed once per block (coalesced reads; LDS scatter)
    for (int j = tid; j < 2048; j += 256) {
        int kk = j >> 4, c = j & 15;
        W2T[c * 132 + kk] = W2[j];
    }
    __syncthreads();                       // only barrier in the kernel
    int nsel = lane >> 5;            // which node of the wave's pair
    int hl   = lane & 31;            // lane within the node's half-wave
    int c2   = lane & 1;             // feature half (8 halfs each)
    int eo   = (lane >> 1) & 15;     // slot group (4 slots each)
    int bid  = blockIdx.x;
    int local = ((bid >> 3) * 4 + wave) * 2 + nsel;  // node index within XCD slab
    int node  = (bid & 7) * NPX + local;
    bool alive = (local < NPX);
    float di = dinv[node];
    int ns = *spill_cnt;                       // hoisted (uniform scalar)
    // hoisted self-term loads: in flight during the whole gather+reduce
    float4 xa = make_float4(0.f, 0.f, 0.f, 0.f), xb = xa;
    if (hl < 2 && alive) {
        const float4* xr = (const float4*)(x + (size_t)node * 16 + c2 * 8);
        xa = xr[0]; xb = xr[1];
    }
    float4 bv = *(const float4*)(b1 + 4 * hl);  // hoisted bias
    const uint* row = table + srow(node);
    uintx4 ev = __builtin_nontemporal_load(reinterpret_cast<const uintx4*>(row + 4 * eo));
    int s0 = ev.x & 0x1FFFF, s1 = ev.y & 0x1FFFF;
    int s2 = ev.z & 0x1FFFF, s3 = ev.w & 0x1FFFF;
    uint4 hv0 = *(const uint4*)(y16 + (size_t)s0 * 16 + c2 * 8);
    uint4 hv1 = *(const uint4*)(y16 + (size_t)s1 * 16 + c2 * 8);
    uint4 hv2 = *(const uint4*)(y16 + (size_t)s2 * 16 + c2 * 8);
    uint4 hv3 = *(const uint4*)(y16 + (size_t)s3 * 16 + c2 * 8);
    __half2 q0 = __half2half2(__ushort_as_half((ushort)(ev.x >> 17)));
    __half2 q1 = __half2half2(__ushort_as_half((ushort)(ev.y >> 17)));
    __half2 q2 = __half2half2(__ushort_as_half((ushort)(ev.z >> 17)));
    __half2 q3 = __half2half2(__ushort_as_half((ushort)(ev.w >> 17)));
    __half2 acc[4];
    acc[0] = __hmul2(q0, as_h2(hv0.x));
    acc[1] = __hmul2(q0, as_h2(hv0.y));
    acc[2] = __hmul2(q0, as_h2(hv0.z));
    acc[3] = __hmul2(q0, as_h2(hv0.w));
    acc[0] = __hfma2(q1, as_h2(hv1.x), acc[0]);
    acc[1] = __hfma2(q1, as_h2(hv1.y), acc[1]);
    acc[2] = __hfma2(q1, as_h2(hv1.z), acc[2]);
    acc[3] = __hfma2(q1, as_h2(hv1.w), acc[3]);
    acc[0] = __hfma2(q2, as_h2(hv2.x), acc[0]);
    acc[1] = __hfma2(q2, as_h2(hv2.y), acc[1]);
    acc[2] = __hfma2(q2, as_h2(hv2.z), acc[2]);
    acc[3] = __hfma2(q2, as_h2(hv2.w), acc[3]);
    acc[0] = __hfma2(q3, as_h2(hv3.x), acc[0]);
    acc[1] = __hfma2(q3, as_h2(hv3.y), acc[1]);
    acc[2] = __hfma2(q3, as_h2(hv3.z), acc[2]);
    acc[3] = __hfma2(q3, as_h2(hv3.w), acc[3]);
    // reduce across 16 slot-groups (lane bits 1..4); stays within 32-lane node half
#pragma unroll
    for (int m = 2; m < 32; m <<= 1) {
#pragma unroll
        for (int k = 0; k < 4; k++)
            acc[k] = __hadd2(acc[k], as_h2(__shfl_xor(as_u32(acc[k]), m, 64)));
    }
    if ((hl < 2) && alive) {
        float accf[8];
#pragma unroll
        for (int k = 0; k < 4; k++) {
            float2 f = __half22float2(acc[k]);
            accf[2 * k + 0] = f.x;
            accf[2 * k + 1] = f.y;
        }
        float slf[8] = {xa.x, xa.y, xa.z, xa.w, xb.x, xb.y, xb.z, xb.w};
        float r[8];
#pragma unroll
        for (int k = 0; k < 8; k++) r[k] = accf[k] + di * slf[k];
        if (ns > 0) {
            int nss = ns > SPILL_MAX ? SPILL_MAX : ns;
            for (int i = 0; i < nss; i++) {
                int4 q = sp[i];
                if (q.y == node) {
                    float f = __int_as_float(q.z);     // raw w; dinv_s already in y16
                    uint4 qv = *(const uint4*)(y16 + (size_t)q.x * 16 + c2 * 8);
                    float2 u0 = __half22float2(as_h2(qv.x));
                    float2 u1 = __half22float2(as_h2(qv.y));
                    float2 u2 = __half22float2(as_h2(qv.z));
                    float2 u3 = __half22float2(as_h2(qv.w));
                    float uv[8] = {u0.x, u0.y, u1.x, u1.y, u2.x, u2.y, u3.x, u3.y};
                    for (int k = 0; k < 8; k++) r[k] += f * uv[k];
                }
            }
        }
#pragma unroll
        for (int k = 0; k < 8; k++) fvs[wave * 2 + nsel][c2 * 8 + k] = r[k] * di;
    }
    // no barrier: fvs[wave*2+nsel] is wave-private, wave64 lockstep
    // MLP: both nodes concurrently; each half-wave owns its node.
    float fv[16];
#pragma unroll
    for (int k = 0; k < 16; k++) fv[k] = fvs[wave * 2 + nsel][k];
    // W1 DIRECT from global (coalesced float4, L1/L2-hot): outputs o = 4*hl + j
    float a0 = bv.x, a1 = bv.y, a2 = bv.z, a3 = bv.w;
#pragma unroll
    for (int k = 0; k < 16; k++) {
        float4 wv = *(const float4*)(W1 + k * 128 + 4 * hl);
        a0 = fmaf(fv[k], wv.x, a0);
        a1 = fmaf(fv[k], wv.y, a1);
        a2 = fmaf(fv[k], wv.z, a2);
        a3 = fmaf(fv[k], wv.w, a3);
    }
    // natural layout, single float4 store (contiguous across lanes)
    float* o1p = &o1s[wave][nsel][0];     // wave-private
    *(float4*)(o1p + 4 * hl) = make_float4(fmaxf(a0, 0.0f), fmaxf(a1, 0.0f),
                                           fmaxf(a2, 0.0f), fmaxf(a3, 0.0f));
    // W2 from LDS (transposed): output c = hl&15, K-half g = hl>>4
    int c = hl & 15, g = hl >> 4;
    const float4* o1v = (const float4*)(o1p + g * 64);        // broadcast reads
    const float4* w2v = (const float4*)(W2T + c * 132 + g * 64);
    float p = 0.0f;
#pragma unroll
    for (int k = 0; k < 16; k++) {
        float4 hv = o1v[k];
        float4 wv = w2v[k];
        p = fmaf(hv.x, wv.x, p);
        p = fmaf(hv.y, wv.y, p);
        p = fmaf(hv.z, wv.z, p);
        p = fmaf(hv.w, wv.w, p);
    }
    p += __shfl_down(p, 16, 64);          // combine the two K-halves (stays in node half)
    if (hl < 16 && alive) {
        h2[(size_t)node * 16 + c] = __float2half(di * p);   // pre-scaled by dinv_s
        out[(size_t)node * 16 + c] = di * di * p + b2[c];
    }
}

// layer-2 gather: out[node] += di * sum w*h2[s] (+spill); h2 pre-scaled by dinv_s.
// out RMW loads hoisted to entry.
__global__ __launch_bounds__(256) void k_gather2(const uint* __restrict__ table,
                                                 const int4* __restrict__ sp,
                                                 const int* __restrict__ spill_cnt,
                                                 const float* __restrict__ dinv,
                                                 const __half* __restrict__ h2,
                                                 float* __restrict__ out) {
    int wave = threadIdx.x >> 6, lane = threadIdx.x & 63;
    int nsel = lane >> 5;
    int hl   = lane & 31;
    int c2   = lane & 1;
    int eo   = (lane >> 1) & 15;
    int bid  = blockIdx.x;
    int local = ((bid >> 3) * 4 + wave) * 2 + nsel;
    int node  = (bid & 7) * NPX + local;
    bool alive = (local < NPX);
    float di = dinv[node];
    int ns = *spill_cnt;                       // hoisted (uniform scalar)
    // hoisted out RMW loads: in flight during the whole gather+reduce
    float4 o0 = make_float4(0.f, 0.f, 0.f, 0.f), o1 = o0;
    float4* op = (float4*)(out + (size_t)node * 16 + c2 * 8);
    if (hl < 2 && alive) { o0 = op[0]; o1 = op[1]; }
    const uint* row = table + srow(node);
    uintx4 ev = __builtin_nontemporal_load(reinterpret_cast<const uintx4*>(row + 4 * eo));
    int s0 = ev.x & 0x1FFFF, s1 = ev.y & 0x1FFFF;
    int s2 = ev.z & 0x1FFFF, s3 = ev.w & 0x1FFFF;
    uint4 hv0 = *(const uint4*)(h2 + (size_t)s0 * 16 + c2 * 8);
    uint4 hv1 = *(const uint4*)(h2 + (size_t)s1 * 16 + c2 * 8);
    uint4 hv2 = *(const uint4*)(h2 + (size_t)s2 * 16 + c2 * 8);
    uint4 hv3 = *(const uint4*)(h2 + (size_t)s3 * 16 + c2 * 8);
    __half2 q0 = __half2half2(__ushort_as_half((ushort)(ev.x >> 17)));
    __half2 q1 = __half2half2(__ushort_as_half((ushort)(ev.y >> 17)));
    __half2 q2 = __half2half2(__ushort_as_half((ushort)(ev.z >> 17)));
    __half2 q3 = __half2half2(__ushort_as_half((ushort)(ev.w >> 17)));
    __half2 acc[4];
    acc[0] = __hmul2(q0, as_h2(hv0.x));
    acc[1] = __hmul2(q0, as_h2(hv0.y));
    acc[2] = __hmul2(q0, as_h2(hv0.z));
    acc[3] = __hmul2(q0, as_h2(hv0.w));
    acc[0] = __hfma2(q1, as_h2(hv1.x), acc[0]);
    acc[1] = __hfma2(q1, as_h2(hv1.y), acc[1]);
    acc[2] = __hfma2(q1, as_h2(hv1.z), acc[2]);
    acc[3] = __hfma2(q1, as_h2(hv1.w), acc[3]);
    acc[0] = __hfma2(q2, as_h2(hv2.x), acc[0]);
    acc[1] = __hfma2(q2, as_h2(hv2.y), acc[1]);
    acc[2] = __hfma2(q2, as_h2(hv2.z), acc[2]);
    acc[3] = __hfma2(q2, as_h2(hv2.w), acc[3]);
    acc[0] = __hfma2(q3, as_h2(hv3.x), acc[0]);
    acc[1] = __hfma2(q3, as_h2(hv3.y), acc[1]);
    acc[2] = __hfma2(q3, as_h2(hv3.z), acc[2]);
    acc[3] = __hfma2(q3, as_h2(hv3.w), acc[3]);
#pragma unroll
    for (int m = 2; m < 32; m <<= 1) {
#pragma unroll
        for (int k = 0; k < 4; k++)
            acc[k] = __hadd2(acc[k], as_h2(__shfl_xor(as_u32(acc[k]), m, 64)));
    }
    if ((hl < 2) && alive) {
        float accf[8];
#pragma unroll
        for (int k = 0; k < 4; k++) {
            float2 f = __half22float2(acc[k]);
            accf[2 * k + 0] = f.x;
            accf[2 * k + 1] = f.y;
        }
        if (ns > 0) {
            int nss = ns > SPILL_MAX ? SPILL_MAX : ns;
            for (int i = 0; i < nss; i++) {
                int4 q = sp[i];
                if (q.y == node) {
                    float f = __int_as_float(q.z);
                    uint4 qv = *(const uint4*)(h2 + (size_t)q.x * 16 + c2 * 8);
                    float2 u0 = __half22float2(as_h2(qv.x));
                    float2 u1 = __half22float2(as_h2(qv.y));
                    float2 u2 = __half22float2(as_h2(qv.z));
                    float2 u3 = __half22float2(as_h2(qv.w));
                    float uv[8] = {u0.x, u0.y, u1.x, u1.y, u2.x, u2.y, u3.x, u3.y};
                    for (int k = 0; k < 8; k++) accf[k] += f * uv[k];
                }
            }
        }
        o0.x += di * accf[0]; o0.y += di * accf[1];
        o0.z += di * accf[2]; o0.w += di * accf[3];
        o1.x += di * accf[4]; o1.y += di * accf[5];
        o1.z += di * accf[6]; o1.w += di * accf[7];
        op[0] = o0; op[1] = o1;
    }
}

// ===================== CSR fallback (round-2) =====================

__global__ void k_init(float* __restrict__ deg, int* __restrict__ cnt) {
    int i = blockIdx.x * blockDim.x + threadIdx.x;
    if (i < N_NODES) { deg[i] = 1.0f; if (cnt) cnt[i] = 0; }
}

__global__ void k_degcnt(const int* __restrict__ dst, const float* __restrict__ w,
                         float* __restrict__ deg, int* __restrict__ cnt) {
    int e = blockIdx.x * blockDim.x + threadIdx.x;
    if (e < N_EDGES) {
        int d = dst[e];
        atomicAdd(&deg[d], w[e]);
        if (cnt) atomicAdd(&cnt[d], 1);
    }
}

__global__ void k_dinv_agg(const float* __restrict__ x, float* __restrict__ deg_dinv,
                           float* __restrict__ agg) {
    int i = blockIdx.x * blockDim.x + threadIdx.x;
    if (i >= N_NODES) return;
    float di = rsqrtf(deg_dinv[i]);
    deg_dinv[i] = di;
    float s = di * di;
    const float4* xr = (const float4*)(x + (size_t)i * 16);
    float4* ar = (float4*)(agg + (size_t)i * 16);
#pragma unroll
    for (int k = 0; k < 4; k++) {
        float4 v = xr[k];
        v.x *= s; v.y *= s; v.z *= s; v.w *= s;
        ar[k] = v;
    }
}

__global__ __launch_bounds__(256) void k_scan1(const int* __restrict__ cnt,
                                               int* __restrict__ rowptr,
                                               int* __restrict__ bsum) {
    __shared__ int ts[256];
    int tid = threadIdx.x;
    int base = blockIdx.x * SCAN_CHUNK + tid * 8;
    int v[8]; int s = 0;
#pragma unroll
    for (int k = 0; k < 8; k++) {
        int idx = base + k;
        v[k] = (idx < N_NODES) ? cnt[idx] : 0;
        s += v[k];
    }
    ts[tid] = s;
    __syncthreads();
    for (int off = 1; off < 256; off <<= 1) {
        int t = (tid >= off) ? ts[tid - off] : 0;
        __syncthreads();
        ts[tid] += t;
        __syncthreads();
    }
    int run = ts[tid] - s;
#pragma unroll
    for (int k = 0; k < 8; k++) {
        int idx = base + k;
        if (idx < N_NODES) rowptr[idx] = run;
        run += v[k];
    }
    if (tid == 255) bsum[blockIdx.x] = ts[255];
}

__global__ void k_scan2(int* __restrict__ bsum) {
    if (threadIdx.x == 0 && blockIdx.x == 0) {
        int run = 0;
        for (int g = 0; g < SCAN_BLOCKS; g++) { int t = bsum[g]; bsum[g] = run; run += t; }
    }
}

__global__ __launch_bounds__(256) void k_scan3(int* __restrict__ rowptr,
                                               const int* __restrict__ bsum) {
    int tid = threadIdx.x;
    int base = blockIdx.x * SCAN_CHUNK + tid * 8;
    int off = bsum[blockIdx.x];
#pragma unroll
    for (int k = 0; k < 8; k++) {
        int idx = base + k;
        if (idx < N_NODES) rowptr[idx] += off;
    }
    if (blockIdx.x == 0 && tid == 0) rowptr[N_NODES] = N_EDGES;
}

__global__ void k_fill(const int* __restrict__ src, const int* __restrict__ dst,
                       const float* __restrict__ w, const float* __restrict__ dinv,
                       const int* __restrict__ rowptr, int* __restrict__ cnt,
                       int2* __restrict__ perm) {
    int e = blockIdx.x * blockDim.x + threadIdx.x;
    if (e >= N_EDGES) return;
    int s = src[e], d = dst[e];
    float nrm = dinv[s] * w[e] * dinv[d];
    int r = atomicSub(&cnt[d], 1) - 1;
    int pos = rowptr[d] + r;
    perm[pos] = make_int2(s, __float_as_int(nrm));
}

__global__ __launch_bounds__(256) void k_gather(const int2* __restrict__ perm,
                                                const int* __restrict__ rowptr,
                                                const float* __restrict__ feat,
                                                float* __restrict__ out) {
    int wave = threadIdx.x >> 6, lane = threadIdx.x & 63;
    int node = blockIdx.x * 4 + wave;
    int c = lane & 15, eo = lane >> 4;
    int beg = rowptr[node], end = rowptr[node + 1];
    float acc = 0.0f;
    for (int j = beg + eo; j < end; j += 4) {
        int2 ed = perm[j];
        acc = fmaf(__int_as_float(ed.y), feat[(size_t)ed.x * 16 + c], acc);
    }
    acc += __shfl_xor(acc, 16, 64);
    acc += __shfl_xor(acc, 32, 64);
    if (lane < 16) out[(size_t)node * 16 + c] += acc;
}

__global__ __launch_bounds__(256) void k_mlp(float* __restrict__ agg,
                                             const float* __restrict__ W1,
                                             const float* __restrict__ b1,
                                             const float* __restrict__ W2,
                                             const float* __restrict__ b2,
                                             const float* __restrict__ dinv,
                                             float* __restrict__ out) {
    __shared__ float o1s[4][128];
    int wave = threadIdx.x >> 6;
    int lane = threadIdx.x & 63;
    int node = blockIdx.x * 4 + wave;
    const float* f = agg + (size_t)node * 16;
    float fv[16];
#pragma unroll
    for (int k = 0; k < 4; k++) {
        float4 v = ((const float4*)f)[k];
        fv[4 * k + 0] = v.x; fv[4 * k + 1] = v.y; fv[4 * k + 2] = v.z; fv[4 * k + 3] = v.w;
    }
    float a = b1[2 * lane], b = b1[2 * lane + 1];
#pragma unroll
    for (int k = 0; k < 16; k++) {
        float2 wv = *(const float2*)(W1 + k * 128 + 2 * lane);
        a = fmaf(fv[k], wv.x, a);
        b = fmaf(fv[k], wv.y, b);
    }
    o1s[wave][2 * lane + 0] = fmaxf(a, 0.0f);
    o1s[wave][2 * lane + 1] = fmaxf(b, 0.0f);
    __syncthreads();
    int c = lane & 15, g = lane >> 4;
    float p = 0.0f;
#pragma unroll
    for (int k = 0; k < 32; k++) {
        int kk = g * 32 + k;
        p = fmaf(o1s[wave][kk], W2[kk * 16 + c], p);
    }
    p += __shfl_down(p, 16, 64);
    p += __shfl_down(p, 32, 64);
    __syncthreads();
    if (lane < 16) {
        float h2v = p;
        agg[(size_t)node * 16 + c] = h2v;
        float di = dinv[node];
        out[(size_t)node * 16 + c] = di * di * h2v + b2[c];
    }
}

__global__ void k_scatter(const int* __restrict__ src, const int* __restrict__ dst,
                          const float* __restrict__ w, const float* __restrict__ dinv,
                          const float* __restrict__ feat, float* __restrict__ out) {
    int t = blockIdx.x * blockDim.x + threadIdx.x;
    int e = t >> 2;
    int c4 = (t & 3) * 4;
    if (e >= N_EDGES) return;
    int s = src[e], d = dst[e];
    float nrm = dinv[s] * w[e] * dinv[d];
    float4 v = *(const float4*)(feat + (size_t)s * 16 + c4);
    float* o = out + (size_t)d * 16 + c4;
    atomicAdd(o + 0, nrm * v.x);
    atomicAdd(o + 1, nrm * v.y);
    atomicAdd(o + 2, nrm * v.z);
    atomicAdd(o + 3, nrm * v.w);
}

// ===================== launch =====================

extern "C" void kernel_launch(void* const* d_in, const int* in_sizes, int n_in,
                              void* d_out, int out_size, void* d_ws, size_t ws_size,
                              hipStream_t stream) {
    const float* x  = (const float*)d_in[0];
    const int*   ei = (const int*)d_in[1];
    const float* w  = (const float*)d_in[2];
    const float* W1 = (const float*)d_in[3];
    const float* b1 = (const float*)d_in[4];
    const float* W2 = (const float*)d_in[5];
    const float* b2 = (const float*)d_in[6];
    float* out = (float*)d_out;

    const int* src = ei;
    const int* dst = ei + N_EDGES;
    const int B = 256;

    // ---- fast-path workspace layout (16B-aligned blocks) ----
    char* p = (char*)d_ws;
    int*    bucket_cnt = (int*)p;        p += (size_t)((NBUCK + 3) & ~3) * 4;
    int*    spill_cnt  = (int*)p;        p += 16;
    float*  dinv       = (float*)p;      p += (size_t)N_PAD * 4;
    __half* y16        = (__half*)p;     p += (size_t)N_NODES * 16 * 2;
    __half* h2         = (__half*)p;     p += (size_t)N_NODES * 16 * 2;
    int4*   sp         = (int4*)p;       p += (size_t)SPILL_MAX * 16;
    uint2*  ebuf       = (uint2*)p;      p += (size_t)NBUCK * BCAP * 8;
    const size_t WS_FAST = (size_t)(p - (char*)d_ws);

    if (ws_size >= WS_FAST) {
        k_pre0<<<(NBUCK + B - 1) / B, B, 0, stream>>>(bucket_cnt, spill_cnt);
        k_bin<<<BIN_BLOCKS, B, 0, stream>>>(src, dst, w, bucket_cnt, ebuf, sp, spill_cnt);
        k_sortz<<<NBUCK, B, 0, stream>>>(ebuf, bucket_cnt, sp, spill_cnt, x, dinv, y16);
        k_gather_mlp<<<GBLK, B, 0, stream>>>((const uint*)ebuf, sp, spill_cnt, dinv,
                                             y16, x, W1, b1, W2, b2, h2, out);
        k_gather2<<<GBLK, B, 0, stream>>>((const uint*)ebuf, sp, spill_cnt, dinv,
                                          h2, out);
        return;
    }

    // ---- CSR fallback (round-2 path) ----
    float* deg_dinv = (float*)d_ws;
    int*   cntb     = (int*)(deg_dinv + N_PAD);
    int*   rowptr   = cntb + N_PAD;
    int*   bsum     = rowptr + N_PAD;
    float* agg      = (float*)(bsum + 64);
    int2*  perm     = (int2*)(agg + (size_t)N_NODES * 16);
    const size_t WS_CSR = ((size_t)N_PAD * 3 + 64 + (size_t)N_NODES * 16) * 4
                          + (size_t)N_EDGES * 8;

    if (ws_size >= WS_CSR) {
        k_init<<<(N_NODES + B - 1) / B, B, 0, stream>>>(deg_dinv, cntb);
        k_degcnt<<<(N_EDGES + B - 1) / B, B, 0, stream>>>(dst, w, deg_dinv, cntb);
        k_dinv_agg<<<(N_NODES + B - 1) / B, B, 0, stream>>>(x, deg_dinv, agg);
        k_scan1<<<SCAN_BLOCKS, 256, 0, stream>>>(cntb, rowptr, bsum);
        k_scan2<<<1, 64, 0, stream>>>(bsum);
        k_scan3<<<SCAN_BLOCKS, 256, 0, stream>>>(rowptr, bsum);
        k_fill<<<(N_EDGES + B - 1) / B, B, 0, stream>>>(src, dst, w, deg_dinv,
                                                        rowptr, cntb, perm);
        k_gather<<<N_NODES / 4, B, 0, stream>>>(perm, rowptr, x, agg);
        k_mlp<<<N_NODES / 4, B, 0, stream>>>(agg, W1, b1, W2, b2, deg_dinv, out);
        k_gather<<<N_NODES / 4, B, 0, stream>>>(perm, rowptr, agg, out);
    } else {
        float* deg = (float*)d_ws;
        float* ag  = (float*)d_ws + N_NODES;
        k_init<<<(N_NODES + B - 1) / B, B, 0, stream>>>(deg, (int*)nullptr);
        k_degcnt<<<(N_EDGES + B - 1) / B, B, 0, stream>>>(dst, w, deg, (int*)nullptr);
        k_dinv_agg<<<(N_NODES + B - 1) / B, B, 0, stream>>>(x, deg, ag);
        k_scatter<<<((size_t)N_EDGES * 4 + B - 1) / B, B, 0, stream>>>(src, dst, w, deg, x, ag);
        k_mlp<<<N_NODES / 4, B, 0, stream>>>(ag, W1, b1, W2, b2, deg, out);
        k_scatter<<<((size_t)N_EDGES * 4 + B - 1) / B, B, 0, stream>>>(src, dst, w, deg, ag, out);
    }
}